// Round 1
// baseline (2721.051 us; speedup 1.0000x reference)
//
#include <hip/hip_runtime.h>
#include <hip/hip_bf16.h>

// Problem constants
#define BDIM 1024
#define ROI 200
#define DIN 200
#define NSUB 8
#define NROWS (BDIM * ROI)          // 204800
#define XELEMS ((size_t)NROWS * 200) // 40,960,000

__device__ __constant__ int d_starts[8] = {0, 41, 70, 91, 110, 130, 137, 158};
__device__ __constant__ int d_ends[8]   = {41, 70, 91, 110, 130, 137, 158, 200};
__device__ __constant__ float d_invcnt[8] = {
    1.f/41.f, 1.f/29.f, 1.f/21.f, 1.f/19.f, 1.f/20.f, 1.f/7.f, 1.f/21.f, 1.f/42.f};

__device__ inline int seg_of(int r) {
  return (r < 41) ? 0 : (r < 70) ? 1 : (r < 91) ? 2 : (r < 110) ? 3
       : (r < 130) ? 4 : (r < 137) ? 5 : (r < 158) ? 6 : 7;
}

// rs_intra[row] = sum_{c<200} in[row*200 + c]; one wave per row
__global__ __launch_bounds__(64) void rowsum200_k(const float* __restrict__ in,
                                                  float* __restrict__ out) {
  int row = blockIdx.x;
  int lane = threadIdx.x;
  const float* p = in + (size_t)row * 200;
  float v = p[lane] + p[lane + 64] + p[lane + 128];
  if (lane < 8) v += p[lane + 192];
  #pragma unroll
  for (int off = 32; off > 0; off >>= 1) v += __shfl_down(v, off);
  if (lane == 0) out[row] = v;
}

// rs_inter[b*8+s] = sum_{c<8} in[b*64 + s*8 + c]
__global__ __launch_bounds__(256) void intersum_k(const float* __restrict__ in,
                                                  float* __restrict__ out) {
  int i = blockIdx.x * blockDim.x + threadIdx.x;
  if (i >= BDIM * NSUB) return;
  const float* p = in + (size_t)i * 8;
  float v = 0.f;
  #pragma unroll
  for (int c = 0; c < 8; ++c) v += p[c];
  out[i] = v;
}

// sub[(b*8+s)*200+f] = mean over rows of segment s of x[b, r, f]
__global__ __launch_bounds__(256) void seg_mean_k(const float* __restrict__ x,
                                                  float* __restrict__ sub) {
  int s = blockIdx.x;
  int b = blockIdx.y;
  int f = threadIdx.x;
  if (f >= 200) return;
  int st = d_starts[s], en = d_ends[s];
  const float* base = x + (size_t)b * 200 * 200 + f;
  float acc = 0.f;
  for (int r = st; r < en; ++r) acc += base[(size_t)r * 200];
  sub[((size_t)b * 8 + s) * 200 + f] = acc * d_invcnt[s];
}

// y[b,r,f] = 0.5*(rsI[b,r]*x[b,r,f] + rsP[b,seg(r)]*sub[b,seg(r),f])
__global__ __launch_bounds__(64) void block_combine_k(
    const float* __restrict__ x, const float* __restrict__ sub,
    const float* __restrict__ rsI, const float* __restrict__ rsP,
    float* __restrict__ y) {
  int row = blockIdx.x;  // b*200 + r
  int b = row / 200;
  int r = row - b * 200;
  int s = seg_of(r);
  float si = rsI[row];
  float sp = rsP[b * 8 + s];
  const float* xr = x + (size_t)row * 200;
  const float* sr = sub + ((size_t)b * 8 + s) * 200;
  float* yr = y + (size_t)row * 200;
  int lane = threadIdx.x;
  #pragma unroll
  for (int i = 0; i < 3; ++i) {
    int f = lane + i * 64;
    yr[f] = 0.5f * (si * xr[f] + sp * sr[f]);
  }
  if (lane < 8) {
    int f = lane + 192;
    yr[f] = 0.5f * (si * xr[f] + sp * sr[f]);
  }
}

// C[M,N] = act(A[M,K] @ W[K,N] + bias[N]); act=1 -> leaky_relu(0.2)
// 64x64 tile, BK=16, 256 threads, 4x4 per-thread micro-tile.
__global__ __launch_bounds__(256) void gemm_bias_act(
    const float* __restrict__ A, const float* __restrict__ W,
    const float* __restrict__ bias, float* __restrict__ C,
    int M, int N, int K, int act) {
  __shared__ float As[16][64];  // [k][m]
  __shared__ float Bs[16][64];  // [k][n]
  int tid = threadIdx.x;
  int tx = tid & 15;   // n dir
  int ty = tid >> 4;   // m dir
  int row0 = blockIdx.y * 64;
  int col0 = blockIdx.x * 64;
  float acc[4][4] = {{0.f}};

  for (int k0 = 0; k0 < K; k0 += 16) {
    // --- load A tile: 64 rows x 16 k, thread -> (m = tid/4, 4 k's) ---
    {
      int m = tid >> 2;
      int kq = (tid & 3) * 4;
      const float* src = A + (size_t)(row0 + m) * K + k0 + kq;
      if (k0 + 16 <= K) {
        float4 av = *(const float4*)src;
        As[kq + 0][m] = av.x; As[kq + 1][m] = av.y;
        As[kq + 2][m] = av.z; As[kq + 3][m] = av.w;
      } else {
        #pragma unroll
        for (int j = 0; j < 4; ++j) {
          int kk = k0 + kq + j;
          As[kq + j][m] = (kk < K) ? src[j] : 0.f;
        }
      }
    }
    // --- load B tile: 16 k x 64 n, thread -> (kk = tid/16, 4 n's) ---
    {
      int kk = tid >> 4;
      int nq = (tid & 15) * 4;
      const float* src = W + (size_t)(k0 + kk) * N + col0 + nq;
      if (k0 + 16 <= K && col0 + 64 <= N) {
        *(float4*)&Bs[kk][nq] = *(const float4*)src;
      } else {
        #pragma unroll
        for (int j = 0; j < 4; ++j) {
          int n = col0 + nq + j;
          Bs[kk][nq + j] = (k0 + kk < K && n < N) ? src[j] : 0.f;
        }
      }
    }
    __syncthreads();
    #pragma unroll
    for (int k = 0; k < 16; ++k) {
      float4 a = *(const float4*)&As[k][ty * 4];
      float4 bv = *(const float4*)&Bs[k][tx * 4];
      float av[4] = {a.x, a.y, a.z, a.w};
      float bb[4] = {bv.x, bv.y, bv.z, bv.w};
      #pragma unroll
      for (int i = 0; i < 4; ++i)
        #pragma unroll
        for (int j = 0; j < 4; ++j)
          acc[i][j] += av[i] * bb[j];
    }
    __syncthreads();
  }

  #pragma unroll
  for (int i = 0; i < 4; ++i) {
    int r = row0 + ty * 4 + i;
    if (r >= M) continue;
    #pragma unroll
    for (int j = 0; j < 4; ++j) {
      int c = col0 + tx * 4 + j;
      if (c >= N) continue;
      float v = acc[i][j] + bias[c];
      if (act) v = (v >= 0.f) ? v : 0.2f * v;
      C[(size_t)r * N + c] = v;
    }
  }
}

// BN2d stats: per-column sums/sumsq over 204800x200; stats[0..199]=sum, [200..399]=sumsq
__global__ __launch_bounds__(256) void bn2d_stats_k(const float* __restrict__ x,
                                                    float* __restrict__ stats) {
  __shared__ float s_sum[200];
  __shared__ float s_sq[200];
  int tid = threadIdx.x;
  if (tid < 200) { s_sum[tid] = 0.f; s_sq[tid] = 0.f; }
  __syncthreads();
  const int per = 20000;  // 100 rows
  size_t base = (size_t)blockIdx.x * per;
  for (int i = tid; i < per; i += 256) {
    float v = x[base + i];
    int col = i % 200;
    atomicAdd(&s_sum[col], v);
    atomicAdd(&s_sq[col], v * v);
  }
  __syncthreads();
  if (tid < 200) {
    atomicAdd(&stats[tid], s_sum[tid]);
    atomicAdd(&stats[200 + tid], s_sq[tid]);
  }
}

__global__ __launch_bounds__(256) void bn2d_apply_k(float* __restrict__ x,
                                                    const float* __restrict__ stats,
                                                    const float* __restrict__ g,
                                                    const float* __restrict__ be) {
  const float invN = 1.f / (float)NROWS;
  size_t stride = (size_t)gridDim.x * blockDim.x;
  for (size_t i = (size_t)blockIdx.x * blockDim.x + threadIdx.x; i < XELEMS; i += stride) {
    int col = (int)(i % 200);
    float m = stats[col] * invN;
    float var = stats[200 + col] * invN - m * m;
    x[i] = (x[i] - m) * rsqrtf(var + 1e-5f) * g[col] + be[col];
  }
}

// BN3d stats: x is (1024, 200, 8); per-r sums over (b, k)
__global__ __launch_bounds__(256) void bn3d_stats_k(const float* __restrict__ x,
                                                    float* __restrict__ stats) {
  __shared__ float s_sum[200];
  __shared__ float s_sq[200];
  int tid = threadIdx.x;
  if (tid < 200) { s_sum[tid] = 0.f; s_sq[tid] = 0.f; }
  __syncthreads();
  size_t base = (size_t)blockIdx.x * 1600;
  for (int i = tid; i < 1600; i += 256) {
    float v = x[base + i];
    int r = i >> 3;
    atomicAdd(&s_sum[r], v);
    atomicAdd(&s_sq[r], v * v);
  }
  __syncthreads();
  if (tid < 200) {
    atomicAdd(&stats[tid], s_sum[tid]);
    atomicAdd(&stats[200 + tid], s_sq[tid]);
  }
}

__global__ __launch_bounds__(256) void bn3d_apply_k(float* __restrict__ x,
                                                    const float* __restrict__ stats,
                                                    const float* __restrict__ g,
                                                    const float* __restrict__ be) {
  const size_t n = (size_t)BDIM * 1600;
  const float invN = 1.f / 8192.f;
  size_t stride = (size_t)gridDim.x * blockDim.x;
  for (size_t i = (size_t)blockIdx.x * blockDim.x + threadIdx.x; i < n; i += stride) {
    int r = (int)((i >> 3) % 200);
    float m = stats[r] * invN;
    float var = stats[200 + r] * invN - m * m;
    x[i] = (x[i] - m) * rsqrtf(var + 1e-5f) * g[r] + be[r];
  }
}

extern "C" void kernel_launch(void* const* d_in, const int* in_sizes, int n_in,
                              void* d_out, int out_size, void* d_ws, size_t ws_size,
                              hipStream_t stream) {
  const float* intra = (const float*)d_in[1];
  const float* inter = (const float*)d_in[2];
  const float* nodef = (const float*)d_in[3];
  const float* W0 = (const float*)d_in[4];
  const float* b0 = (const float*)d_in[5];
  const float* W1 = (const float*)d_in[6];
  const float* b1 = (const float*)d_in[7];
  const float* g1 = (const float*)d_in[8];
  const float* be1 = (const float*)d_in[9];
  const float* W2 = (const float*)d_in[10];
  const float* b2 = (const float*)d_in[11];
  const float* g2 = (const float*)d_in[12];
  const float* be2 = (const float*)d_in[13];
  const float* W3 = (const float*)d_in[14];
  const float* b3 = (const float*)d_in[15];
  const float* W4 = (const float*)d_in[16];
  const float* b4 = (const float*)d_in[17];
  const float* g3 = (const float*)d_in[18];
  const float* be3 = (const float*)d_in[19];
  const float* Wc1 = (const float*)d_in[20];
  const float* bc1 = (const float*)d_in[21];
  const float* Wc2 = (const float*)d_in[22];
  const float* bc2 = (const float*)d_in[23];
  const float* Wc3 = (const float*)d_in[24];
  const float* bc3 = (const float*)d_in[25];
  float* out = (float*)d_out;

  float* ws = (float*)d_ws;
  float* bufA = ws;                        // 40,960,000
  float* bufB = bufA + XELEMS;             // 40,960,000
  float* sub  = bufB + XELEMS;             // 1,638,400
  float* rsI  = sub + (size_t)BDIM * 8 * 200;  // 204,800
  float* rsP  = rsI + NROWS;               // 8,192
  float* stats = rsP + BDIM * 8;           // 400 (pad to 512)
  float* h1 = stats + 512;                 // 262,144
  float* h2 = h1 + (size_t)BDIM * 256;     // 32,768

  // row sums
  rowsum200_k<<<NROWS, 64, 0, stream>>>(intra, rsI);
  intersum_k<<<(BDIM * 8 + 255) / 256, 256, 0, stream>>>(inter, rsP);

  // block 1: node_features -> bufA
  seg_mean_k<<<dim3(8, BDIM), 256, 0, stream>>>(nodef, sub);
  block_combine_k<<<NROWS, 64, 0, stream>>>(nodef, sub, rsI, rsP, bufA);

  // x = leaky(x@W0+b0) @ W1 + b1
  gemm_bias_act<<<dim3(4, NROWS / 64), 256, 0, stream>>>(bufA, W0, b0, bufB, NROWS, 200, 200, 1);
  gemm_bias_act<<<dim3(4, NROWS / 64), 256, 0, stream>>>(bufB, W1, b1, bufA, NROWS, 200, 200, 0);

  // bn2d #1 (in place on bufA)
  hipMemsetAsync(stats, 0, 400 * sizeof(float), stream);
  bn2d_stats_k<<<2048, 256, 0, stream>>>(bufA, stats);
  bn2d_apply_k<<<2048, 256, 0, stream>>>(bufA, stats, g1, be1);

  // block 2: bufA -> bufB
  seg_mean_k<<<dim3(8, BDIM), 256, 0, stream>>>(bufA, sub);
  block_combine_k<<<NROWS, 64, 0, stream>>>(bufA, sub, rsI, rsP, bufB);

  // x = leaky(x@W2+b2)
  gemm_bias_act<<<dim3(4, NROWS / 64), 256, 0, stream>>>(bufB, W2, b2, bufA, NROWS, 200, 200, 1);

  // bn2d #2 (in place on bufA)
  hipMemsetAsync(stats, 0, 400 * sizeof(float), stream);
  bn2d_stats_k<<<2048, 256, 0, stream>>>(bufA, stats);
  bn2d_apply_k<<<2048, 256, 0, stream>>>(bufA, stats, g2, be2);

  // block 3: bufA -> bufB
  seg_mean_k<<<dim3(8, BDIM), 256, 0, stream>>>(bufA, sub);
  block_combine_k<<<NROWS, 64, 0, stream>>>(bufA, sub, rsI, rsP, bufB);

  // x = leaky(leaky(x@W3+b3)@W4+b4)
  gemm_bias_act<<<dim3(1, NROWS / 64), 256, 0, stream>>>(bufB, W3, b3, bufA, NROWS, 64, 200, 1);
  gemm_bias_act<<<dim3(1, NROWS / 64), 256, 0, stream>>>(bufA, W4, b4, bufB, NROWS, 8, 64, 1);

  // bn3d (in place on bufB, which is (1024, 200, 8) = (1024, 1600))
  hipMemsetAsync(stats, 0, 400 * sizeof(float), stream);
  bn3d_stats_k<<<BDIM, 256, 0, stream>>>(bufB, stats);
  bn3d_apply_k<<<1024, 256, 0, stream>>>(bufB, stats, g3, be3);

  // classifier
  gemm_bias_act<<<dim3(4, BDIM / 64), 256, 0, stream>>>(bufB, Wc1, bc1, h1, BDIM, 256, 1600, 1);
  gemm_bias_act<<<dim3(1, BDIM / 64), 256, 0, stream>>>(h1, Wc2, bc2, h2, BDIM, 32, 256, 1);
  gemm_bias_act<<<dim3(1, BDIM / 64), 256, 0, stream>>>(h2, Wc3, bc3, out, BDIM, 2, 32, 0);
}

// Round 2
// 2066.573 us; speedup vs baseline: 1.3167x; 1.3167x over previous
//
#include <hip/hip_runtime.h>
#include <hip/hip_bf16.h>

// Problem constants
#define BDIM 1024
#define ROI 200
#define DIN 200
#define NSUB 8
#define NROWS (BDIM * ROI)          // 204800
#define XELEMS ((size_t)NROWS * 200) // 40,960,000

__device__ __constant__ int d_starts[8] = {0, 41, 70, 91, 110, 130, 137, 158};
__device__ __constant__ int d_ends[8]   = {41, 70, 91, 110, 130, 137, 158, 200};
__device__ __constant__ float d_invcnt[8] = {
    1.f/41.f, 1.f/29.f, 1.f/21.f, 1.f/19.f, 1.f/20.f, 1.f/7.f, 1.f/21.f, 1.f/42.f};

__device__ inline int seg_of(int r) {
  return (r < 41) ? 0 : (r < 70) ? 1 : (r < 91) ? 2 : (r < 110) ? 3
       : (r < 130) ? 4 : (r < 137) ? 5 : (r < 158) ? 6 : 7;
}

// rs_intra[row] = sum_{c<200} in[row*200 + c]; one wave per row
__global__ __launch_bounds__(64) void rowsum200_k(const float* __restrict__ in,
                                                  float* __restrict__ out) {
  int row = blockIdx.x;
  int lane = threadIdx.x;
  const float* p = in + (size_t)row * 200;
  float v = p[lane] + p[lane + 64] + p[lane + 128];
  if (lane < 8) v += p[lane + 192];
  #pragma unroll
  for (int off = 32; off > 0; off >>= 1) v += __shfl_down(v, off);
  if (lane == 0) out[row] = v;
}

// rs_inter[b*8+s] = sum_{c<8} in[b*64 + s*8 + c]
__global__ __launch_bounds__(256) void intersum_k(const float* __restrict__ in,
                                                  float* __restrict__ out) {
  int i = blockIdx.x * blockDim.x + threadIdx.x;
  if (i >= BDIM * NSUB) return;
  const float* p = in + (size_t)i * 8;
  float v = 0.f;
  #pragma unroll
  for (int c = 0; c < 8; ++c) v += p[c];
  out[i] = v;
}

// sub[(b*8+s)*200+f] = mean over rows of segment s of x[b, r, f]
__global__ __launch_bounds__(256) void seg_mean_k(const float* __restrict__ x,
                                                  float* __restrict__ sub) {
  int s = blockIdx.x;
  int b = blockIdx.y;
  int f = threadIdx.x;
  if (f >= 200) return;
  int st = d_starts[s], en = d_ends[s];
  const float* base = x + (size_t)b * 200 * 200 + f;
  float acc = 0.f;
  for (int r = st; r < en; ++r) acc += base[(size_t)r * 200];
  sub[((size_t)b * 8 + s) * 200 + f] = acc * d_invcnt[s];
}

// y[b,r,f] = 0.5*(rsI[b,r]*x[b,r,f] + rsP[b,seg(r)]*sub[b,seg(r),f])
__global__ __launch_bounds__(64) void block_combine_k(
    const float* __restrict__ x, const float* __restrict__ sub,
    const float* __restrict__ rsI, const float* __restrict__ rsP,
    float* __restrict__ y) {
  int row = blockIdx.x;  // b*200 + r
  int b = row / 200;
  int r = row - b * 200;
  int s = seg_of(r);
  float si = rsI[row];
  float sp = rsP[b * 8 + s];
  const float* xr = x + (size_t)row * 200;
  const float* sr = sub + ((size_t)b * 8 + s) * 200;
  float* yr = y + (size_t)row * 200;
  int lane = threadIdx.x;
  #pragma unroll
  for (int i = 0; i < 3; ++i) {
    int f = lane + i * 64;
    yr[f] = 0.5f * (si * xr[f] + sp * sr[f]);
  }
  if (lane < 8) {
    int f = lane + 192;
    yr[f] = 0.5f * (si * xr[f] + sp * sr[f]);
  }
}

// C[M,N] = act(A[M,K] @ W[K,N] + bias[N]); act=1 -> leaky_relu(0.2)
// 64x64 tile, BK=16, 256 threads, 4x4 per-thread micro-tile.
__global__ __launch_bounds__(256) void gemm_bias_act(
    const float* __restrict__ A, const float* __restrict__ W,
    const float* __restrict__ bias, float* __restrict__ C,
    int M, int N, int K, int act) {
  __shared__ float As[16][64];  // [k][m]
  __shared__ float Bs[16][64];  // [k][n]
  int tid = threadIdx.x;
  int tx = tid & 15;   // n dir
  int ty = tid >> 4;   // m dir
  int row0 = blockIdx.y * 64;
  int col0 = blockIdx.x * 64;
  float acc[4][4] = {{0.f}};

  for (int k0 = 0; k0 < K; k0 += 16) {
    // --- load A tile: 64 rows x 16 k, thread -> (m = tid/4, 4 k's) ---
    {
      int m = tid >> 2;
      int kq = (tid & 3) * 4;
      const float* src = A + (size_t)(row0 + m) * K + k0 + kq;
      if (k0 + 16 <= K) {
        float4 av = *(const float4*)src;
        As[kq + 0][m] = av.x; As[kq + 1][m] = av.y;
        As[kq + 2][m] = av.z; As[kq + 3][m] = av.w;
      } else {
        #pragma unroll
        for (int j = 0; j < 4; ++j) {
          int kk = k0 + kq + j;
          As[kq + j][m] = (kk < K) ? src[j] : 0.f;
        }
      }
    }
    // --- load B tile: 16 k x 64 n, thread -> (kk = tid/16, 4 n's) ---
    {
      int kk = tid >> 4;
      int nq = (tid & 15) * 4;
      const float* src = W + (size_t)(k0 + kk) * N + col0 + nq;
      if (k0 + 16 <= K && col0 + 64 <= N) {
        *(float4*)&Bs[kk][nq] = *(const float4*)src;
      } else {
        #pragma unroll
        for (int j = 0; j < 4; ++j) {
          int n = col0 + nq + j;
          Bs[kk][nq + j] = (k0 + kk < K && n < N) ? src[j] : 0.f;
        }
      }
    }
    __syncthreads();
    #pragma unroll
    for (int k = 0; k < 16; ++k) {
      float4 a = *(const float4*)&As[k][ty * 4];
      float4 bv = *(const float4*)&Bs[k][tx * 4];
      float av[4] = {a.x, a.y, a.z, a.w};
      float bb[4] = {bv.x, bv.y, bv.z, bv.w};
      #pragma unroll
      for (int i = 0; i < 4; ++i)
        #pragma unroll
        for (int j = 0; j < 4; ++j)
          acc[i][j] += av[i] * bb[j];
    }
    __syncthreads();
  }

  #pragma unroll
  for (int i = 0; i < 4; ++i) {
    int r = row0 + ty * 4 + i;
    if (r >= M) continue;
    #pragma unroll
    for (int j = 0; j < 4; ++j) {
      int c = col0 + tx * 4 + j;
      if (c >= N) continue;
      float v = acc[i][j] + bias[c];
      if (act) v = (v >= 0.f) ? v : 0.2f * v;
      C[(size_t)r * N + c] = v;
    }
  }
}

// BN2d stats v2: fixed-column register accumulation, float2 loads.
// grid 1024 x block 128 (threads 0..99 active, each owns cols 2t, 2t+1).
__global__ __launch_bounds__(128) void bn2d_stats_k(const float* __restrict__ x,
                                                    float* __restrict__ stats) {
  int t = threadIdx.x;
  if (t >= 100) return;
  const int rows = NROWS / 1024;  // 200
  const float* p = x + (size_t)blockIdx.x * rows * 200 + 2 * t;
  float s0 = 0.f, q0 = 0.f, s1 = 0.f, q1 = 0.f;
  #pragma unroll 4
  for (int r = 0; r < rows; ++r) {
    float2 v = *(const float2*)(p + (size_t)r * 200);
    s0 += v.x; q0 += v.x * v.x;
    s1 += v.y; q1 += v.y * v.y;
  }
  int c = 2 * t;
  atomicAdd(&stats[c], s0);
  atomicAdd(&stats[200 + c], q0);
  atomicAdd(&stats[c + 1], s1);
  atomicAdd(&stats[200 + c + 1], q1);
}

// scale/shift from stats: ss[c] = g*rsqrt(var+eps), ss[200+c] = be - m*scale
__global__ __launch_bounds__(256) void bn_scale_k(const float* __restrict__ stats,
                                                  const float* __restrict__ g,
                                                  const float* __restrict__ be,
                                                  float invN,
                                                  float* __restrict__ ss) {
  int c = threadIdx.x;
  if (c >= 200) return;
  float m = stats[c] * invN;
  float var = stats[200 + c] * invN - m * m;
  float sc = rsqrtf(var + 1e-5f) * g[c];
  ss[c] = sc;
  ss[200 + c] = be[c] - m * sc;
}

__global__ __launch_bounds__(256) void bn2d_apply_k(float* __restrict__ x,
                                                    const float* __restrict__ ss) {
  const size_t nvec = XELEMS / 4;  // 10,240,000
  size_t stride = (size_t)gridDim.x * blockDim.x;
  for (size_t i = (size_t)blockIdx.x * blockDim.x + threadIdx.x; i < nvec; i += stride) {
    int c = (int)((i * 4) % 200);
    float4 v = ((float4*)x)[i];
    v.x = v.x * ss[c + 0] + ss[200 + c + 0];
    v.y = v.y * ss[c + 1] + ss[200 + c + 1];
    v.z = v.z * ss[c + 2] + ss[200 + c + 2];
    v.w = v.w * ss[c + 3] + ss[200 + c + 3];
    ((float4*)x)[i] = v;
  }
}

// BN3d stats v2: x is (1024, 200, 8); thread t (<200) owns r=t.
// grid 64 x block 256; each block covers 16 batch entries.
__global__ __launch_bounds__(256) void bn3d_stats_k(const float* __restrict__ x,
                                                    float* __restrict__ stats) {
  int t = threadIdx.x;
  if (t >= 200) return;
  const int bs = BDIM / 64;  // 16
  const float* p = x + (size_t)blockIdx.x * bs * 1600 + t * 8;
  float s = 0.f, q = 0.f;
  for (int b = 0; b < bs; ++b) {
    float4 v0 = *(const float4*)(p + (size_t)b * 1600);
    float4 v1 = *(const float4*)(p + (size_t)b * 1600 + 4);
    s += v0.x + v0.y + v0.z + v0.w + v1.x + v1.y + v1.z + v1.w;
    q += v0.x * v0.x + v0.y * v0.y + v0.z * v0.z + v0.w * v0.w
       + v1.x * v1.x + v1.y * v1.y + v1.z * v1.z + v1.w * v1.w;
  }
  atomicAdd(&stats[t], s);
  atomicAdd(&stats[200 + t], q);
}

__global__ __launch_bounds__(256) void bn3d_apply_k(float* __restrict__ x,
                                                    const float* __restrict__ ss) {
  const size_t nvec = (size_t)BDIM * 1600 / 4;  // 409,600
  size_t stride = (size_t)gridDim.x * blockDim.x;
  for (size_t i = (size_t)blockIdx.x * blockDim.x + threadIdx.x; i < nvec; i += stride) {
    int r = (int)((i >> 1) % 200);
    float4 v = ((float4*)x)[i];
    float sc = ss[r], sh = ss[200 + r];
    v.x = v.x * sc + sh;
    v.y = v.y * sc + sh;
    v.z = v.z * sc + sh;
    v.w = v.w * sc + sh;
    ((float4*)x)[i] = v;
  }
}

extern "C" void kernel_launch(void* const* d_in, const int* in_sizes, int n_in,
                              void* d_out, int out_size, void* d_ws, size_t ws_size,
                              hipStream_t stream) {
  const float* intra = (const float*)d_in[1];
  const float* inter = (const float*)d_in[2];
  const float* nodef = (const float*)d_in[3];
  const float* W0 = (const float*)d_in[4];
  const float* b0 = (const float*)d_in[5];
  const float* W1 = (const float*)d_in[6];
  const float* b1 = (const float*)d_in[7];
  const float* g1 = (const float*)d_in[8];
  const float* be1 = (const float*)d_in[9];
  const float* W2 = (const float*)d_in[10];
  const float* b2 = (const float*)d_in[11];
  const float* g2 = (const float*)d_in[12];
  const float* be2 = (const float*)d_in[13];
  const float* W3 = (const float*)d_in[14];
  const float* b3 = (const float*)d_in[15];
  const float* W4 = (const float*)d_in[16];
  const float* b4 = (const float*)d_in[17];
  const float* g3 = (const float*)d_in[18];
  const float* be3 = (const float*)d_in[19];
  const float* Wc1 = (const float*)d_in[20];
  const float* bc1 = (const float*)d_in[21];
  const float* Wc2 = (const float*)d_in[22];
  const float* bc2 = (const float*)d_in[23];
  const float* Wc3 = (const float*)d_in[24];
  const float* bc3 = (const float*)d_in[25];
  float* out = (float*)d_out;

  float* ws = (float*)d_ws;
  float* bufA = ws;                        // 40,960,000
  float* bufB = bufA + XELEMS;             // 40,960,000
  float* sub  = bufB + XELEMS;             // 1,638,400
  float* rsI  = sub + (size_t)BDIM * 8 * 200;  // 204,800
  float* rsP  = rsI + NROWS;               // 8,192
  float* stats = rsP + BDIM * 8;           // 400 (pad to 512)
  float* ssbuf = stats + 512;              // 400 (pad to 512)
  float* h1 = ssbuf + 512;                 // 262,144
  float* h2 = h1 + (size_t)BDIM * 256;     // 32,768

  // row sums
  rowsum200_k<<<NROWS, 64, 0, stream>>>(intra, rsI);
  intersum_k<<<(BDIM * 8 + 255) / 256, 256, 0, stream>>>(inter, rsP);

  // block 1: node_features -> bufA
  seg_mean_k<<<dim3(8, BDIM), 256, 0, stream>>>(nodef, sub);
  block_combine_k<<<NROWS, 64, 0, stream>>>(nodef, sub, rsI, rsP, bufA);

  // x = leaky(x@W0+b0) @ W1 + b1
  gemm_bias_act<<<dim3(4, NROWS / 64), 256, 0, stream>>>(bufA, W0, b0, bufB, NROWS, 200, 200, 1);
  gemm_bias_act<<<dim3(4, NROWS / 64), 256, 0, stream>>>(bufB, W1, b1, bufA, NROWS, 200, 200, 0);

  // bn2d #1 (in place on bufA)
  hipMemsetAsync(stats, 0, 400 * sizeof(float), stream);
  bn2d_stats_k<<<1024, 128, 0, stream>>>(bufA, stats);
  bn_scale_k<<<1, 256, 0, stream>>>(stats, g1, be1, 1.f / (float)NROWS, ssbuf);
  bn2d_apply_k<<<2048, 256, 0, stream>>>(bufA, ssbuf);

  // block 2: bufA -> bufB
  seg_mean_k<<<dim3(8, BDIM), 256, 0, stream>>>(bufA, sub);
  block_combine_k<<<NROWS, 64, 0, stream>>>(bufA, sub, rsI, rsP, bufB);

  // x = leaky(x@W2+b2)
  gemm_bias_act<<<dim3(4, NROWS / 64), 256, 0, stream>>>(bufB, W2, b2, bufA, NROWS, 200, 200, 1);

  // bn2d #2 (in place on bufA)
  hipMemsetAsync(stats, 0, 400 * sizeof(float), stream);
  bn2d_stats_k<<<1024, 128, 0, stream>>>(bufA, stats);
  bn_scale_k<<<1, 256, 0, stream>>>(stats, g2, be2, 1.f / (float)NROWS, ssbuf);
  bn2d_apply_k<<<2048, 256, 0, stream>>>(bufA, ssbuf);

  // block 3: bufA -> bufB
  seg_mean_k<<<dim3(8, BDIM), 256, 0, stream>>>(bufA, sub);
  block_combine_k<<<NROWS, 64, 0, stream>>>(bufA, sub, rsI, rsP, bufB);

  // x = leaky(leaky(x@W3+b3)@W4+b4)
  gemm_bias_act<<<dim3(1, NROWS / 64), 256, 0, stream>>>(bufB, W3, b3, bufA, NROWS, 64, 200, 1);
  gemm_bias_act<<<dim3(1, NROWS / 64), 256, 0, stream>>>(bufA, W4, b4, bufB, NROWS, 8, 64, 1);

  // bn3d (in place on bufB, which is (1024, 200, 8) = (1024, 1600))
  hipMemsetAsync(stats, 0, 400 * sizeof(float), stream);
  bn3d_stats_k<<<64, 256, 0, stream>>>(bufB, stats);
  bn_scale_k<<<1, 256, 0, stream>>>(stats, g3, be3, 1.f / 8192.f, ssbuf);
  bn3d_apply_k<<<512, 256, 0, stream>>>(bufB, ssbuf);

  // classifier
  gemm_bias_act<<<dim3(4, BDIM / 64), 256, 0, stream>>>(bufB, Wc1, bc1, h1, BDIM, 256, 1600, 1);
  gemm_bias_act<<<dim3(1, BDIM / 64), 256, 0, stream>>>(h1, Wc2, bc2, h2, BDIM, 32, 256, 1);
  gemm_bias_act<<<dim3(1, BDIM / 64), 256, 0, stream>>>(h2, Wc3, bc3, out, BDIM, 2, 32, 0);
}

// Round 3
// 1758.117 us; speedup vs baseline: 1.5477x; 1.1754x over previous
//
#include <hip/hip_runtime.h>
#include <hip/hip_bf16.h>

// Problem constants
#define BDIM 1024
#define ROI 200
#define DIN 200
#define NSUB 8
#define NROWS (BDIM * ROI)           // 204800
#define XELEMS ((size_t)NROWS * 200) // 40,960,000
#define KP 224                       // padded K for MFMA (14 steps of 16)

typedef __attribute__((ext_vector_type(8))) short short8;
typedef __attribute__((ext_vector_type(16))) float f32x16;

__device__ __constant__ int d_starts[8] = {0, 41, 70, 91, 110, 130, 137, 158};
__device__ __constant__ int d_ends[8]   = {41, 70, 91, 110, 130, 137, 158, 200};
__device__ __constant__ float d_invcnt[8] = {
    1.f/41.f, 1.f/29.f, 1.f/21.f, 1.f/19.f, 1.f/20.f, 1.f/7.f, 1.f/21.f, 1.f/42.f};

__device__ inline int seg_of(int r) {
  return (r < 41) ? 0 : (r < 70) ? 1 : (r < 91) ? 2 : (r < 110) ? 3
       : (r < 130) ? 4 : (r < 137) ? 5 : (r < 158) ? 6 : 7;
}

__device__ inline unsigned short f2bf_rn(float x) {
  unsigned u = __float_as_uint(x);
  return (unsigned short)((u + 0x7FFFu + ((u >> 16) & 1u)) >> 16);
}

// rs_intra: one wave per row, 4 rows per block
__global__ __launch_bounds__(256) void rowsum4_k(const float* __restrict__ in,
                                                 float* __restrict__ out) {
  int row = blockIdx.x * 4 + (threadIdx.x >> 6);
  int lane = threadIdx.x & 63;
  const float* p = in + (size_t)row * 200;
  float v = p[lane] + p[lane + 64] + p[lane + 128];
  if (lane < 8) v += p[lane + 192];
  #pragma unroll
  for (int off = 32; off > 0; off >>= 1) v += __shfl_down(v, off);
  if (lane == 0) out[row] = v;
}

__global__ __launch_bounds__(256) void intersum_k(const float* __restrict__ in,
                                                  float* __restrict__ out) {
  int i = blockIdx.x * blockDim.x + threadIdx.x;
  if (i >= BDIM * NSUB) return;
  const float* p = in + (size_t)i * 8;
  float v = 0.f;
  #pragma unroll
  for (int c = 0; c < 8; ++c) v += p[c];
  out[i] = v;
}

// sub[(b*8+s)*200+f] = mean over segment rows
__global__ __launch_bounds__(256) void seg_mean_k(const float* __restrict__ x,
                                                  float* __restrict__ sub) {
  int s = blockIdx.x;
  int b = blockIdx.y;
  int f = threadIdx.x;
  if (f >= 200) return;
  int st = d_starts[s], en = d_ends[s];
  const float* base = x + (size_t)b * 200 * 200 + f;
  float acc = 0.f;
  for (int r = st; r < en; ++r) acc += base[(size_t)r * 200];
  sub[((size_t)b * 8 + s) * 200 + f] = acc * d_invcnt[s];
}

// grid-stride float4 block combine: y = 0.5*(rsI*x + rsP*sub[seg])
__global__ __launch_bounds__(256) void block_combine4_k(
    const float* __restrict__ x, const float* __restrict__ sub,
    const float* __restrict__ rsI, const float* __restrict__ rsP,
    float* __restrict__ y) {
  const unsigned nvec = (unsigned)(XELEMS / 4);
  unsigned stride = gridDim.x * blockDim.x;
  for (unsigned i = blockIdx.x * blockDim.x + threadIdx.x; i < nvec; i += stride) {
    unsigned e = i * 4u;
    unsigned row = e / 200u;
    unsigned f = e - row * 200u;
    unsigned b = row / 200u;
    unsigned r = row - b * 200u;
    int s = seg_of((int)r);
    float si = rsI[row];
    float sp = rsP[b * 8 + s];
    float4 xv = ((const float4*)x)[i];
    float4 sv = *(const float4*)(sub + ((size_t)b * 8 + s) * 200 + f);
    float4 o;
    o.x = 0.5f * (si * xv.x + sp * sv.x);
    o.y = 0.5f * (si * xv.y + sp * sv.y);
    o.z = 0.5f * (si * xv.z + sp * sv.z);
    o.w = 0.5f * (si * xv.w + sp * sv.w);
    ((float4*)y)[i] = o;
  }
}

// Weight preconversion: W[k][n] fp32 -> Wt hi/lo [n][KP] bf16 (zero-padded)
__global__ __launch_bounds__(256) void wconv_k(const float* __restrict__ W, int K, int N,
                                               unsigned short* __restrict__ hi,
                                               unsigned short* __restrict__ lo) {
  int idx = blockIdx.x * 256 + threadIdx.x;
  if (idx >= KP * KP) return;
  int n = idx / KP, k = idx - n * KP;
  float v = (k < K && n < N) ? W[(size_t)k * N + n] : 0.f;
  unsigned short h = f2bf_rn(v);
  float hf = __uint_as_float(((unsigned)h) << 16);
  hi[idx] = h;
  lo[idx] = f2bf_rn(v - hf);
}

// MFMA GEMM: C[M,N] = act(A[M,200] @ W + bias), hi/lo bf16 3-MFMA split.
// 128 rows/block, 4 waves x 1 32-row fragment x NCF 32-col fragments.
template<int NCF, int ACT>
__global__ __launch_bounds__(256) void gemm_mfma_k(
    const float* __restrict__ A, const unsigned short* __restrict__ Wh,
    const unsigned short* __restrict__ Wl, const float* __restrict__ bias,
    float* __restrict__ C, int N) {
  __shared__ unsigned short wlds[4 * 224 * 8];  // [plane(arr*2+g)][n<224][8 bf16]
  int tid = threadIdx.x;
  int lane = tid & 63;
  int wid = tid >> 6;
  int row0 = blockIdx.x * 128 + wid * 32;
  int m = row0 + (lane & 31);
  const float* arow = A + (size_t)m * 200;
  int gsel = lane >> 5;       // k-half select
  int nidx = lane & 31;
  int khalf = gsel * 8;

  f32x16 acc[NCF];
  #pragma unroll
  for (int c = 0; c < NCF; ++c) acc[c] = 0.0f;

  for (int ks = 0; ks < 14; ++ks) {
    int k0 = ks * 16;
    __syncthreads();
    // stage W tile (fragment-order granules, contiguous 16B)
    for (int i = tid; i < 4 * NCF * 32; i += 256) {
      int n = i % (NCF * 32);
      int plane = i / (NCF * 32);   // 0,1 = hi g0/g1 ; 2,3 = lo g0/g1
      int g = plane & 1;
      const unsigned short* src = (plane < 2 ? Wh : Wl) + (size_t)n * KP + k0 + g * 8;
      int4 v = *(const int4*)src;
      *(int4*)&wlds[(plane * 224 + n) * 8] = v;
    }
    // A fragment: 8 consecutive k fp32 -> hi/lo bf16
    float4 f0 = *(const float4*)(arow + k0 + khalf);
    float4 f1 = *(const float4*)(arow + k0 + khalf + 4);
    short8 ah, al;
    {
      float xs[8] = {f0.x, f0.y, f0.z, f0.w, f1.x, f1.y, f1.z, f1.w};
      #pragma unroll
      for (int j = 0; j < 8; ++j) {
        unsigned u = __float_as_uint(xs[j]);
        unsigned r = (u + 0x7FFFu + ((u >> 16) & 1u)) >> 16;
        ah[j] = (short)r;
        float hf = __uint_as_float(r << 16);
        float xl = xs[j] - hf;
        unsigned ul = __float_as_uint(xl);
        al[j] = (short)((ul + 0x7FFFu + ((ul >> 16) & 1u)) >> 16);
      }
    }
    __syncthreads();
    const short8* wp = (const short8*)wlds;
    #pragma unroll
    for (int c = 0; c < NCF; ++c) {
      short8 wh = wp[gsel * 224 + c * 32 + nidx];
      short8 wl = wp[(2 + gsel) * 224 + c * 32 + nidx];
      acc[c] = __builtin_amdgcn_mfma_f32_32x32x16_bf16(ah, wh, acc[c], 0, 0, 0);
      acc[c] = __builtin_amdgcn_mfma_f32_32x32x16_bf16(al, wh, acc[c], 0, 0, 0);
      acc[c] = __builtin_amdgcn_mfma_f32_32x32x16_bf16(ah, wl, acc[c], 0, 0, 0);
    }
  }
  // epilogue: col = lane&31 (+32c); row = (reg&3) + 8*(reg>>2) + 4*(lane>>5)
  int rsub = 4 * gsel;
  #pragma unroll
  for (int c = 0; c < NCF; ++c) {
    int col = c * 32 + nidx;
    if (col < N) {
      float b = bias[col];
      #pragma unroll
      for (int reg = 0; reg < 16; ++reg) {
        int row = row0 + (reg & 3) + 8 * (reg >> 2) + rsub;
        float v = acc[c][reg] + b;
        if (ACT) v = (v >= 0.f) ? v : 0.2f * v;
        C[(size_t)row * N + col] = v;
      }
    }
  }
}

// fp32 vector GEMM (kept for tiny GEMMs: W4, classifier)
__global__ __launch_bounds__(256) void gemm_bias_act(
    const float* __restrict__ A, const float* __restrict__ W,
    const float* __restrict__ bias, float* __restrict__ C,
    int M, int N, int K, int act) {
  __shared__ float As[16][64];
  __shared__ float Bs[16][64];
  int tid = threadIdx.x;
  int tx = tid & 15;
  int ty = tid >> 4;
  int row0 = blockIdx.y * 64;
  int col0 = blockIdx.x * 64;
  float acc[4][4] = {{0.f}};

  for (int k0 = 0; k0 < K; k0 += 16) {
    {
      int mm = tid >> 2;
      int kq = (tid & 3) * 4;
      const float* src = A + (size_t)(row0 + mm) * K + k0 + kq;
      if (k0 + 16 <= K) {
        float4 av = *(const float4*)src;
        As[kq + 0][mm] = av.x; As[kq + 1][mm] = av.y;
        As[kq + 2][mm] = av.z; As[kq + 3][mm] = av.w;
      } else {
        #pragma unroll
        for (int j = 0; j < 4; ++j) {
          int kk = k0 + kq + j;
          As[kq + j][mm] = (kk < K) ? src[j] : 0.f;
        }
      }
    }
    {
      int kk = tid >> 4;
      int nq = (tid & 15) * 4;
      const float* src = W + (size_t)(k0 + kk) * N + col0 + nq;
      if (k0 + 16 <= K && col0 + 64 <= N) {
        *(float4*)&Bs[kk][nq] = *(const float4*)src;
      } else {
        #pragma unroll
        for (int j = 0; j < 4; ++j) {
          int n = col0 + nq + j;
          Bs[kk][nq + j] = (k0 + kk < K && n < N) ? src[j] : 0.f;
        }
      }
    }
    __syncthreads();
    #pragma unroll
    for (int k = 0; k < 16; ++k) {
      float4 a = *(const float4*)&As[k][ty * 4];
      float4 bv = *(const float4*)&Bs[k][tx * 4];
      float av[4] = {a.x, a.y, a.z, a.w};
      float bb[4] = {bv.x, bv.y, bv.z, bv.w};
      #pragma unroll
      for (int i = 0; i < 4; ++i)
        #pragma unroll
        for (int j = 0; j < 4; ++j)
          acc[i][j] += av[i] * bb[j];
    }
    __syncthreads();
  }

  #pragma unroll
  for (int i = 0; i < 4; ++i) {
    int r = row0 + ty * 4 + i;
    if (r >= M) continue;
    #pragma unroll
    for (int j = 0; j < 4; ++j) {
      int c = col0 + tx * 4 + j;
      if (c >= N) continue;
      float v = acc[i][j] + bias[c];
      if (act) v = (v >= 0.f) ? v : 0.2f * v;
      C[(size_t)r * N + c] = v;
    }
  }
}

// BN2d stats: fixed-column register accumulation
__global__ __launch_bounds__(128) void bn2d_stats_k(const float* __restrict__ x,
                                                    float* __restrict__ stats) {
  int t = threadIdx.x;
  if (t >= 100) return;
  const int rows = NROWS / 1024;  // 200
  const float* p = x + (size_t)blockIdx.x * rows * 200 + 2 * t;
  float s0 = 0.f, q0 = 0.f, s1 = 0.f, q1 = 0.f;
  #pragma unroll 4
  for (int r = 0; r < rows; ++r) {
    float2 v = *(const float2*)(p + (size_t)r * 200);
    s0 += v.x; q0 += v.x * v.x;
    s1 += v.y; q1 += v.y * v.y;
  }
  int c = 2 * t;
  atomicAdd(&stats[c], s0);
  atomicAdd(&stats[200 + c], q0);
  atomicAdd(&stats[c + 1], s1);
  atomicAdd(&stats[200 + c + 1], q1);
}

__global__ __launch_bounds__(256) void bn_scale_k(const float* __restrict__ stats,
                                                  const float* __restrict__ g,
                                                  const float* __restrict__ be,
                                                  float invN,
                                                  float* __restrict__ ss) {
  int c = threadIdx.x;
  if (c >= 200) return;
  float m = stats[c] * invN;
  float var = stats[200 + c] * invN - m * m;
  float sc = rsqrtf(var + 1e-5f) * g[c];
  ss[c] = sc;
  ss[200 + c] = be[c] - m * sc;
}

__global__ __launch_bounds__(256) void bn2d_apply_k(float* __restrict__ x,
                                                    const float* __restrict__ ss) {
  const size_t nvec = XELEMS / 4;
  size_t stride = (size_t)gridDim.x * blockDim.x;
  for (size_t i = (size_t)blockIdx.x * blockDim.x + threadIdx.x; i < nvec; i += stride) {
    int c = (int)((i * 4) % 200);
    float4 v = ((float4*)x)[i];
    v.x = v.x * ss[c + 0] + ss[200 + c + 0];
    v.y = v.y * ss[c + 1] + ss[200 + c + 1];
    v.z = v.z * ss[c + 2] + ss[200 + c + 2];
    v.w = v.w * ss[c + 3] + ss[200 + c + 3];
    ((float4*)x)[i] = v;
  }
}

__global__ __launch_bounds__(256) void bn3d_stats_k(const float* __restrict__ x,
                                                    float* __restrict__ stats) {
  int t = threadIdx.x;
  if (t >= 200) return;
  const int bs = BDIM / 64;  // 16
  const float* p = x + (size_t)blockIdx.x * bs * 1600 + t * 8;
  float s = 0.f, q = 0.f;
  for (int b = 0; b < bs; ++b) {
    float4 v0 = *(const float4*)(p + (size_t)b * 1600);
    float4 v1 = *(const float4*)(p + (size_t)b * 1600 + 4);
    s += v0.x + v0.y + v0.z + v0.w + v1.x + v1.y + v1.z + v1.w;
    q += v0.x * v0.x + v0.y * v0.y + v0.z * v0.z + v0.w * v0.w
       + v1.x * v1.x + v1.y * v1.y + v1.z * v1.z + v1.w * v1.w;
  }
  atomicAdd(&stats[t], s);
  atomicAdd(&stats[200 + t], q);
}

__global__ __launch_bounds__(256) void bn3d_apply_k(float* __restrict__ x,
                                                    const float* __restrict__ ss) {
  const size_t nvec = (size_t)BDIM * 1600 / 4;
  size_t stride = (size_t)gridDim.x * blockDim.x;
  for (size_t i = (size_t)blockIdx.x * blockDim.x + threadIdx.x; i < nvec; i += stride) {
    int r = (int)((i >> 1) % 200);
    float4 v = ((float4*)x)[i];
    float sc = ss[r], sh = ss[200 + r];
    v.x = v.x * sc + sh;
    v.y = v.y * sc + sh;
    v.z = v.z * sc + sh;
    v.w = v.w * sc + sh;
    ((float4*)x)[i] = v;
  }
}

extern "C" void kernel_launch(void* const* d_in, const int* in_sizes, int n_in,
                              void* d_out, int out_size, void* d_ws, size_t ws_size,
                              hipStream_t stream) {
  const float* intra = (const float*)d_in[1];
  const float* inter = (const float*)d_in[2];
  const float* nodef = (const float*)d_in[3];
  const float* W0 = (const float*)d_in[4];
  const float* b0 = (const float*)d_in[5];
  const float* W1 = (const float*)d_in[6];
  const float* b1 = (const float*)d_in[7];
  const float* g1 = (const float*)d_in[8];
  const float* be1 = (const float*)d_in[9];
  const float* W2 = (const float*)d_in[10];
  const float* b2 = (const float*)d_in[11];
  const float* g2 = (const float*)d_in[12];
  const float* be2 = (const float*)d_in[13];
  const float* W3 = (const float*)d_in[14];
  const float* b3 = (const float*)d_in[15];
  const float* W4 = (const float*)d_in[16];
  const float* b4 = (const float*)d_in[17];
  const float* g3 = (const float*)d_in[18];
  const float* be3 = (const float*)d_in[19];
  const float* Wc1 = (const float*)d_in[20];
  const float* bc1 = (const float*)d_in[21];
  const float* Wc2 = (const float*)d_in[22];
  const float* bc2 = (const float*)d_in[23];
  const float* Wc3 = (const float*)d_in[24];
  const float* bc3 = (const float*)d_in[25];
  float* out = (float*)d_out;

  float* ws = (float*)d_ws;
  float* bufA = ws;                            // 40,960,000 f
  float* bufB = bufA + XELEMS;                 // 40,960,000 f
  float* sub  = bufB + XELEMS;                 // 1,638,400 f
  float* rsI  = sub + (size_t)BDIM * 8 * 200;  // 204,800 f
  float* rsP  = rsI + NROWS;                   // 8,192 f
  float* stats = rsP + BDIM * 8;               // 512 f
  float* ssbuf = stats + 512;                  // 512 f
  float* h1 = ssbuf + 512;                     // 262,144 f
  float* h2 = h1 + (size_t)BDIM * 256;         // 32,768 f
  unsigned short* wt = (unsigned short*)(h2 + 32768);
  const size_t WSLOT = (size_t)KP * KP;        // 50,176
  unsigned short* w0h = wt;             unsigned short* w0l = w0h + WSLOT;
  unsigned short* w1h = w0l + WSLOT;    unsigned short* w1l = w1h + WSLOT;
  unsigned short* w2h = w1l + WSLOT;    unsigned short* w2l = w2h + WSLOT;
  unsigned short* w3h = w2l + WSLOT;    unsigned short* w3l = w3h + WSLOT;

  const int WCBLK = (KP * KP + 255) / 256;
  wconv_k<<<WCBLK, 256, 0, stream>>>(W0, 200, 200, w0h, w0l);
  wconv_k<<<WCBLK, 256, 0, stream>>>(W1, 200, 200, w1h, w1l);
  wconv_k<<<WCBLK, 256, 0, stream>>>(W2, 200, 200, w2h, w2l);
  wconv_k<<<WCBLK, 256, 0, stream>>>(W3, 200, 64, w3h, w3l);

  // row sums
  rowsum4_k<<<NROWS / 4, 256, 0, stream>>>(intra, rsI);
  intersum_k<<<(BDIM * 8 + 255) / 256, 256, 0, stream>>>(inter, rsP);

  // block 1: node_features -> bufA
  seg_mean_k<<<dim3(8, BDIM), 256, 0, stream>>>(nodef, sub);
  block_combine4_k<<<2048, 256, 0, stream>>>(nodef, sub, rsI, rsP, bufA);

  // x = leaky(x@W0+b0) @ W1 + b1   (MFMA)
  gemm_mfma_k<7, 1><<<NROWS / 128, 256, 0, stream>>>(bufA, w0h, w0l, b0, bufB, 200);
  gemm_mfma_k<7, 0><<<NROWS / 128, 256, 0, stream>>>(bufB, w1h, w1l, b1, bufA, 200);

  // bn2d #1
  hipMemsetAsync(stats, 0, 400 * sizeof(float), stream);
  bn2d_stats_k<<<1024, 128, 0, stream>>>(bufA, stats);
  bn_scale_k<<<1, 256, 0, stream>>>(stats, g1, be1, 1.f / (float)NROWS, ssbuf);
  bn2d_apply_k<<<2048, 256, 0, stream>>>(bufA, ssbuf);

  // block 2: bufA -> bufB
  seg_mean_k<<<dim3(8, BDIM), 256, 0, stream>>>(bufA, sub);
  block_combine4_k<<<2048, 256, 0, stream>>>(bufA, sub, rsI, rsP, bufB);

  // x = leaky(x@W2+b2)   (MFMA)
  gemm_mfma_k<7, 1><<<NROWS / 128, 256, 0, stream>>>(bufB, w2h, w2l, b2, bufA, 200);

  // bn2d #2
  hipMemsetAsync(stats, 0, 400 * sizeof(float), stream);
  bn2d_stats_k<<<1024, 128, 0, stream>>>(bufA, stats);
  bn_scale_k<<<1, 256, 0, stream>>>(stats, g2, be2, 1.f / (float)NROWS, ssbuf);
  bn2d_apply_k<<<2048, 256, 0, stream>>>(bufA, ssbuf);

  // block 3: bufA -> bufB
  seg_mean_k<<<dim3(8, BDIM), 256, 0, stream>>>(bufA, sub);
  block_combine4_k<<<2048, 256, 0, stream>>>(bufA, sub, rsI, rsP, bufB);

  // x = leaky(x@W3+b3)   (MFMA, N=64) ; then leaky(x@W4+b4) (vector)
  gemm_mfma_k<2, 1><<<NROWS / 128, 256, 0, stream>>>(bufB, w3h, w3l, b3, bufA, 64);
  gemm_bias_act<<<dim3(1, NROWS / 64), 256, 0, stream>>>(bufA, W4, b4, bufB, NROWS, 8, 64, 1);

  // bn3d on bufB (1024 x 1600)
  hipMemsetAsync(stats, 0, 400 * sizeof(float), stream);
  bn3d_stats_k<<<64, 256, 0, stream>>>(bufB, stats);
  bn_scale_k<<<1, 256, 0, stream>>>(stats, g3, be3, 1.f / 8192.f, ssbuf);
  bn3d_apply_k<<<512, 256, 0, stream>>>(bufB, ssbuf);

  // classifier
  gemm_bias_act<<<dim3(4, BDIM / 64), 256, 0, stream>>>(bufB, Wc1, bc1, h1, BDIM, 256, 1600, 1);
  gemm_bias_act<<<dim3(1, BDIM / 64), 256, 0, stream>>>(h1, Wc2, bc2, h2, BDIM, 32, 256, 1);
  gemm_bias_act<<<dim3(1, BDIM / 64), 256, 0, stream>>>(h2, Wc3, bc3, out, BDIM, 2, 32, 0);
}

// Round 4
// 1418.326 us; speedup vs baseline: 1.9185x; 1.2396x over previous
//
#include <hip/hip_runtime.h>
#include <hip/hip_bf16.h>

// Problem constants
#define BDIM 1024
#define ROI 200
#define DIN 200
#define NSUB 8
#define NROWS (BDIM * ROI)           // 204800
#define XELEMS ((size_t)NROWS * 200) // 40,960,000
#define KP 224                       // padded K (14 steps of 16; only 13 used)

typedef __attribute__((ext_vector_type(8))) short short8;
typedef __attribute__((ext_vector_type(16))) float f32x16;

__device__ __constant__ int d_starts[8] = {0, 41, 70, 91, 110, 130, 137, 158};
__device__ __constant__ int d_ends[8]   = {41, 70, 91, 110, 130, 137, 158, 200};
__device__ __constant__ float d_invcnt[8] = {
    1.f/41.f, 1.f/29.f, 1.f/21.f, 1.f/19.f, 1.f/20.f, 1.f/7.f, 1.f/21.f, 1.f/42.f};

__device__ inline int seg_of(int r) {
  return (r < 41) ? 0 : (r < 70) ? 1 : (r < 91) ? 2 : (r < 110) ? 3
       : (r < 130) ? 4 : (r < 137) ? 5 : (r < 158) ? 6 : 7;
}

__device__ inline unsigned short f2bf_rn(float x) {
  unsigned u = __float_as_uint(x);
  return (unsigned short)((u + 0x7FFFu + ((u >> 16) & 1u)) >> 16);
}

// rs_intra: one wave per row, 4 rows per block
__global__ __launch_bounds__(256) void rowsum4_k(const float* __restrict__ in,
                                                 float* __restrict__ out) {
  int row = blockIdx.x * 4 + (threadIdx.x >> 6);
  int lane = threadIdx.x & 63;
  const float* p = in + (size_t)row * 200;
  float v = p[lane] + p[lane + 64] + p[lane + 128];
  if (lane < 8) v += p[lane + 192];
  #pragma unroll
  for (int off = 32; off > 0; off >>= 1) v += __shfl_down(v, off);
  if (lane == 0) out[row] = v;
}

__global__ __launch_bounds__(256) void intersum_k(const float* __restrict__ in,
                                                  float* __restrict__ out) {
  int i = blockIdx.x * blockDim.x + threadIdx.x;
  if (i >= BDIM * NSUB) return;
  const float* p = in + (size_t)i * 8;
  float v = 0.f;
  #pragma unroll
  for (int c = 0; c < 8; ++c) v += p[c];
  out[i] = v;
}

// sub[(b*8+s)*200+f] = mean over segment rows (raw x; BN affine applied later)
__global__ __launch_bounds__(256) void seg_mean_k(const float* __restrict__ x,
                                                  float* __restrict__ sub) {
  int s = blockIdx.x;
  int b = blockIdx.y;
  int f = threadIdx.x;
  if (f >= 200) return;
  int st = d_starts[s], en = d_ends[s];
  const float* base = x + (size_t)b * 200 * 200 + f;
  float acc = 0.f;
  for (int r = st; r < en; ++r) acc += base[(size_t)r * 200];
  sub[((size_t)b * 8 + s) * 200 + f] = acc * d_invcnt[s];
}

// grid-stride float4 combine with optional BN affine fold:
// x_hat = x*sc+sh ; sub_hat = sub*sc+sh ; y = 0.5*(rsI*x_hat + rsP*sub_hat)
template<int BN>
__global__ __launch_bounds__(256) void block_combine_bn_k(
    const float* __restrict__ x, const float* __restrict__ sub,
    const float* __restrict__ rsI, const float* __restrict__ rsP,
    const float* __restrict__ ss, float* __restrict__ y) {
  const unsigned nvec = (unsigned)(XELEMS / 4);
  unsigned stride = gridDim.x * blockDim.x;
  for (unsigned i = blockIdx.x * blockDim.x + threadIdx.x; i < nvec; i += stride) {
    unsigned e = i * 4u;
    unsigned row = e / 200u;
    unsigned f = e - row * 200u;
    unsigned b = row / 200u;
    unsigned r = row - b * 200u;
    int s = seg_of((int)r);
    float si = rsI[row];
    float sp = rsP[b * 8 + s];
    float4 xv = ((const float4*)x)[i];
    float4 sv = *(const float4*)(sub + ((size_t)b * 8 + s) * 200 + f);
    if (BN) {
      float4 sc = *(const float4*)(ss + f);
      float4 sh = *(const float4*)(ss + 200 + f);
      xv.x = xv.x * sc.x + sh.x; xv.y = xv.y * sc.y + sh.y;
      xv.z = xv.z * sc.z + sh.z; xv.w = xv.w * sc.w + sh.w;
      sv.x = sv.x * sc.x + sh.x; sv.y = sv.y * sc.y + sh.y;
      sv.z = sv.z * sc.z + sh.z; sv.w = sv.w * sc.w + sh.w;
    }
    float4 o;
    o.x = 0.5f * (si * xv.x + sp * sv.x);
    o.y = 0.5f * (si * xv.y + sp * sv.y);
    o.z = 0.5f * (si * xv.z + sp * sv.z);
    o.w = 0.5f * (si * xv.w + sp * sv.w);
    ((float4*)y)[i] = o;
  }
}

// Weight preconversion into fragment-major layout:
// out[(((ks*2+g)*224)+n)*8 + j] = bf16(W[ks*16 + g*8 + j][n]), zero-padded.
__global__ __launch_bounds__(256) void wconv2_k(const float* __restrict__ W, int K, int N,
                                                unsigned short* __restrict__ hi,
                                                unsigned short* __restrict__ lo) {
  int idx = blockIdx.x * 256 + threadIdx.x;
  if (idx >= KP * KP) return;  // 50176 = 14*2*224*8
  int j = idx & 7;
  int g3 = idx >> 3;
  int n = g3 % 224;
  int p = g3 / 224;       // ks*2 + g
  int k = (p >> 1) * 16 + (p & 1) * 8 + j;
  float v = (k < K && n < N) ? W[(size_t)k * N + n] : 0.f;
  unsigned short h = f2bf_rn(v);
  float hf = __uint_as_float(((unsigned)h) << 16);
  hi[idx] = h;
  lo[idx] = f2bf_rn(v - hf);
}

// Barrier-free MFMA GEMM: C[M,N] = act(A[M,200] @ W + bias), hi/lo bf16 3-MFMA.
// No LDS staging: W fragments read directly from global (L2-resident),
// fully coalesced via fragment-major layout. A prefetched 1 K-step ahead.
// Optional fused BN2d column stats (sum / sumsq) via LDS reduce + atomics.
template<int NCF, int ACT, int STATS>
__global__ __launch_bounds__(256) void gemm_nb_k(
    const float* __restrict__ A, const unsigned short* __restrict__ Wh,
    const unsigned short* __restrict__ Wl, const float* __restrict__ bias,
    float* __restrict__ C, int N, float* __restrict__ stats) {
  __shared__ float s_sum[224];
  __shared__ float s_sq[224];
  int tid = threadIdx.x;
  if (STATS) {
    if (tid < 224) { s_sum[tid] = 0.f; s_sq[tid] = 0.f; }
    __syncthreads();
  }
  int lane = tid & 63;
  int wid = tid >> 6;
  int row0 = blockIdx.x * 128 + wid * 32;
  int gsel = lane >> 5;
  int nidx = lane & 31;
  int m = row0 + nidx;
  const float* arow = A + (size_t)m * 200 + gsel * 8;

  f32x16 acc[NCF];
  #pragma unroll
  for (int c = 0; c < NCF; ++c) acc[c] = 0.0f;

  float4 c0 = *(const float4*)(arow);
  float4 c1 = *(const float4*)(arow + 4);
  #pragma unroll
  for (int ks = 0; ks < 13; ++ks) {
    float4 nx0, nx1;
    if (ks < 12) {
      nx0 = *(const float4*)(arow + (ks + 1) * 16);
      nx1 = *(const float4*)(arow + (ks + 1) * 16 + 4);
    }
    short8 ah, al;
    {
      float xs[8] = {c0.x, c0.y, c0.z, c0.w, c1.x, c1.y, c1.z, c1.w};
      #pragma unroll
      for (int j = 0; j < 8; ++j) {
        unsigned u = __float_as_uint(xs[j]);
        unsigned r = (u + 0x7FFFu + ((u >> 16) & 1u)) >> 16;
        ah[j] = (short)r;
        float hf = __uint_as_float(r << 16);
        float xl = xs[j] - hf;
        unsigned ul = __float_as_uint(xl);
        al[j] = (short)((ul + 0x7FFFu + ((ul >> 16) & 1u)) >> 16);
      }
    }
    const short8* whp = (const short8*)Wh + (size_t)(ks * 2 + gsel) * 224 + nidx;
    const short8* wlp = (const short8*)Wl + (size_t)(ks * 2 + gsel) * 224 + nidx;
    #pragma unroll
    for (int c = 0; c < NCF; ++c) {
      short8 wh = whp[c * 32];
      short8 wl = wlp[c * 32];
      acc[c] = __builtin_amdgcn_mfma_f32_32x32x16_bf16(ah, wh, acc[c], 0, 0, 0);
      acc[c] = __builtin_amdgcn_mfma_f32_32x32x16_bf16(al, wh, acc[c], 0, 0, 0);
      acc[c] = __builtin_amdgcn_mfma_f32_32x32x16_bf16(ah, wl, acc[c], 0, 0, 0);
    }
    if (ks < 12) { c0 = nx0; c1 = nx1; }
  }

  // epilogue: col = c*32 + nidx ; row = row0 + (reg&3) + 8*(reg>>2) + 4*gsel
  int rsub = 4 * gsel;
  #pragma unroll
  for (int c = 0; c < NCF; ++c) {
    int col = c * 32 + nidx;
    if (col < N) {
      float b = bias[col];
      float ls = 0.f, lq = 0.f;
      #pragma unroll
      for (int reg = 0; reg < 16; ++reg) {
        int row = row0 + (reg & 3) + 8 * (reg >> 2) + rsub;
        float v = acc[c][reg] + b;
        if (ACT) v = (v >= 0.f) ? v : 0.2f * v;
        C[(size_t)row * N + col] = v;
        if (STATS) { ls += v; lq += v * v; }
      }
      if (STATS && col < 200) {
        atomicAdd(&s_sum[col], ls);
        atomicAdd(&s_sq[col], lq);
      }
    }
  }
  if (STATS) {
    __syncthreads();
    if (tid < 200) {
      atomicAdd(&stats[tid], s_sum[tid]);
      atomicAdd(&stats[200 + tid], s_sq[tid]);
    }
  }
}

// fp32 vector GEMM (tiny GEMMs: W4, classifier)
__global__ __launch_bounds__(256) void gemm_bias_act(
    const float* __restrict__ A, const float* __restrict__ W,
    const float* __restrict__ bias, float* __restrict__ C,
    int M, int N, int K, int act) {
  __shared__ float As[16][64];
  __shared__ float Bs[16][64];
  int tid = threadIdx.x;
  int tx = tid & 15;
  int ty = tid >> 4;
  int row0 = blockIdx.y * 64;
  int col0 = blockIdx.x * 64;
  float acc[4][4] = {{0.f}};

  for (int k0 = 0; k0 < K; k0 += 16) {
    {
      int mm = tid >> 2;
      int kq = (tid & 3) * 4;
      const float* src = A + (size_t)(row0 + mm) * K + k0 + kq;
      if (k0 + 16 <= K) {
        float4 av = *(const float4*)src;
        As[kq + 0][mm] = av.x; As[kq + 1][mm] = av.y;
        As[kq + 2][mm] = av.z; As[kq + 3][mm] = av.w;
      } else {
        #pragma unroll
        for (int j = 0; j < 4; ++j) {
          int kk = k0 + kq + j;
          As[kq + j][mm] = (kk < K) ? src[j] : 0.f;
        }
      }
    }
    {
      int kk = tid >> 4;
      int nq = (tid & 15) * 4;
      const float* src = W + (size_t)(k0 + kk) * N + col0 + nq;
      if (k0 + 16 <= K && col0 + 64 <= N) {
        *(float4*)&Bs[kk][nq] = *(const float4*)src;
      } else {
        #pragma unroll
        for (int j = 0; j < 4; ++j) {
          int n = col0 + nq + j;
          Bs[kk][nq + j] = (k0 + kk < K && n < N) ? src[j] : 0.f;
        }
      }
    }
    __syncthreads();
    #pragma unroll
    for (int k = 0; k < 16; ++k) {
      float4 a = *(const float4*)&As[k][ty * 4];
      float4 bv = *(const float4*)&Bs[k][tx * 4];
      float av[4] = {a.x, a.y, a.z, a.w};
      float bb[4] = {bv.x, bv.y, bv.z, bv.w};
      #pragma unroll
      for (int i = 0; i < 4; ++i)
        #pragma unroll
        for (int j = 0; j < 4; ++j)
          acc[i][j] += av[i] * bb[j];
    }
    __syncthreads();
  }

  #pragma unroll
  for (int i = 0; i < 4; ++i) {
    int r = row0 + ty * 4 + i;
    if (r >= M) continue;
    #pragma unroll
    for (int j = 0; j < 4; ++j) {
      int c = col0 + tx * 4 + j;
      if (c >= N) continue;
      float v = acc[i][j] + bias[c];
      if (act) v = (v >= 0.f) ? v : 0.2f * v;
      C[(size_t)r * N + c] = v;
    }
  }
}

__global__ __launch_bounds__(256) void bn_scale_k(const float* __restrict__ stats,
                                                  const float* __restrict__ g,
                                                  const float* __restrict__ be,
                                                  float invN,
                                                  float* __restrict__ ss) {
  int c = threadIdx.x;
  if (c >= 200) return;
  float m = stats[c] * invN;
  float var = stats[200 + c] * invN - m * m;
  float sc = rsqrtf(var + 1e-5f) * g[c];
  ss[c] = sc;
  ss[200 + c] = be[c] - m * sc;
}

__global__ __launch_bounds__(256) void bn3d_stats_k(const float* __restrict__ x,
                                                    float* __restrict__ stats) {
  int t = threadIdx.x;
  if (t >= 200) return;
  const int bs = BDIM / 64;  // 16
  const float* p = x + (size_t)blockIdx.x * bs * 1600 + t * 8;
  float s = 0.f, q = 0.f;
  for (int b = 0; b < bs; ++b) {
    float4 v0 = *(const float4*)(p + (size_t)b * 1600);
    float4 v1 = *(const float4*)(p + (size_t)b * 1600 + 4);
    s += v0.x + v0.y + v0.z + v0.w + v1.x + v1.y + v1.z + v1.w;
    q += v0.x * v0.x + v0.y * v0.y + v0.z * v0.z + v0.w * v0.w
       + v1.x * v1.x + v1.y * v1.y + v1.z * v1.z + v1.w * v1.w;
  }
  atomicAdd(&stats[t], s);
  atomicAdd(&stats[200 + t], q);
}

__global__ __launch_bounds__(256) void bn3d_apply_k(float* __restrict__ x,
                                                    const float* __restrict__ ss) {
  const size_t nvec = (size_t)BDIM * 1600 / 4;
  size_t stride = (size_t)gridDim.x * blockDim.x;
  for (size_t i = (size_t)blockIdx.x * blockDim.x + threadIdx.x; i < nvec; i += stride) {
    int r = (int)((i >> 1) % 200);
    float4 v = ((float4*)x)[i];
    float sc = ss[r], sh = ss[200 + r];
    v.x = v.x * sc + sh;
    v.y = v.y * sc + sh;
    v.z = v.z * sc + sh;
    v.w = v.w * sc + sh;
    ((float4*)x)[i] = v;
  }
}

extern "C" void kernel_launch(void* const* d_in, const int* in_sizes, int n_in,
                              void* d_out, int out_size, void* d_ws, size_t ws_size,
                              hipStream_t stream) {
  const float* intra = (const float*)d_in[1];
  const float* inter = (const float*)d_in[2];
  const float* nodef = (const float*)d_in[3];
  const float* W0 = (const float*)d_in[4];
  const float* b0 = (const float*)d_in[5];
  const float* W1 = (const float*)d_in[6];
  const float* b1 = (const float*)d_in[7];
  const float* g1 = (const float*)d_in[8];
  const float* be1 = (const float*)d_in[9];
  const float* W2 = (const float*)d_in[10];
  const float* b2 = (const float*)d_in[11];
  const float* g2 = (const float*)d_in[12];
  const float* be2 = (const float*)d_in[13];
  const float* W3 = (const float*)d_in[14];
  const float* b3 = (const float*)d_in[15];
  const float* W4 = (const float*)d_in[16];
  const float* b4 = (const float*)d_in[17];
  const float* g3 = (const float*)d_in[18];
  const float* be3 = (const float*)d_in[19];
  const float* Wc1 = (const float*)d_in[20];
  const float* bc1 = (const float*)d_in[21];
  const float* Wc2 = (const float*)d_in[22];
  const float* bc2 = (const float*)d_in[23];
  const float* Wc3 = (const float*)d_in[24];
  const float* bc3 = (const float*)d_in[25];
  float* out = (float*)d_out;

  float* ws = (float*)d_ws;
  float* bufA = ws;                            // 40,960,000 f
  float* bufB = bufA + XELEMS;                 // 40,960,000 f
  float* sub  = bufB + XELEMS;                 // 1,638,400 f
  float* rsI  = sub + (size_t)BDIM * 8 * 200;  // 204,800 f
  float* rsP  = rsI + NROWS;                   // 8,192 f
  float* stats = rsP + BDIM * 8;               // 512 f
  float* ssbuf = stats + 512;                  // 512 f
  float* h1 = ssbuf + 512;                     // 262,144 f
  float* h2 = h1 + (size_t)BDIM * 256;         // 32,768 f
  unsigned short* wt = (unsigned short*)(h2 + 32768);
  const size_t WSLOT = (size_t)KP * KP;        // 50,176 shorts
  unsigned short* w0h = wt;             unsigned short* w0l = w0h + WSLOT;
  unsigned short* w1h = w0l + WSLOT;    unsigned short* w1l = w1h + WSLOT;
  unsigned short* w2h = w1l + WSLOT;    unsigned short* w2l = w2h + WSLOT;
  unsigned short* w3h = w2l + WSLOT;    unsigned short* w3l = w3h + WSLOT;

  const int WCBLK = (KP * KP + 255) / 256;
  wconv2_k<<<WCBLK, 256, 0, stream>>>(W0, 200, 200, w0h, w0l);
  wconv2_k<<<WCBLK, 256, 0, stream>>>(W1, 200, 200, w1h, w1l);
  wconv2_k<<<WCBLK, 256, 0, stream>>>(W2, 200, 200, w2h, w2l);
  wconv2_k<<<WCBLK, 256, 0, stream>>>(W3, 200, 64, w3h, w3l);

  // row sums
  rowsum4_k<<<NROWS / 4, 256, 0, stream>>>(intra, rsI);
  intersum_k<<<(BDIM * 8 + 255) / 256, 256, 0, stream>>>(inter, rsP);

  // block 1 (no BN fold): node_features -> bufA
  seg_mean_k<<<dim3(8, BDIM), 256, 0, stream>>>(nodef, sub);
  block_combine_bn_k<0><<<2048, 256, 0, stream>>>(nodef, sub, rsI, rsP, nullptr, bufA);

  // x = leaky(x@W0+b0) @ W1 + b1 ; fused BN stats on W1 output
  gemm_nb_k<7, 1, 0><<<1600, 256, 0, stream>>>(bufA, w0h, w0l, b0, bufB, 200, nullptr);
  hipMemsetAsync(stats, 0, 400 * sizeof(float), stream);
  gemm_nb_k<7, 0, 1><<<1600, 256, 0, stream>>>(bufB, w1h, w1l, b1, bufA, 200, stats);
  bn_scale_k<<<1, 256, 0, stream>>>(stats, g1, be1, 1.f / (float)NROWS, ssbuf);

  // block 2 with BN fold: bufA(raw) -> bufB (BN'd + combined)
  seg_mean_k<<<dim3(8, BDIM), 256, 0, stream>>>(bufA, sub);
  block_combine_bn_k<1><<<2048, 256, 0, stream>>>(bufA, sub, rsI, rsP, ssbuf, bufB);

  // x = leaky(x@W2+b2) ; fused BN stats
  hipMemsetAsync(stats, 0, 400 * sizeof(float), stream);
  gemm_nb_k<7, 1, 1><<<1600, 256, 0, stream>>>(bufB, w2h, w2l, b2, bufA, 200, stats);
  bn_scale_k<<<1, 256, 0, stream>>>(stats, g2, be2, 1.f / (float)NROWS, ssbuf);

  // block 3 with BN fold: bufA(raw) -> bufB
  seg_mean_k<<<dim3(8, BDIM), 256, 0, stream>>>(bufA, sub);
  block_combine_bn_k<1><<<2048, 256, 0, stream>>>(bufA, sub, rsI, rsP, ssbuf, bufB);

  // x = leaky(x@W3+b3) (MFMA, N=64) ; then leaky(x@W4+b4) (vector)
  gemm_nb_k<2, 1, 0><<<1600, 256, 0, stream>>>(bufB, w3h, w3l, b3, bufA, 64, nullptr);
  gemm_bias_act<<<dim3(1, NROWS / 64), 256, 0, stream>>>(bufA, W4, b4, bufB, NROWS, 8, 64, 1);

  // bn3d on bufB (1024 x 1600)
  hipMemsetAsync(stats, 0, 400 * sizeof(float), stream);
  bn3d_stats_k<<<64, 256, 0, stream>>>(bufB, stats);
  bn_scale_k<<<1, 256, 0, stream>>>(stats, g3, be3, 1.f / 8192.f, ssbuf);
  bn3d_apply_k<<<512, 256, 0, stream>>>(bufB, ssbuf);

  // classifier
  gemm_bias_act<<<dim3(4, BDIM / 64), 256, 0, stream>>>(bufB, Wc1, bc1, h1, BDIM, 256, 1600, 1);
  gemm_bias_act<<<dim3(1, BDIM / 64), 256, 0, stream>>>(h1, Wc2, bc2, h2, BDIM, 32, 256, 1);
  gemm_bias_act<<<dim3(1, BDIM / 64), 256, 0, stream>>>(h2, Wc3, bc3, out, BDIM, 2, 32, 0);
}

// Round 5
// 1275.787 us; speedup vs baseline: 2.1328x; 1.1117x over previous
//
#include <hip/hip_runtime.h>
#include <hip/hip_bf16.h>

// Problem constants
#define BDIM 1024
#define ROI 200
#define DIN 200
#define NSUB 8
#define NROWS (BDIM * ROI)           // 204800
#define XELEMS ((size_t)NROWS * 200) // 40,960,000
#define KP 224                       // padded K (14 steps of 16; only 13 used)

typedef __attribute__((ext_vector_type(8))) short short8;
typedef __attribute__((ext_vector_type(16))) float f32x16;

__device__ __constant__ float d_invcnt[8] = {
    1.f/41.f, 1.f/29.f, 1.f/21.f, 1.f/19.f, 1.f/20.f, 1.f/7.f, 1.f/21.f, 1.f/42.f};

__device__ inline unsigned short f2bf_rn(float x) {
  unsigned u = __float_as_uint(x);
  return (unsigned short)((u + 0x7FFFu + ((u >> 16) & 1u)) >> 16);
}

// rs_intra: one wave per row, 4 rows per block
__global__ __launch_bounds__(256) void rowsum4_k(const float* __restrict__ in,
                                                 float* __restrict__ out) {
  int row = blockIdx.x * 4 + (threadIdx.x >> 6);
  int lane = threadIdx.x & 63;
  const float* p = in + (size_t)row * 200;
  float v = p[lane] + p[lane + 64] + p[lane + 128];
  if (lane < 8) v += p[lane + 192];
  #pragma unroll
  for (int off = 32; off > 0; off >>= 1) v += __shfl_down(v, off);
  if (lane == 0) out[row] = v;
}

__global__ __launch_bounds__(256) void intersum_k(const float* __restrict__ in,
                                                  float* __restrict__ out) {
  int i = blockIdx.x * blockDim.x + threadIdx.x;
  if (i >= BDIM * NSUB) return;
  const float* p = in + (size_t)i * 8;
  float v = 0.f;
  #pragma unroll
  for (int c = 0; c < 8; ++c) v += p[c];
  out[i] = v;
}

// Fused seg_mean + block_combine (+ optional BN affine fold).
// One block per batch b; thread f (<200) owns column f.
// Phase 1: per-segment column means (registers, segment-static loops).
// Phase 2: y[r,f] = 0.5*(rsI[r]*x_hat + rsP[s]*sub_hat[s]), x re-read (L2-hot).
template<int BN>
__global__ __launch_bounds__(256) void seg_combine_k(
    const float* __restrict__ x, const float* __restrict__ rsI,
    const float* __restrict__ rsP, const float* __restrict__ ss,
    float* __restrict__ y) {
  constexpr int STARTS[8] = {0, 41, 70, 91, 110, 130, 137, 158};
  constexpr int ENDS[8]   = {41, 70, 91, 110, 130, 137, 158, 200};
  int b = blockIdx.x;
  int f = threadIdx.x;
  if (f >= 200) return;
  const float* xb = x + (size_t)b * 200 * 200 + f;
  float sc = 1.f, sh = 0.f;
  if (BN) { sc = ss[f]; sh = ss[200 + f]; }
  float prop[8];
  #pragma unroll
  for (int s = 0; s < 8; ++s) {
    float a = 0.f;
    #pragma unroll 4
    for (int r = STARTS[s]; r < ENDS[s]; ++r) a += xb[(size_t)r * 200];
    a *= d_invcnt[s];
    if (BN) a = a * sc + sh;
    prop[s] = rsP[b * 8 + s] * a;
  }
  const float* rsIb = rsI + b * 200;
  float* yb = y + (size_t)b * 200 * 200 + f;
  #pragma unroll
  for (int s = 0; s < 8; ++s) {
    float pv = prop[s];
    #pragma unroll 4
    for (int r = STARTS[s]; r < ENDS[s]; ++r) {
      float xv = xb[(size_t)r * 200];
      if (BN) xv = xv * sc + sh;
      yb[(size_t)r * 200] = 0.5f * (rsIb[r] * xv + pv);
    }
  }
}

// Weight preconversion into fragment-major layout:
// out[(((ks*2+g)*224)+n)*8 + j] = bf16(W[ks*16 + g*8 + j][n]), zero-padded.
__global__ __launch_bounds__(256) void wconv2_k(const float* __restrict__ W, int K, int N,
                                                unsigned short* __restrict__ hi,
                                                unsigned short* __restrict__ lo) {
  int idx = blockIdx.x * 256 + threadIdx.x;
  if (idx >= KP * KP) return;  // 50176 = 14*2*224*8
  int j = idx & 7;
  int g3 = idx >> 3;
  int n = g3 % 224;
  int p = g3 / 224;       // ks*2 + g
  int k = (p >> 1) * 16 + (p & 1) * 8 + j;
  float v = (k < K && n < N) ? W[(size_t)k * N + n] : 0.f;
  unsigned short h = f2bf_rn(v);
  float hf = __uint_as_float(((unsigned)h) << 16);
  hi[idx] = h;
  lo[idx] = f2bf_rn(v - hf);
}

// Barrier-free MFMA GEMM with 4-deep A prefetch.
// C[M,N] = act(A[M,200] @ W + bias), hi/lo bf16 3-MFMA split.
// W fragments read directly from global (L2-resident), fragment-major.
// Optional fused BN2d column stats (sum / sumsq) via LDS reduce + atomics.
template<int NCF, int ACT, int STATS>
__global__ __launch_bounds__(256) void gemm_nb_k(
    const float* __restrict__ A, const unsigned short* __restrict__ Wh,
    const unsigned short* __restrict__ Wl, const float* __restrict__ bias,
    float* __restrict__ C, int N, float* __restrict__ stats) {
  __shared__ float s_sum[224];
  __shared__ float s_sq[224];
  int tid = threadIdx.x;
  if (STATS) {
    if (tid < 224) { s_sum[tid] = 0.f; s_sq[tid] = 0.f; }
    __syncthreads();
  }
  int lane = tid & 63;
  int wid = tid >> 6;
  int row0 = blockIdx.x * 128 + wid * 32;
  int gsel = lane >> 5;
  int nidx = lane & 31;
  int m = row0 + nidx;
  const float* arow = A + (size_t)m * 200 + gsel * 8;

  f32x16 acc[NCF];
  #pragma unroll
  for (int c = 0; c < NCF; ++c) acc[c] = 0.0f;

  // 4-deep A prefetch ring (static indices after full unroll)
  float4 p0[4], p1[4];
  #pragma unroll
  for (int i = 0; i < 4; ++i) {
    p0[i] = *(const float4*)(arow + i * 16);
    p1[i] = *(const float4*)(arow + i * 16 + 4);
  }

  #pragma unroll
  for (int ks = 0; ks < 13; ++ks) {
    const int sl = ks & 3;
    short8 ah, al;
    {
      float xs[8] = {p0[sl].x, p0[sl].y, p0[sl].z, p0[sl].w,
                     p1[sl].x, p1[sl].y, p1[sl].z, p1[sl].w};
      #pragma unroll
      for (int j = 0; j < 8; ++j) {
        unsigned u = __float_as_uint(xs[j]);
        unsigned r = (u + 0x7FFFu + ((u >> 16) & 1u)) >> 16;
        ah[j] = (short)r;
        float hf = __uint_as_float(r << 16);
        float xl = xs[j] - hf;
        unsigned ul = __float_as_uint(xl);
        al[j] = (short)((ul + 0x7FFFu + ((ul >> 16) & 1u)) >> 16);
      }
    }
    if (ks < 9) {
      p0[sl] = *(const float4*)(arow + (ks + 4) * 16);
      p1[sl] = *(const float4*)(arow + (ks + 4) * 16 + 4);
    }
    const short8* whp = (const short8*)Wh + (size_t)(ks * 2 + gsel) * 224 + nidx;
    const short8* wlp = (const short8*)Wl + (size_t)(ks * 2 + gsel) * 224 + nidx;
    #pragma unroll
    for (int c = 0; c < NCF; ++c) {
      short8 wh = whp[c * 32];
      short8 wl = wlp[c * 32];
      acc[c] = __builtin_amdgcn_mfma_f32_32x32x16_bf16(ah, wh, acc[c], 0, 0, 0);
      acc[c] = __builtin_amdgcn_mfma_f32_32x32x16_bf16(al, wh, acc[c], 0, 0, 0);
      acc[c] = __builtin_amdgcn_mfma_f32_32x32x16_bf16(ah, wl, acc[c], 0, 0, 0);
    }
  }

  // epilogue: col = c*32 + nidx ; row = row0 + (reg&3) + 8*(reg>>2) + 4*gsel
  int rsub = 4 * gsel;
  #pragma unroll
  for (int c = 0; c < NCF; ++c) {
    int col = c * 32 + nidx;
    if (col < N) {
      float b = bias[col];
      float ls = 0.f, lq = 0.f;
      #pragma unroll
      for (int reg = 0; reg < 16; ++reg) {
        int row = row0 + (reg & 3) + 8 * (reg >> 2) + rsub;
        float v = acc[c][reg] + b;
        if (ACT) v = (v >= 0.f) ? v : 0.2f * v;
        C[(size_t)row * N + col] = v;
        if (STATS) { ls += v; lq += v * v; }
      }
      if (STATS && col < 200) {
        atomicAdd(&s_sum[col], ls);
        atomicAdd(&s_sq[col], lq);
      }
    }
  }
  if (STATS) {
    __syncthreads();
    if (tid < 200) {
      atomicAdd(&stats[tid], s_sum[tid]);
      atomicAdd(&stats[200 + tid], s_sq[tid]);
    }
  }
}

// fp32 vector GEMM (tiny GEMMs: W4, classifier)
__global__ __launch_bounds__(256) void gemm_bias_act(
    const float* __restrict__ A, const float* __restrict__ W,
    const float* __restrict__ bias, float* __restrict__ C,
    int M, int N, int K, int act) {
  __shared__ float As[16][64];
  __shared__ float Bs[16][64];
  int tid = threadIdx.x;
  int tx = tid & 15;
  int ty = tid >> 4;
  int row0 = blockIdx.y * 64;
  int col0 = blockIdx.x * 64;
  float acc[4][4] = {{0.f}};

  for (int k0 = 0; k0 < K; k0 += 16) {
    {
      int mm = tid >> 2;
      int kq = (tid & 3) * 4;
      const float* src = A + (size_t)(row0 + mm) * K + k0 + kq;
      if (k0 + 16 <= K) {
        float4 av = *(const float4*)src;
        As[kq + 0][mm] = av.x; As[kq + 1][mm] = av.y;
        As[kq + 2][mm] = av.z; As[kq + 3][mm] = av.w;
      } else {
        #pragma unroll
        for (int j = 0; j < 4; ++j) {
          int kk = k0 + kq + j;
          As[kq + j][mm] = (kk < K) ? src[j] : 0.f;
        }
      }
    }
    {
      int kk = tid >> 4;
      int nq = (tid & 15) * 4;
      const float* src = W + (size_t)(k0 + kk) * N + col0 + nq;
      if (k0 + 16 <= K && col0 + 64 <= N) {
        *(float4*)&Bs[kk][nq] = *(const float4*)src;
      } else {
        #pragma unroll
        for (int j = 0; j < 4; ++j) {
          int n = col0 + nq + j;
          Bs[kk][nq + j] = (k0 + kk < K && n < N) ? src[j] : 0.f;
        }
      }
    }
    __syncthreads();
    #pragma unroll
    for (int k = 0; k < 16; ++k) {
      float4 a = *(const float4*)&As[k][ty * 4];
      float4 bv = *(const float4*)&Bs[k][tx * 4];
      float av[4] = {a.x, a.y, a.z, a.w};
      float bb[4] = {bv.x, bv.y, bv.z, bv.w};
      #pragma unroll
      for (int i = 0; i < 4; ++i)
        #pragma unroll
        for (int j = 0; j < 4; ++j)
          acc[i][j] += av[i] * bb[j];
    }
    __syncthreads();
  }

  #pragma unroll
  for (int i = 0; i < 4; ++i) {
    int r = row0 + ty * 4 + i;
    if (r >= M) continue;
    #pragma unroll
    for (int j = 0; j < 4; ++j) {
      int c = col0 + tx * 4 + j;
      if (c >= N) continue;
      float v = acc[i][j] + bias[c];
      if (act) v = (v >= 0.f) ? v : 0.2f * v;
      C[(size_t)r * N + c] = v;
    }
  }
}

__global__ __launch_bounds__(256) void bn_scale_k(const float* __restrict__ stats,
                                                  const float* __restrict__ g,
                                                  const float* __restrict__ be,
                                                  float invN,
                                                  float* __restrict__ ss) {
  int c = threadIdx.x;
  if (c >= 200) return;
  float m = stats[c] * invN;
  float var = stats[200 + c] * invN - m * m;
  float sc = rsqrtf(var + 1e-5f) * g[c];
  ss[c] = sc;
  ss[200 + c] = be[c] - m * sc;
}

__global__ __launch_bounds__(256) void bn3d_stats_k(const float* __restrict__ x,
                                                    float* __restrict__ stats) {
  int t = threadIdx.x;
  if (t >= 200) return;
  const int bs = BDIM / 64;  // 16
  const float* p = x + (size_t)blockIdx.x * bs * 1600 + t * 8;
  float s = 0.f, q = 0.f;
  for (int b = 0; b < bs; ++b) {
    float4 v0 = *(const float4*)(p + (size_t)b * 1600);
    float4 v1 = *(const float4*)(p + (size_t)b * 1600 + 4);
    s += v0.x + v0.y + v0.z + v0.w + v1.x + v1.y + v1.z + v1.w;
    q += v0.x * v0.x + v0.y * v0.y + v0.z * v0.z + v0.w * v0.w
       + v1.x * v1.x + v1.y * v1.y + v1.z * v1.z + v1.w * v1.w;
  }
  atomicAdd(&stats[t], s);
  atomicAdd(&stats[200 + t], q);
}

__global__ __launch_bounds__(256) void bn3d_apply_k(float* __restrict__ x,
                                                    const float* __restrict__ ss) {
  const size_t nvec = (size_t)BDIM * 1600 / 4;
  size_t stride = (size_t)gridDim.x * blockDim.x;
  for (size_t i = (size_t)blockIdx.x * blockDim.x + threadIdx.x; i < nvec; i += stride) {
    int r = (int)((i >> 1) % 200);
    float4 v = ((float4*)x)[i];
    float sc = ss[r], sh = ss[200 + r];
    v.x = v.x * sc + sh;
    v.y = v.y * sc + sh;
    v.z = v.z * sc + sh;
    v.w = v.w * sc + sh;
    ((float4*)x)[i] = v;
  }
}

extern "C" void kernel_launch(void* const* d_in, const int* in_sizes, int n_in,
                              void* d_out, int out_size, void* d_ws, size_t ws_size,
                              hipStream_t stream) {
  const float* intra = (const float*)d_in[1];
  const float* inter = (const float*)d_in[2];
  const float* nodef = (const float*)d_in[3];
  const float* W0 = (const float*)d_in[4];
  const float* b0 = (const float*)d_in[5];
  const float* W1 = (const float*)d_in[6];
  const float* b1 = (const float*)d_in[7];
  const float* g1 = (const float*)d_in[8];
  const float* be1 = (const float*)d_in[9];
  const float* W2 = (const float*)d_in[10];
  const float* b2 = (const float*)d_in[11];
  const float* g2 = (const float*)d_in[12];
  const float* be2 = (const float*)d_in[13];
  const float* W3 = (const float*)d_in[14];
  const float* b3 = (const float*)d_in[15];
  const float* W4 = (const float*)d_in[16];
  const float* b4 = (const float*)d_in[17];
  const float* g3 = (const float*)d_in[18];
  const float* be3 = (const float*)d_in[19];
  const float* Wc1 = (const float*)d_in[20];
  const float* bc1 = (const float*)d_in[21];
  const float* Wc2 = (const float*)d_in[22];
  const float* bc2 = (const float*)d_in[23];
  const float* Wc3 = (const float*)d_in[24];
  const float* bc3 = (const float*)d_in[25];
  float* out = (float*)d_out;

  float* ws = (float*)d_ws;
  float* bufA = ws;                            // 40,960,000 f
  float* bufB = bufA + XELEMS;                 // 40,960,000 f
  float* rsI  = bufB + XELEMS;                 // 204,800 f
  float* rsP  = rsI + NROWS;                   // 8,192 f
  float* stats = rsP + BDIM * 8;               // 512 f
  float* ssbuf = stats + 512;                  // 512 f
  float* h1 = ssbuf + 512;                     // 262,144 f
  float* h2 = h1 + (size_t)BDIM * 256;         // 32,768 f
  unsigned short* wt = (unsigned short*)(h2 + 32768);
  const size_t WSLOT = (size_t)KP * KP;        // 50,176 shorts
  unsigned short* w0h = wt;             unsigned short* w0l = w0h + WSLOT;
  unsigned short* w1h = w0l + WSLOT;    unsigned short* w1l = w1h + WSLOT;
  unsigned short* w2h = w1l + WSLOT;    unsigned short* w2l = w2h + WSLOT;
  unsigned short* w3h = w2l + WSLOT;    unsigned short* w3l = w3h + WSLOT;

  const int WCBLK = (KP * KP + 255) / 256;
  wconv2_k<<<WCBLK, 256, 0, stream>>>(W0, 200, 200, w0h, w0l);
  wconv2_k<<<WCBLK, 256, 0, stream>>>(W1, 200, 200, w1h, w1l);
  wconv2_k<<<WCBLK, 256, 0, stream>>>(W2, 200, 200, w2h, w2l);
  wconv2_k<<<WCBLK, 256, 0, stream>>>(W3, 200, 64, w3h, w3l);

  // row sums
  rowsum4_k<<<NROWS / 4, 256, 0, stream>>>(intra, rsI);
  intersum_k<<<(BDIM * 8 + 255) / 256, 256, 0, stream>>>(inter, rsP);

  // block 1 (no BN fold): node_features -> bufA
  seg_combine_k<0><<<BDIM, 256, 0, stream>>>(nodef, rsI, rsP, nullptr, bufA);

  // x = leaky(x@W0+b0) @ W1 + b1 ; fused BN stats on W1 output
  gemm_nb_k<7, 1, 0><<<1600, 256, 0, stream>>>(bufA, w0h, w0l, b0, bufB, 200, nullptr);
  hipMemsetAsync(stats, 0, 400 * sizeof(float), stream);
  gemm_nb_k<7, 0, 1><<<1600, 256, 0, stream>>>(bufB, w1h, w1l, b1, bufA, 200, stats);
  bn_scale_k<<<1, 256, 0, stream>>>(stats, g1, be1, 1.f / (float)NROWS, ssbuf);

  // block 2 with BN1 fold: bufA(raw) -> bufB
  seg_combine_k<1><<<BDIM, 256, 0, stream>>>(bufA, rsI, rsP, ssbuf, bufB);

  // x = leaky(x@W2+b2) ; fused BN stats
  hipMemsetAsync(stats, 0, 400 * sizeof(float), stream);
  gemm_nb_k<7, 1, 1><<<1600, 256, 0, stream>>>(bufB, w2h, w2l, b2, bufA, 200, stats);
  bn_scale_k<<<1, 256, 0, stream>>>(stats, g2, be2, 1.f / (float)NROWS, ssbuf);

  // block 3 with BN2 fold: bufA(raw) -> bufB
  seg_combine_k<1><<<BDIM, 256, 0, stream>>>(bufA, rsI, rsP, ssbuf, bufB);

  // x = leaky(x@W3+b3) (MFMA, N=64) ; then leaky(x@W4+b4) (vector)
  gemm_nb_k<2, 1, 0><<<1600, 256, 0, stream>>>(bufB, w3h, w3l, b3, bufA, 64, nullptr);
  gemm_bias_act<<<dim3(1, NROWS / 64), 256, 0, stream>>>(bufA, W4, b4, bufB, NROWS, 8, 64, 1);

  // bn3d on bufB (1024 x 1600)
  hipMemsetAsync(stats, 0, 400 * sizeof(float), stream);
  bn3d_stats_k<<<64, 256, 0, stream>>>(bufB, stats);
  bn_scale_k<<<1, 256, 0, stream>>>(stats, g3, be3, 1.f / 8192.f, ssbuf);
  bn3d_apply_k<<<512, 256, 0, stream>>>(bufB, ssbuf);

  // classifier
  gemm_bias_act<<<dim3(4, BDIM / 64), 256, 0, stream>>>(bufB, Wc1, bc1, h1, BDIM, 256, 1600, 1);
  gemm_bias_act<<<dim3(1, BDIM / 64), 256, 0, stream>>>(h1, Wc2, bc2, h2, BDIM, 32, 256, 1);
  gemm_bias_act<<<dim3(1, BDIM / 64), 256, 0, stream>>>(h2, Wc3, bc3, out, BDIM, 2, 32, 0);
}

// Round 6
// 1267.200 us; speedup vs baseline: 2.1473x; 1.0068x over previous
//
#include <hip/hip_runtime.h>
#include <hip/hip_bf16.h>

// Problem constants
#define BDIM 1024
#define ROI 200
#define DIN 200
#define NSUB 8
#define NROWS (BDIM * ROI)           // 204800
#define XELEMS ((size_t)NROWS * 200) // 40,960,000

typedef __attribute__((ext_vector_type(8))) short short8;
typedef __attribute__((ext_vector_type(4))) float f32x4;

__device__ __constant__ float d_invcnt[8] = {
    1.f/41.f, 1.f/29.f, 1.f/21.f, 1.f/19.f, 1.f/20.f, 1.f/7.f, 1.f/21.f, 1.f/42.f};

__device__ inline unsigned short f2bf_rn(float x) {
  unsigned u = __float_as_uint(x);
  return (unsigned short)((u + 0x7FFFu + ((u >> 16) & 1u)) >> 16);
}

// rs_intra: one wave per row, 4 rows per block
__global__ __launch_bounds__(256) void rowsum4_k(const float* __restrict__ in,
                                                 float* __restrict__ out) {
  int row = blockIdx.x * 4 + (threadIdx.x >> 6);
  int lane = threadIdx.x & 63;
  const float* p = in + (size_t)row * 200;
  float v = p[lane] + p[lane + 64] + p[lane + 128];
  if (lane < 8) v += p[lane + 192];
  #pragma unroll
  for (int off = 32; off > 0; off >>= 1) v += __shfl_down(v, off);
  if (lane == 0) out[row] = v;
}

__global__ __launch_bounds__(256) void intersum_k(const float* __restrict__ in,
                                                  float* __restrict__ out) {
  int i = blockIdx.x * blockDim.x + threadIdx.x;
  if (i >= BDIM * NSUB) return;
  const float* p = in + (size_t)i * 8;
  float v = 0.f;
  #pragma unroll
  for (int c = 0; c < 8; ++c) v += p[c];
  out[i] = v;
}

// Fused seg_mean + block_combine (+ optional BN affine fold).
template<int BN>
__global__ __launch_bounds__(256) void seg_combine_k(
    const float* __restrict__ x, const float* __restrict__ rsI,
    const float* __restrict__ rsP, const float* __restrict__ ss,
    float* __restrict__ y) {
  constexpr int STARTS[8] = {0, 41, 70, 91, 110, 130, 137, 158};
  constexpr int ENDS[8]   = {41, 70, 91, 110, 130, 137, 158, 200};
  int b = blockIdx.x;
  int f = threadIdx.x;
  if (f >= 200) return;
  const float* xb = x + (size_t)b * 200 * 200 + f;
  float sc = 1.f, sh = 0.f;
  if (BN) { sc = ss[f]; sh = ss[200 + f]; }
  float prop[8];
  #pragma unroll
  for (int s = 0; s < 8; ++s) {
    float a = 0.f;
    #pragma unroll 4
    for (int r = STARTS[s]; r < ENDS[s]; ++r) a += xb[(size_t)r * 200];
    a *= d_invcnt[s];
    if (BN) a = a * sc + sh;
    prop[s] = rsP[b * 8 + s] * a;
  }
  const float* rsIb = rsI + b * 200;
  float* yb = y + (size_t)b * 200 * 200 + f;
  #pragma unroll
  for (int s = 0; s < 8; ++s) {
    float pv = prop[s];
    #pragma unroll 4
    for (int r = STARTS[s]; r < ENDS[s]; ++r) {
      float xv = xb[(size_t)r * 200];
      if (BN) xv = xv * sc + sh;
      yb[(size_t)r * 200] = 0.5f * (rsIb[r] * xv + pv);
    }
  }
}

// Weight preconversion into per-colblock fragment-major granule layout for
// mfma_f32_16x16x32_bf16:
// dst[(((half*7 + ks)*NFRAG + frag)*64 + lane)*8 + j]
//   = bf16(W[ks*32 + (lane>>4)*8 + j][half*NFRAG*16 + frag*16 + (lane&15)])
__global__ __launch_bounds__(256) void wconv3_k(const float* __restrict__ W, int K, int N,
                                                int NFRAG, int NB,
                                                unsigned short* __restrict__ dst) {
  int total = NB * 7 * NFRAG * 64 * 8;
  int idx = blockIdx.x * 256 + threadIdx.x;
  if (idx >= total) return;
  int j = idx & 7;
  int lane = (idx >> 3) & 63;
  int rest = idx >> 9;
  int frag = rest % NFRAG;
  int rest2 = rest / NFRAG;
  int ks = rest2 % 7;
  int half = rest2 / 7;
  int k = ks * 32 + ((lane >> 4) << 3) + j;
  int col = half * NFRAG * 16 + frag * 16 + (lane & 15);
  float v = (k < K && col < N) ? W[(size_t)k * N + col] : 0.f;
  dst[idx] = f2bf_rn(v);
}

// W-in-LDS MFMA GEMM: C[M,N] = act(A[M,200] @ W + bias).
// Block = 256 thr = 4 waves x 16 rows = 64 rows; covers NFRAG*16 cols
// (col-block = blockIdx.y). W slice (bf16, fragment-major) staged to LDS once,
// ONE barrier, then 7 K-steps of pure {A global loads + hi/lo split + lane-
// linear ds_read_b128 + 2 MFMAs (ah*w + al*w : exact-A x bf16-W)}.
// Optional fused BN2d column stats via LDS reduce + global atomics.
template<int NFRAG, int ACT, int STATS>
__global__ __launch_bounds__(256) void gemm_lds_k(
    const float* __restrict__ A, const unsigned short* __restrict__ Wf,
    const float* __restrict__ bias, float* __restrict__ C,
    int N, float* __restrict__ stats) {
  constexpr int G = NFRAG * 7 * 64;  // 16B granules in this col-block's slice
  __shared__ unsigned short wlds[G * 8];
  __shared__ float s_sum[NFRAG * 16];
  __shared__ float s_sq[NFRAG * 16];
  int tid = threadIdx.x;
  int lane = tid & 63;
  int wid = tid >> 6;

  // one-time W stage (linear copy; slice is contiguous)
  const unsigned short* wsrc = Wf + (size_t)blockIdx.y * G * 8;
  for (int g = tid; g < G; g += 256) {
    *(int4*)&wlds[(size_t)g * 8] = *(const int4*)&wsrc[(size_t)g * 8];
  }
  if (STATS) {
    if (tid < NFRAG * 16) { s_sum[tid] = 0.f; s_sq[tid] = 0.f; }
  }
  int colbase = blockIdx.y * NFRAG * 16;
  int row0 = blockIdx.x * 64 + wid * 16;
  int m = row0 + (lane & 15);
  const float* arow = A + (size_t)m * 200 + ((lane >> 4) << 3);
  __syncthreads();

  f32x4 acc[NFRAG];
  #pragma unroll
  for (int f = 0; f < NFRAG; ++f) acc[f] = 0.0f;

  float4 pa[2], pb[2];
  pa[0] = *(const float4*)(arow);
  pb[0] = *(const float4*)(arow + 4);
  #pragma unroll
  for (int ks = 0; ks < 7; ++ks) {
    const int cur = ks & 1;
    if (ks < 6) {
      pa[cur ^ 1] = *(const float4*)(arow + (ks + 1) * 32);
      pb[cur ^ 1] = *(const float4*)(arow + (ks + 1) * 32 + 4);
    }
    short8 ah, al;
    {
      float xs[8] = {pa[cur].x, pa[cur].y, pa[cur].z, pa[cur].w,
                     pb[cur].x, pb[cur].y, pb[cur].z, pb[cur].w};
      #pragma unroll
      for (int j = 0; j < 8; ++j) {
        unsigned u = __float_as_uint(xs[j]);
        unsigned r = (u + 0x7FFFu + ((u >> 16) & 1u)) >> 16;
        ah[j] = (short)r;
        float hf = __uint_as_float(r << 16);
        float xl = xs[j] - hf;
        unsigned ul = __float_as_uint(xl);
        al[j] = (short)((ul + 0x7FFFu + ((ul >> 16) & 1u)) >> 16);
      }
    }
    const short8* wp = (const short8*)wlds;
    #pragma unroll
    for (int f = 0; f < NFRAG; ++f) {
      short8 wv = wp[(ks * NFRAG + f) * 64 + lane];
      acc[f] = __builtin_amdgcn_mfma_f32_16x16x32_bf16(ah, wv, acc[f], 0, 0, 0);
      acc[f] = __builtin_amdgcn_mfma_f32_16x16x32_bf16(al, wv, acc[f], 0, 0, 0);
    }
  }

  // epilogue: col = lane&15 (+16f), row = row0 + (lane>>4)*4 + r
  int r0 = (lane >> 4) * 4;
  #pragma unroll
  for (int f = 0; f < NFRAG; ++f) {
    int col = colbase + f * 16 + (lane & 15);
    if (col < N) {
      float b = bias[col];
      float ls = 0.f, lq = 0.f;
      #pragma unroll
      for (int r = 0; r < 4; ++r) {
        int row = row0 + r0 + r;
        float v = acc[f][r] + b;
        if (ACT) v = (v >= 0.f) ? v : 0.2f * v;
        C[(size_t)row * N + col] = v;
        if (STATS) { ls += v; lq += v * v; }
      }
      if (STATS) {
        atomicAdd(&s_sum[col - colbase], ls);
        atomicAdd(&s_sq[col - colbase], lq);
      }
    }
  }
  if (STATS) {
    __syncthreads();
    if (tid < NFRAG * 16) {
      int col = colbase + tid;
      if (col < 200) {
        atomicAdd(&stats[col], s_sum[tid]);
        atomicAdd(&stats[200 + col], s_sq[tid]);
      }
    }
  }
}

// fp32 vector GEMM (tiny GEMMs: W4, classifier)
__global__ __launch_bounds__(256) void gemm_bias_act(
    const float* __restrict__ A, const float* __restrict__ W,
    const float* __restrict__ bias, float* __restrict__ C,
    int M, int N, int K, int act) {
  __shared__ float As[16][64];
  __shared__ float Bs[16][64];
  int tid = threadIdx.x;
  int tx = tid & 15;
  int ty = tid >> 4;
  int row0 = blockIdx.y * 64;
  int col0 = blockIdx.x * 64;
  float acc[4][4] = {{0.f}};

  for (int k0 = 0; k0 < K; k0 += 16) {
    {
      int mm = tid >> 2;
      int kq = (tid & 3) * 4;
      const float* src = A + (size_t)(row0 + mm) * K + k0 + kq;
      if (k0 + 16 <= K) {
        float4 av = *(const float4*)src;
        As[kq + 0][mm] = av.x; As[kq + 1][mm] = av.y;
        As[kq + 2][mm] = av.z; As[kq + 3][mm] = av.w;
      } else {
        #pragma unroll
        for (int j = 0; j < 4; ++j) {
          int kk = k0 + kq + j;
          As[kq + j][mm] = (kk < K) ? src[j] : 0.f;
        }
      }
    }
    {
      int kk = tid >> 4;
      int nq = (tid & 15) * 4;
      const float* src = W + (size_t)(k0 + kk) * N + col0 + nq;
      if (k0 + 16 <= K && col0 + 64 <= N) {
        *(float4*)&Bs[kk][nq] = *(const float4*)src;
      } else {
        #pragma unroll
        for (int j = 0; j < 4; ++j) {
          int n = col0 + nq + j;
          Bs[kk][nq + j] = (k0 + kk < K && n < N) ? src[j] : 0.f;
        }
      }
    }
    __syncthreads();
    #pragma unroll
    for (int k = 0; k < 16; ++k) {
      float4 a = *(const float4*)&As[k][ty * 4];
      float4 bv = *(const float4*)&Bs[k][tx * 4];
      float av[4] = {a.x, a.y, a.z, a.w};
      float bb[4] = {bv.x, bv.y, bv.z, bv.w};
      #pragma unroll
      for (int i = 0; i < 4; ++i)
        #pragma unroll
        for (int j = 0; j < 4; ++j)
          acc[i][j] += av[i] * bb[j];
    }
    __syncthreads();
  }

  #pragma unroll
  for (int i = 0; i < 4; ++i) {
    int r = row0 + ty * 4 + i;
    if (r >= M) continue;
    #pragma unroll
    for (int j = 0; j < 4; ++j) {
      int c = col0 + tx * 4 + j;
      if (c >= N) continue;
      float v = acc[i][j] + bias[c];
      if (act) v = (v >= 0.f) ? v : 0.2f * v;
      C[(size_t)r * N + c] = v;
    }
  }
}

__global__ __launch_bounds__(256) void bn_scale_k(const float* __restrict__ stats,
                                                  const float* __restrict__ g,
                                                  const float* __restrict__ be,
                                                  float invN,
                                                  float* __restrict__ ss) {
  int c = threadIdx.x;
  if (c >= 200) return;
  float m = stats[c] * invN;
  float var = stats[200 + c] * invN - m * m;
  float sc = rsqrtf(var + 1e-5f) * g[c];
  ss[c] = sc;
  ss[200 + c] = be[c] - m * sc;
}

__global__ __launch_bounds__(256) void bn3d_stats_k(const float* __restrict__ x,
                                                    float* __restrict__ stats) {
  int t = threadIdx.x;
  if (t >= 200) return;
  const int bs = BDIM / 64;  // 16
  const float* p = x + (size_t)blockIdx.x * bs * 1600 + t * 8;
  float s = 0.f, q = 0.f;
  for (int b = 0; b < bs; ++b) {
    float4 v0 = *(const float4*)(p + (size_t)b * 1600);
    float4 v1 = *(const float4*)(p + (size_t)b * 1600 + 4);
    s += v0.x + v0.y + v0.z + v0.w + v1.x + v1.y + v1.z + v1.w;
    q += v0.x * v0.x + v0.y * v0.y + v0.z * v0.z + v0.w * v0.w
       + v1.x * v1.x + v1.y * v1.y + v1.z * v1.z + v1.w * v1.w;
  }
  atomicAdd(&stats[t], s);
  atomicAdd(&stats[200 + t], q);
}

__global__ __launch_bounds__(256) void bn3d_apply_k(float* __restrict__ x,
                                                    const float* __restrict__ ss) {
  const size_t nvec = (size_t)BDIM * 1600 / 4;
  size_t stride = (size_t)gridDim.x * blockDim.x;
  for (size_t i = (size_t)blockIdx.x * blockDim.x + threadIdx.x; i < nvec; i += stride) {
    int r = (int)((i >> 1) % 200);
    float4 v = ((float4*)x)[i];
    float sc = ss[r], sh = ss[200 + r];
    v.x = v.x * sc + sh;
    v.y = v.y * sc + sh;
    v.z = v.z * sc + sh;
    v.w = v.w * sc + sh;
    ((float4*)x)[i] = v;
  }
}

extern "C" void kernel_launch(void* const* d_in, const int* in_sizes, int n_in,
                              void* d_out, int out_size, void* d_ws, size_t ws_size,
                              hipStream_t stream) {
  const float* intra = (const float*)d_in[1];
  const float* inter = (const float*)d_in[2];
  const float* nodef = (const float*)d_in[3];
  const float* W0 = (const float*)d_in[4];
  const float* b0 = (const float*)d_in[5];
  const float* W1 = (const float*)d_in[6];
  const float* b1 = (const float*)d_in[7];
  const float* g1 = (const float*)d_in[8];
  const float* be1 = (const float*)d_in[9];
  const float* W2 = (const float*)d_in[10];
  const float* b2 = (const float*)d_in[11];
  const float* g2 = (const float*)d_in[12];
  const float* be2 = (const float*)d_in[13];
  const float* W3 = (const float*)d_in[14];
  const float* b3 = (const float*)d_in[15];
  const float* W4 = (const float*)d_in[16];
  const float* b4 = (const float*)d_in[17];
  const float* g3 = (const float*)d_in[18];
  const float* be3 = (const float*)d_in[19];
  const float* Wc1 = (const float*)d_in[20];
  const float* bc1 = (const float*)d_in[21];
  const float* Wc2 = (const float*)d_in[22];
  const float* bc2 = (const float*)d_in[23];
  const float* Wc3 = (const float*)d_in[24];
  const float* bc3 = (const float*)d_in[25];
  float* out = (float*)d_out;

  float* ws = (float*)d_ws;
  float* bufA = ws;                            // 40,960,000 f
  float* bufB = bufA + XELEMS;                 // 40,960,000 f
  float* rsI  = bufB + XELEMS;                 // 204,800 f
  float* rsP  = rsI + NROWS;                   // 8,192 f
  float* stats = rsP + BDIM * 8;               // 512 f
  float* ssbuf = stats + 512;                  // 512 f
  float* h1 = ssbuf + 512;                     // 262,144 f
  float* h2 = h1 + (size_t)BDIM * 256;         // 32,768 f
  unsigned short* wt = (unsigned short*)(h2 + 32768);
  const size_t W200SZ = 2 * 7 * 7 * 64 * 8;    // 50,176 shorts
  const size_t W64SZ  = 1 * 7 * 4 * 64 * 8;    // 14,336 shorts
  unsigned short* w0f = wt;
  unsigned short* w1f = w0f + W200SZ;
  unsigned short* w2f = w1f + W200SZ;
  unsigned short* w3f = w2f + W200SZ;

  wconv3_k<<<(int)((W200SZ + 255) / 256), 256, 0, stream>>>(W0, 200, 200, 7, 2, w0f);
  wconv3_k<<<(int)((W200SZ + 255) / 256), 256, 0, stream>>>(W1, 200, 200, 7, 2, w1f);
  wconv3_k<<<(int)((W200SZ + 255) / 256), 256, 0, stream>>>(W2, 200, 200, 7, 2, w2f);
  wconv3_k<<<(int)((W64SZ + 255) / 256), 256, 0, stream>>>(W3, 200, 64, 4, 1, w3f);

  // row sums
  rowsum4_k<<<NROWS / 4, 256, 0, stream>>>(intra, rsI);
  intersum_k<<<(BDIM * 8 + 255) / 256, 256, 0, stream>>>(inter, rsP);

  // block 1 (no BN fold): node_features -> bufA
  seg_combine_k<0><<<BDIM, 256, 0, stream>>>(nodef, rsI, rsP, nullptr, bufA);

  // x = leaky(x@W0+b0) @ W1 + b1 ; fused BN stats on W1 output
  gemm_lds_k<7, 1, 0><<<dim3(NROWS / 64, 2), 256, 0, stream>>>(bufA, w0f, b0, bufB, 200, nullptr);
  hipMemsetAsync(stats, 0, 400 * sizeof(float), stream);
  gemm_lds_k<7, 0, 1><<<dim3(NROWS / 64, 2), 256, 0, stream>>>(bufB, w1f, b1, bufA, 200, stats);
  bn_scale_k<<<1, 256, 0, stream>>>(stats, g1, be1, 1.f / (float)NROWS, ssbuf);

  // block 2 with BN1 fold: bufA(raw) -> bufB
  seg_combine_k<1><<<BDIM, 256, 0, stream>>>(bufA, rsI, rsP, ssbuf, bufB);

  // x = leaky(x@W2+b2) ; fused BN stats
  hipMemsetAsync(stats, 0, 400 * sizeof(float), stream);
  gemm_lds_k<7, 1, 1><<<dim3(NROWS / 64, 2), 256, 0, stream>>>(bufB, w2f, b2, bufA, 200, stats);
  bn_scale_k<<<1, 256, 0, stream>>>(stats, g2, be2, 1.f / (float)NROWS, ssbuf);

  // block 3 with BN2 fold: bufA(raw) -> bufB
  seg_combine_k<1><<<BDIM, 256, 0, stream>>>(bufA, rsI, rsP, ssbuf, bufB);

  // x = leaky(x@W3+b3) (MFMA, N=64) ; then leaky(x@W4+b4) (vector)
  gemm_lds_k<4, 1, 0><<<dim3(NROWS / 64, 1), 256, 0, stream>>>(bufB, w3f, b3, bufA, 64, nullptr);
  gemm_bias_act<<<dim3(1, NROWS / 64), 256, 0, stream>>>(bufA, W4, b4, bufB, NROWS, 8, 64, 1);

  // bn3d on bufB (1024 x 1600)
  hipMemsetAsync(stats, 0, 400 * sizeof(float), stream);
  bn3d_stats_k<<<64, 256, 0, stream>>>(bufB, stats);
  bn_scale_k<<<1, 256, 0, stream>>>(stats, g3, be3, 1.f / 8192.f, ssbuf);
  bn3d_apply_k<<<512, 256, 0, stream>>>(bufB, ssbuf);

  // classifier
  gemm_bias_act<<<dim3(4, BDIM / 64), 256, 0, stream>>>(bufB, Wc1, bc1, h1, BDIM, 256, 1600, 1);
  gemm_bias_act<<<dim3(1, BDIM / 64), 256, 0, stream>>>(h1, Wc2, bc2, h2, BDIM, 32, 256, 1);
  gemm_bias_act<<<dim3(1, BDIM / 64), 256, 0, stream>>>(h2, Wc3, bc3, out, BDIM, 2, 32, 0);
}

// Round 7
// 1203.168 us; speedup vs baseline: 2.2616x; 1.0532x over previous
//
#include <hip/hip_runtime.h>
#include <hip/hip_bf16.h>

// Problem constants
#define BDIM 1024
#define ROI 200
#define DIN 200
#define NSUB 8
#define NROWS (BDIM * ROI)           // 204800
#define XELEMS ((size_t)NROWS * 200) // 40,960,000
#define PLPAD 32                     // tail pad (shorts) per plane for k-overrun
#define PLSZ (XELEMS + PLPAD)        // shorts per bf16 plane

typedef __attribute__((ext_vector_type(8))) short short8;
typedef __attribute__((ext_vector_type(4))) float f32x4;

__device__ __constant__ float d_invcnt[8] = {
    1.f/41.f, 1.f/29.f, 1.f/21.f, 1.f/19.f, 1.f/20.f, 1.f/7.f, 1.f/21.f, 1.f/42.f};

__device__ inline unsigned short f2bf_rn(float x) {
  unsigned u = __float_as_uint(x);
  return (unsigned short)((u + 0x7FFFu + ((u >> 16) & 1u)) >> 16);
}
__device__ inline float bf2f(unsigned short h) {
  return __uint_as_float(((unsigned)h) << 16);
}
__device__ inline void split_bf(float v, unsigned short& h, unsigned short& l) {
  unsigned u = __float_as_uint(v);
  unsigned hh = (u + 0x7FFFu + ((u >> 16) & 1u)) >> 16;
  h = (unsigned short)hh;
  float rem = v - __uint_as_float(hh << 16);
  unsigned ul = __float_as_uint(rem);
  l = (unsigned short)((ul + 0x7FFFu + ((ul >> 16) & 1u)) >> 16);
}

// rs_intra: one wave per row, 4 rows per block
__global__ __launch_bounds__(256) void rowsum4_k(const float* __restrict__ in,
                                                 float* __restrict__ out) {
  int row = blockIdx.x * 4 + (threadIdx.x >> 6);
  int lane = threadIdx.x & 63;
  const float* p = in + (size_t)row * 200;
  float v = p[lane] + p[lane + 64] + p[lane + 128];
  if (lane < 8) v += p[lane + 192];
  #pragma unroll
  for (int off = 32; off > 0; off >>= 1) v += __shfl_down(v, off);
  if (lane == 0) out[row] = v;
}

__global__ __launch_bounds__(256) void intersum_k(const float* __restrict__ in,
                                                  float* __restrict__ out) {
  int i = blockIdx.x * blockDim.x + threadIdx.x;
  if (i >= BDIM * NSUB) return;
  const float* p = in + (size_t)i * 8;
  float v = 0.f;
  #pragma unroll
  for (int c = 0; c < 8; ++c) v += p[c];
  out[i] = v;
}

// Fused seg_mean + block_combine (+ optional BN fold). Input either fp32
// (INPL=0) or bf16 hi/lo planes (INPL=1); output bf16 hi/lo planes.
template<int INPL, int BN>
__global__ __launch_bounds__(256) void seg_combine_pl_k(
    const float* __restrict__ xf,
    const unsigned short* __restrict__ xh, const unsigned short* __restrict__ xl,
    const float* __restrict__ rsI, const float* __restrict__ rsP,
    const float* __restrict__ ss,
    unsigned short* __restrict__ yh, unsigned short* __restrict__ yl) {
  constexpr int STARTS[8] = {0, 41, 70, 91, 110, 130, 137, 158};
  constexpr int ENDS[8]   = {41, 70, 91, 110, 130, 137, 158, 200};
  int b = blockIdx.x;
  int f = threadIdx.x;
  if (f >= 200) return;
  size_t base = (size_t)b * 40000 + f;
  float sc = 1.f, sh = 0.f;
  if (BN) { sc = ss[f]; sh = ss[200 + f]; }
  float prop[8];
  #pragma unroll
  for (int s = 0; s < 8; ++s) {
    float a = 0.f;
    #pragma unroll 4
    for (int r = STARTS[s]; r < ENDS[s]; ++r) {
      size_t idx = base + (size_t)r * 200;
      float v = INPL ? (bf2f(xh[idx]) + bf2f(xl[idx])) : xf[idx];
      a += v;
    }
    a *= d_invcnt[s];
    if (BN) a = a * sc + sh;
    prop[s] = rsP[b * 8 + s] * a;
  }
  const float* rsIb = rsI + b * 200;
  #pragma unroll
  for (int s = 0; s < 8; ++s) {
    float pv = prop[s];
    #pragma unroll 4
    for (int r = STARTS[s]; r < ENDS[s]; ++r) {
      size_t idx = base + (size_t)r * 200;
      float v = INPL ? (bf2f(xh[idx]) + bf2f(xl[idx])) : xf[idx];
      if (BN) v = v * sc + sh;
      float res = 0.5f * (rsIb[r] * v + pv);
      unsigned short hh, ll;
      split_bf(res, hh, ll);
      yh[idx] = hh;
      yl[idx] = ll;
    }
  }
}

// Weight preconversion into per-colblock fragment-major granule layout for
// mfma_f32_16x16x32_bf16 (hi bf16 only):
// dst[(((cb*7 + ks)*NFRAG + frag)*64 + lane)*8 + j]
//   = bf16(W[ks*32 + (lane>>4)*8 + j][cb*NFRAG*16 + frag*16 + (lane&15)])
__global__ __launch_bounds__(256) void wconv3_k(const float* __restrict__ W, int K, int N,
                                                int NFRAG, int NB,
                                                unsigned short* __restrict__ dst) {
  int total = NB * 7 * NFRAG * 64 * 8;
  int idx = blockIdx.x * 256 + threadIdx.x;
  if (idx >= total) return;
  int j = idx & 7;
  int lane = (idx >> 3) & 63;
  int rest = idx >> 9;
  int frag = rest % NFRAG;
  int rest2 = rest / NFRAG;
  int ks = rest2 % 7;
  int cb = rest2 / 7;
  int k = ks * 32 + ((lane >> 4) << 3) + j;
  int col = cb * NFRAG * 16 + frag * 16 + (lane & 15);
  float v = (k < K && col < N) ? W[(size_t)k * N + col] : 0.f;
  dst[idx] = f2bf_rn(v);
}

// Upfront-burst MFMA GEMM: C = act(A @ W + bias), A given as bf16 hi/lo
// planes (stride 200 shorts), W bf16 fragment-major staged once to LDS.
// 4 waves x 32 rows = 128 rows/block; NFRAG*16 cols per col-block (grid.y).
// Each wave loads its ENTIRE A strip (28 x 16B) in one burst before the
// K-loop (latency paid once), then pure {ds_read_b128 + 4 MFMA} x 7 steps.
// OUTPL: 0 -> fp32 out (stride N), 1 -> bf16 hi/lo planes (stride 200).
template<int NFRAG, int ACT, int STATS, int OUTPL>
__global__ __launch_bounds__(256, 2) void gemm_reg_k(
    const unsigned short* __restrict__ Ah, const unsigned short* __restrict__ Al,
    const unsigned short* __restrict__ Wf, const float* __restrict__ bias,
    unsigned short* __restrict__ Ch, unsigned short* __restrict__ Cl,
    float* __restrict__ Cf, int N, float* __restrict__ stats) {
  constexpr int G = NFRAG * 7 * 64;  // 16B granules in this col-block's W slice
  __shared__ unsigned short wlds[G * 8];
  __shared__ float s_sum[NFRAG * 16];
  __shared__ float s_sq[NFRAG * 16];
  int tid = threadIdx.x;
  int lane = tid & 63;
  int wid = tid >> 6;

  // one-time W stage (linear copy; slice contiguous)
  const unsigned short* wsrc = Wf + (size_t)blockIdx.y * G * 8;
  for (int g = tid; g < G; g += 256)
    *(int4*)&wlds[(size_t)g * 8] = *(const int4*)&wsrc[(size_t)g * 8];
  if (STATS && tid < NFRAG * 16) { s_sum[tid] = 0.f; s_sq[tid] = 0.f; }

  int row0 = blockIdx.x * 128 + wid * 32;
  int mA = row0 + (lane & 15);
  int kofs = (lane >> 4) * 8;
  const unsigned short* pHA = Ah + (size_t)mA * 200 + kofs;
  const unsigned short* pLA = Al + (size_t)mA * 200 + kofs;
  const unsigned short* pHB = pHA + 16 * 200;
  const unsigned short* pLB = pLA + 16 * 200;

  // upfront A burst: entire K strip for both row-fragments, hi+lo
  short8 ahA[7], alA[7], ahB[7], alB[7];
  #pragma unroll
  for (int i = 0; i < 7; ++i) {
    ahA[i] = *(const short8*)(pHA + i * 32);
    alA[i] = *(const short8*)(pLA + i * 32);
    ahB[i] = *(const short8*)(pHB + i * 32);
    alB[i] = *(const short8*)(pLB + i * 32);
  }
  __builtin_amdgcn_sched_barrier(0);  // keep the burst above everything below
  __syncthreads();                    // W ready (also drains vmcnt)

  f32x4 accA[NFRAG], accB[NFRAG];
  #pragma unroll
  for (int f = 0; f < NFRAG; ++f) { accA[f] = 0.0f; accB[f] = 0.0f; }

  #pragma unroll
  for (int ks = 0; ks < 7; ++ks) {
    const short8* wp = (const short8*)wlds + (size_t)(ks * NFRAG) * 64 + lane;
    #pragma unroll
    for (int f = 0; f < NFRAG; ++f) {
      short8 wv = wp[(size_t)f * 64];
      accA[f] = __builtin_amdgcn_mfma_f32_16x16x32_bf16(ahA[ks], wv, accA[f], 0, 0, 0);
      accA[f] = __builtin_amdgcn_mfma_f32_16x16x32_bf16(alA[ks], wv, accA[f], 0, 0, 0);
      accB[f] = __builtin_amdgcn_mfma_f32_16x16x32_bf16(ahB[ks], wv, accB[f], 0, 0, 0);
      accB[f] = __builtin_amdgcn_mfma_f32_16x16x32_bf16(alB[ks], wv, accB[f], 0, 0, 0);
    }
  }

  // epilogue: col = cb*NFRAG*16 + f*16 + (lane&15); row = row0 + (lane>>4)*4 + r (+16 for B)
  int colbase = blockIdx.y * NFRAG * 16;
  int r0 = (lane >> 4) * 4;
  #pragma unroll
  for (int f = 0; f < NFRAG; ++f) {
    int col = colbase + f * 16 + (lane & 15);
    if (col < N) {
      float b = bias[col];
      float ls = 0.f, lq = 0.f;
      #pragma unroll
      for (int r = 0; r < 4; ++r) {
        int row = row0 + r0 + r;
        float v = accA[f][r] + b;
        if (ACT) v = (v >= 0.f) ? v : 0.2f * v;
        if (OUTPL) {
          unsigned short hh, ll;
          split_bf(v, hh, ll);
          Ch[(size_t)row * 200 + col] = hh;
          Cl[(size_t)row * 200 + col] = ll;
        } else {
          Cf[(size_t)row * N + col] = v;
        }
        if (STATS) { ls += v; lq += v * v; }
      }
      #pragma unroll
      for (int r = 0; r < 4; ++r) {
        int row = row0 + 16 + r0 + r;
        float v = accB[f][r] + b;
        if (ACT) v = (v >= 0.f) ? v : 0.2f * v;
        if (OUTPL) {
          unsigned short hh, ll;
          split_bf(v, hh, ll);
          Ch[(size_t)row * 200 + col] = hh;
          Cl[(size_t)row * 200 + col] = ll;
        } else {
          Cf[(size_t)row * N + col] = v;
        }
        if (STATS) { ls += v; lq += v * v; }
      }
      if (STATS) {
        atomicAdd(&s_sum[f * 16 + (lane & 15)], ls);
        atomicAdd(&s_sq[f * 16 + (lane & 15)], lq);
      }
    }
  }
  if (STATS) {
    __syncthreads();
    if (tid < NFRAG * 16) {
      int col = colbase + tid;
      if (col < 200) {
        atomicAdd(&stats[col], s_sum[tid]);
        atomicAdd(&stats[200 + col], s_sq[tid]);
      }
    }
  }
}

// fp32 vector GEMM (tiny GEMMs: W4, classifier)
__global__ __launch_bounds__(256) void gemm_bias_act(
    const float* __restrict__ A, const float* __restrict__ W,
    const float* __restrict__ bias, float* __restrict__ C,
    int M, int N, int K, int act) {
  __shared__ float As[16][64];
  __shared__ float Bs[16][64];
  int tid = threadIdx.x;
  int tx = tid & 15;
  int ty = tid >> 4;
  int row0 = blockIdx.y * 64;
  int col0 = blockIdx.x * 64;
  float acc[4][4] = {{0.f}};

  for (int k0 = 0; k0 < K; k0 += 16) {
    {
      int mm = tid >> 2;
      int kq = (tid & 3) * 4;
      const float* src = A + (size_t)(row0 + mm) * K + k0 + kq;
      if (k0 + 16 <= K) {
        float4 av = *(const float4*)src;
        As[kq + 0][mm] = av.x; As[kq + 1][mm] = av.y;
        As[kq + 2][mm] = av.z; As[kq + 3][mm] = av.w;
      } else {
        #pragma unroll
        for (int j = 0; j < 4; ++j) {
          int kk = k0 + kq + j;
          As[kq + j][mm] = (kk < K) ? src[j] : 0.f;
        }
      }
    }
    {
      int kk = tid >> 4;
      int nq = (tid & 15) * 4;
      const float* src = W + (size_t)(k0 + kk) * N + col0 + nq;
      if (k0 + 16 <= K && col0 + 64 <= N) {
        *(float4*)&Bs[kk][nq] = *(const float4*)src;
      } else {
        #pragma unroll
        for (int j = 0; j < 4; ++j) {
          int n = col0 + nq + j;
          Bs[kk][nq + j] = (k0 + kk < K && n < N) ? src[j] : 0.f;
        }
      }
    }
    __syncthreads();
    #pragma unroll
    for (int k = 0; k < 16; ++k) {
      float4 a = *(const float4*)&As[k][ty * 4];
      float4 bv = *(const float4*)&Bs[k][tx * 4];
      float av[4] = {a.x, a.y, a.z, a.w};
      float bb[4] = {bv.x, bv.y, bv.z, bv.w};
      #pragma unroll
      for (int i = 0; i < 4; ++i)
        #pragma unroll
        for (int j = 0; j < 4; ++j)
          acc[i][j] += av[i] * bb[j];
    }
    __syncthreads();
  }

  #pragma unroll
  for (int i = 0; i < 4; ++i) {
    int r = row0 + ty * 4 + i;
    if (r >= M) continue;
    #pragma unroll
    for (int j = 0; j < 4; ++j) {
      int c = col0 + tx * 4 + j;
      if (c >= N) continue;
      float v = acc[i][j] + bias[c];
      if (act) v = (v >= 0.f) ? v : 0.2f * v;
      C[(size_t)r * N + c] = v;
    }
  }
}

__global__ __launch_bounds__(256) void bn_scale_k(const float* __restrict__ stats,
                                                  const float* __restrict__ g,
                                                  const float* __restrict__ be,
                                                  float invN,
                                                  float* __restrict__ ss) {
  int c = threadIdx.x;
  if (c >= 200) return;
  float m = stats[c] * invN;
  float var = stats[200 + c] * invN - m * m;
  float sc = rsqrtf(var + 1e-5f) * g[c];
  ss[c] = sc;
  ss[200 + c] = be[c] - m * sc;
}

__global__ __launch_bounds__(256) void bn3d_stats_k(const float* __restrict__ x,
                                                    float* __restrict__ stats) {
  int t = threadIdx.x;
  if (t >= 200) return;
  const int bs = BDIM / 64;  // 16
  const float* p = x + (size_t)blockIdx.x * bs * 1600 + t * 8;
  float s = 0.f, q = 0.f;
  for (int b = 0; b < bs; ++b) {
    float4 v0 = *(const float4*)(p + (size_t)b * 1600);
    float4 v1 = *(const float4*)(p + (size_t)b * 1600 + 4);
    s += v0.x + v0.y + v0.z + v0.w + v1.x + v1.y + v1.z + v1.w;
    q += v0.x * v0.x + v0.y * v0.y + v0.z * v0.z + v0.w * v0.w
       + v1.x * v1.x + v1.y * v1.y + v1.z * v1.z + v1.w * v1.w;
  }
  atomicAdd(&stats[t], s);
  atomicAdd(&stats[200 + t], q);
}

__global__ __launch_bounds__(256) void bn3d_apply_k(float* __restrict__ x,
                                                    const float* __restrict__ ss) {
  const size_t nvec = (size_t)BDIM * 1600 / 4;
  size_t stride = (size_t)gridDim.x * blockDim.x;
  for (size_t i = (size_t)blockIdx.x * blockDim.x + threadIdx.x; i < nvec; i += stride) {
    int r = (int)((i >> 1) % 200);
    float4 v = ((float4*)x)[i];
    float sc = ss[r], sh = ss[200 + r];
    v.x = v.x * sc + sh;
    v.y = v.y * sc + sh;
    v.z = v.z * sc + sh;
    v.w = v.w * sc + sh;
    ((float4*)x)[i] = v;
  }
}

extern "C" void kernel_launch(void* const* d_in, const int* in_sizes, int n_in,
                              void* d_out, int out_size, void* d_ws, size_t ws_size,
                              hipStream_t stream) {
  const float* intra = (const float*)d_in[1];
  const float* inter = (const float*)d_in[2];
  const float* nodef = (const float*)d_in[3];
  const float* W0 = (const float*)d_in[4];
  const float* b0 = (const float*)d_in[5];
  const float* W1 = (const float*)d_in[6];
  const float* b1 = (const float*)d_in[7];
  const float* g1 = (const float*)d_in[8];
  const float* be1 = (const float*)d_in[9];
  const float* W2 = (const float*)d_in[10];
  const float* b2 = (const float*)d_in[11];
  const float* g2 = (const float*)d_in[12];
  const float* be2 = (const float*)d_in[13];
  const float* W3 = (const float*)d_in[14];
  const float* b3 = (const float*)d_in[15];
  const float* W4 = (const float*)d_in[16];
  const float* b4 = (const float*)d_in[17];
  const float* g3 = (const float*)d_in[18];
  const float* be3 = (const float*)d_in[19];
  const float* Wc1 = (const float*)d_in[20];
  const float* bc1 = (const float*)d_in[21];
  const float* Wc2 = (const float*)d_in[22];
  const float* bc2 = (const float*)d_in[23];
  const float* Wc3 = (const float*)d_in[24];
  const float* bc3 = (const float*)d_in[25];
  float* out = (float*)d_out;

  // Layout: 4 bf16 planes (2 ping-pong pairs), then fp32 scratch + weights.
  unsigned short* p0h = (unsigned short*)d_ws;
  unsigned short* p0l = p0h + PLSZ;
  unsigned short* p1h = p0l + PLSZ;
  unsigned short* p1l = p1h + PLSZ;
  float* fbase = (float*)(p1l + PLSZ);
  float* rsI  = fbase;                         // 204,800
  float* rsP  = rsI + NROWS;                   // 8,192
  float* stats = rsP + BDIM * 8;               // 512
  float* ssbuf = stats + 512;                  // 512
  float* h1 = ssbuf + 512;                     // 262,144
  float* h2 = h1 + (size_t)BDIM * 256;         // 32,768
  unsigned short* wt = (unsigned short*)(h2 + 32768);
  const size_t W200SZ = 2 * 7 * 7 * 64 * 8;    // 50,176 shorts
  const size_t W64SZ  = 1 * 7 * 4 * 64 * 8;    // 14,336 shorts
  unsigned short* w0f = wt;
  unsigned short* w1f = w0f + W200SZ;
  unsigned short* w2f = w1f + W200SZ;
  unsigned short* w3f = w2f + W200SZ;
  // aliases over dead plane regions
  float* H3   = (float*)p0h;   // 204800x64 fp32 (52.4 MB < 81.9 MB plane)
  float* bufC = (float*)p1h;   // 204800x8 fp32 (6.5 MB)

  // zero the k-overrun pads (last ks reads up to 24 shorts past row end)
  hipMemsetAsync(p0h + XELEMS, 0, PLPAD * 2, stream);
  hipMemsetAsync(p0l + XELEMS, 0, PLPAD * 2, stream);
  hipMemsetAsync(p1h + XELEMS, 0, PLPAD * 2, stream);
  hipMemsetAsync(p1l + XELEMS, 0, PLPAD * 2, stream);

  wconv3_k<<<(int)((W200SZ + 255) / 256), 256, 0, stream>>>(W0, 200, 200, 7, 2, w0f);
  wconv3_k<<<(int)((W200SZ + 255) / 256), 256, 0, stream>>>(W1, 200, 200, 7, 2, w1f);
  wconv3_k<<<(int)((W200SZ + 255) / 256), 256, 0, stream>>>(W2, 200, 200, 7, 2, w2f);
  wconv3_k<<<(int)((W64SZ + 255) / 256), 256, 0, stream>>>(W3, 200, 64, 4, 1, w3f);

  rowsum4_k<<<NROWS / 4, 256, 0, stream>>>(intra, rsI);
  intersum_k<<<(BDIM * 8 + 255) / 256, 256, 0, stream>>>(inter, rsP);

  // block 1: nodef (fp32) -> X1 planes (P0)
  seg_combine_pl_k<0, 0><<<BDIM, 256, 0, stream>>>(
      nodef, nullptr, nullptr, rsI, rsP, nullptr, p0h, p0l);

  // H = leaky(X1@W0+b0): P0 -> P1
  gemm_reg_k<7, 1, 0, 1><<<dim3(NROWS / 128, 2), 256, 0, stream>>>(
      p0h, p0l, w0f, b0, p1h, p1l, nullptr, 200, nullptr);
  // Y1 = H@W1+b1 (+stats): P1 -> P0
  hipMemsetAsync(stats, 0, 400 * sizeof(float), stream);
  gemm_reg_k<7, 0, 1, 1><<<dim3(NROWS / 128, 2), 256, 0, stream>>>(
      p1h, p1l, w1f, b1, p0h, p0l, nullptr, 200, stats);
  bn_scale_k<<<1, 256, 0, stream>>>(stats, g1, be1, 1.f / (float)NROWS, ssbuf);

  // block 2 (BN1 fold): P0 -> X2 planes (P1)
  seg_combine_pl_k<1, 1><<<BDIM, 256, 0, stream>>>(
      nullptr, p0h, p0l, rsI, rsP, ssbuf, p1h, p1l);

  // Y2 = leaky(X2@W2+b2) (+stats): P1 -> P0
  hipMemsetAsync(stats, 0, 400 * sizeof(float), stream);
  gemm_reg_k<7, 1, 1, 1><<<dim3(NROWS / 128, 2), 256, 0, stream>>>(
      p1h, p1l, w2f, b2, p0h, p0l, nullptr, 200, stats);
  bn_scale_k<<<1, 256, 0, stream>>>(stats, g2, be2, 1.f / (float)NROWS, ssbuf);

  // block 3 (BN2 fold): P0 -> X3 planes (P1)
  seg_combine_pl_k<1, 1><<<BDIM, 256, 0, stream>>>(
      nullptr, p0h, p0l, rsI, rsP, ssbuf, p1h, p1l);

  // H3 = leaky(X3@W3+b3): P1 -> fp32 (aliases P0)
  gemm_reg_k<4, 1, 0, 0><<<dim3(NROWS / 128, 1), 256, 0, stream>>>(
      p1h, p1l, w3f, b3, nullptr, nullptr, H3, 64, nullptr);
  // leaky(H3@W4+b4) -> bufC (aliases P1)
  gemm_bias_act<<<dim3(1, NROWS / 64), 256, 0, stream>>>(H3, W4, b4, bufC, NROWS, 8, 64, 1);

  // bn3d on bufC (1024 x 1600)
  hipMemsetAsync(stats, 0, 400 * sizeof(float), stream);
  bn3d_stats_k<<<64, 256, 0, stream>>>(bufC, stats);
  bn_scale_k<<<1, 256, 0, stream>>>(stats, g3, be3, 1.f / 8192.f, ssbuf);
  bn3d_apply_k<<<512, 256, 0, stream>>>(bufC, ssbuf);

  // classifier
  gemm_bias_act<<<dim3(4, BDIM / 64), 256, 0, stream>>>(bufC, Wc1, bc1, h1, BDIM, 256, 1600, 1);
  gemm_bias_act<<<dim3(1, BDIM / 64), 256, 0, stream>>>(h1, Wc2, bc2, h2, BDIM, 32, 256, 1);
  gemm_bias_act<<<dim3(1, BDIM / 64), 256, 0, stream>>>(h2, Wc3, bc3, out, BDIM, 2, 32, 0);
}

// Round 8
// 788.416 us; speedup vs baseline: 3.4513x; 1.5261x over previous
//
#include <hip/hip_runtime.h>
#include <hip/hip_bf16.h>

// Problem constants
#define BDIM 1024
#define ROI 200
#define DIN 200
#define NSUB 8
#define NROWS (BDIM * ROI)           // 204800
#define XELEMS ((size_t)NROWS * 200) // 40,960,000
#define PLPAD 32                     // tail pad (shorts) per plane for k-overrun
#define PLSZ (XELEMS + PLPAD)        // shorts per bf16 plane

typedef __attribute__((ext_vector_type(8))) short short8;
typedef __attribute__((ext_vector_type(4))) float f32x4;

__device__ __constant__ float d_invcnt[8] = {
    1.f/41.f, 1.f/29.f, 1.f/21.f, 1.f/19.f, 1.f/20.f, 1.f/7.f, 1.f/21.f, 1.f/42.f};

__device__ inline unsigned short f2bf_rn(float x) {
  unsigned u = __float_as_uint(x);
  return (unsigned short)((u + 0x7FFFu + ((u >> 16) & 1u)) >> 16);
}

// rs_intra: one wave per row, 4 rows per block
__global__ __launch_bounds__(256) void rowsum4_k(const float* __restrict__ in,
                                                 float* __restrict__ out) {
  int row = blockIdx.x * 4 + (threadIdx.x >> 6);
  int lane = threadIdx.x & 63;
  const float* p = in + (size_t)row * 200;
  float v = p[lane] + p[lane + 64] + p[lane + 128];
  if (lane < 8) v += p[lane + 192];
  #pragma unroll
  for (int off = 32; off > 0; off >>= 1) v += __shfl_down(v, off);
  if (lane == 0) out[row] = v;
}

__global__ __launch_bounds__(256) void intersum_k(const float* __restrict__ in,
                                                  float* __restrict__ out) {
  int i = blockIdx.x * blockDim.x + threadIdx.x;
  if (i >= BDIM * NSUB) return;
  const float* p = in + (size_t)i * 8;
  float v = 0.f;
  #pragma unroll
  for (int c = 0; c < 8; ++c) v += p[c];
  out[i] = v;
}

// Fused seg_mean + block_combine (+ optional BN fold).
// Input fp32 (INPL=0) or packed bf16 plane (INPL=1); output packed bf16 plane.
// 128 threads; thread t<100 owns cols (2t, 2t+1) of batch blockIdx.x.
template<int INPL, int BN>
__global__ __launch_bounds__(128) void seg_combine_bf_k(
    const float* __restrict__ xf, const unsigned short* __restrict__ xp,
    const float* __restrict__ rsI, const float* __restrict__ rsP,
    const float* __restrict__ ss, unsigned short* __restrict__ yp) {
  constexpr int STARTS[8] = {0, 41, 70, 91, 110, 130, 137, 158};
  constexpr int ENDS[8]   = {41, 70, 91, 110, 130, 137, 158, 200};
  int b = blockIdx.x;
  int t = threadIdx.x;
  if (t >= 100) return;
  int c0 = 2 * t;
  size_t base = (size_t)b * 40000 + c0;
  float sc0 = 1.f, sh0 = 0.f, sc1 = 1.f, sh1 = 0.f;
  if (BN) { sc0 = ss[c0]; sh0 = ss[200 + c0]; sc1 = ss[c0 + 1]; sh1 = ss[200 + c0 + 1]; }
  float pr0[8], pr1[8];
  #pragma unroll
  for (int s = 0; s < 8; ++s) {
    float a0 = 0.f, a1 = 0.f;
    #pragma unroll 4
    for (int r = STARTS[s]; r < ENDS[s]; ++r) {
      size_t idx = base + (size_t)r * 200;
      float v0, v1;
      if (INPL) {
        unsigned u = *(const unsigned*)(xp + idx);
        v0 = __uint_as_float(u << 16);
        v1 = __uint_as_float(u & 0xFFFF0000u);
      } else {
        float2 fv = *(const float2*)(xf + idx);
        v0 = fv.x; v1 = fv.y;
      }
      a0 += v0; a1 += v1;
    }
    a0 *= d_invcnt[s]; a1 *= d_invcnt[s];
    if (BN) { a0 = a0 * sc0 + sh0; a1 = a1 * sc1 + sh1; }
    float rp = rsP[b * 8 + s];
    pr0[s] = rp * a0; pr1[s] = rp * a1;
  }
  const float* rsIb = rsI + b * 200;
  #pragma unroll
  for (int s = 0; s < 8; ++s) {
    float p0 = pr0[s], p1 = pr1[s];
    #pragma unroll 4
    for (int r = STARTS[s]; r < ENDS[s]; ++r) {
      size_t idx = base + (size_t)r * 200;
      float v0, v1;
      if (INPL) {
        unsigned u = *(const unsigned*)(xp + idx);
        v0 = __uint_as_float(u << 16);
        v1 = __uint_as_float(u & 0xFFFF0000u);
      } else {
        float2 fv = *(const float2*)(xf + idx);
        v0 = fv.x; v1 = fv.y;
      }
      if (BN) { v0 = v0 * sc0 + sh0; v1 = v1 * sc1 + sh1; }
      float ri = rsIb[r];
      float y0 = 0.5f * (ri * v0 + p0);
      float y1 = 0.5f * (ri * v1 + p1);
      unsigned o = (unsigned)f2bf_rn(y0) | ((unsigned)f2bf_rn(y1) << 16);
      *(unsigned*)(yp + idx) = o;
    }
  }
}

// Weight preconversion into per-colblock fragment-major granule layout for
// mfma_f32_16x16x32_bf16:
// dst[(((cb*7 + ks)*NFRAG + frag)*64 + lane)*8 + j]
//   = bf16(W[ks*32 + (lane>>4)*8 + j][cb*NFRAG*16 + frag*16 + (lane&15)])
__global__ __launch_bounds__(256) void wconv3_k(const float* __restrict__ W, int K, int N,
                                                int NFRAG, int NB,
                                                unsigned short* __restrict__ dst) {
  int total = NB * 7 * NFRAG * 64 * 8;
  int idx = blockIdx.x * 256 + threadIdx.x;
  if (idx >= total) return;
  int j = idx & 7;
  int lane = (idx >> 3) & 63;
  int rest = idx >> 9;
  int frag = rest % NFRAG;
  int rest2 = rest / NFRAG;
  int ks = rest2 % 7;
  int cb = rest2 / 7;
  int k = ks * 32 + ((lane >> 4) << 3) + j;
  int col = cb * NFRAG * 16 + frag * 16 + (lane & 15);
  float v = (k < K && col < N) ? W[(size_t)k * N + col] : 0.f;
  dst[idx] = f2bf_rn(v);
}

// bf16-plane MFMA GEMM: C = act(A @ W + bias). A = single bf16 plane
// (stride 200), W bf16 fragment-major staged once to LDS (one barrier).
// 4 waves x 32 rows = 128 rows/block; NFRAG*16 cols per col-block (grid.y).
// Wave loads its whole A strip (14 x 16B) upfront; K-loop is pure
// {ds_read_b128 + 2 MFMA}. OUTF32: 0 -> bf16 plane out, 1 -> fp32 (stride N).
template<int NFRAG, int ACT, int STATS, int OUTF32>
__global__ __launch_bounds__(256, 3) void gemm_bf_k(
    const unsigned short* __restrict__ A, const unsigned short* __restrict__ Wf,
    const float* __restrict__ bias, unsigned short* __restrict__ Cp,
    float* __restrict__ Cf, int N, float* __restrict__ stats) {
  constexpr int G = NFRAG * 7 * 64;  // 16B granules in this col-block's W slice
  __shared__ unsigned short wlds[G * 8];
  __shared__ float s_sum[NFRAG * 16];
  __shared__ float s_sq[NFRAG * 16];
  int tid = threadIdx.x;
  int lane = tid & 63;
  int wid = tid >> 6;

  // one-time W stage (linear copy; slice contiguous)
  const unsigned short* wsrc = Wf + (size_t)blockIdx.y * G * 8;
  for (int g = tid; g < G; g += 256)
    *(int4*)&wlds[(size_t)g * 8] = *(const int4*)&wsrc[(size_t)g * 8];
  if (STATS && tid < NFRAG * 16) { s_sum[tid] = 0.f; s_sq[tid] = 0.f; }

  int row0 = blockIdx.x * 128 + wid * 32;
  const unsigned short* pA = A + (size_t)(row0 + (lane & 15)) * 200 + ((lane >> 4) << 3);
  const unsigned short* pB = pA + 16 * 200;

  // upfront A burst: whole K strip, both row-fragments (14 x 16B = 56 VGPR)
  short8 aA[7], aB[7];
  #pragma unroll
  for (int i = 0; i < 7; ++i) {
    aA[i] = *(const short8*)(pA + i * 32);
    aB[i] = *(const short8*)(pB + i * 32);
  }
  __builtin_amdgcn_sched_barrier(0);  // keep the burst above everything below
  __syncthreads();                    // W ready (also drains vmcnt)

  f32x4 accA[NFRAG], accB[NFRAG];
  #pragma unroll
  for (int f = 0; f < NFRAG; ++f) { accA[f] = 0.0f; accB[f] = 0.0f; }

  #pragma unroll
  for (int ks = 0; ks < 7; ++ks) {
    const short8* wp = (const short8*)wlds + (size_t)(ks * NFRAG) * 64 + lane;
    #pragma unroll
    for (int f = 0; f < NFRAG; ++f) {
      short8 wv = wp[(size_t)f * 64];
      accA[f] = __builtin_amdgcn_mfma_f32_16x16x32_bf16(aA[ks], wv, accA[f], 0, 0, 0);
      accB[f] = __builtin_amdgcn_mfma_f32_16x16x32_bf16(aB[ks], wv, accB[f], 0, 0, 0);
    }
  }

  // epilogue: col = cb*NFRAG*16 + f*16 + (lane&15); row = row0 + (lane>>4)*4 + r (+16 for B)
  int colbase = blockIdx.y * NFRAG * 16;
  int r0 = (lane >> 4) * 4;
  #pragma unroll
  for (int f = 0; f < NFRAG; ++f) {
    int col = colbase + f * 16 + (lane & 15);
    if (col < N) {
      float b = bias[col];
      float ls = 0.f, lq = 0.f;
      #pragma unroll
      for (int r = 0; r < 4; ++r) {
        int row = row0 + r0 + r;
        float v = accA[f][r] + b;
        if (ACT) v = (v >= 0.f) ? v : 0.2f * v;
        if (OUTF32) Cf[(size_t)row * N + col] = v;
        else        Cp[(size_t)row * 200 + col] = f2bf_rn(v);
        if (STATS) { ls += v; lq += v * v; }
      }
      #pragma unroll
      for (int r = 0; r < 4; ++r) {
        int row = row0 + 16 + r0 + r;
        float v = accB[f][r] + b;
        if (ACT) v = (v >= 0.f) ? v : 0.2f * v;
        if (OUTF32) Cf[(size_t)row * N + col] = v;
        else        Cp[(size_t)row * 200 + col] = f2bf_rn(v);
        if (STATS) { ls += v; lq += v * v; }
      }
      if (STATS) {
        atomicAdd(&s_sum[f * 16 + (lane & 15)], ls);
        atomicAdd(&s_sq[f * 16 + (lane & 15)], lq);
      }
    }
  }
  if (STATS) {
    __syncthreads();
    if (tid < NFRAG * 16) {
      int col = colbase + tid;
      if (col < 200) {
        atomicAdd(&stats[col], s_sum[tid]);
        atomicAdd(&stats[200 + col], s_sq[tid]);
      }
    }
  }
}

// fp32 vector GEMM (tiny GEMMs: W4, classifier)
__global__ __launch_bounds__(256) void gemm_bias_act(
    const float* __restrict__ A, const float* __restrict__ W,
    const float* __restrict__ bias, float* __restrict__ C,
    int M, int N, int K, int act) {
  __shared__ float As[16][64];
  __shared__ float Bs[16][64];
  int tid = threadIdx.x;
  int tx = tid & 15;
  int ty = tid >> 4;
  int row0 = blockIdx.y * 64;
  int col0 = blockIdx.x * 64;
  float acc[4][4] = {{0.f}};

  for (int k0 = 0; k0 < K; k0 += 16) {
    {
      int mm = tid >> 2;
      int kq = (tid & 3) * 4;
      const float* src = A + (size_t)(row0 + mm) * K + k0 + kq;
      if (k0 + 16 <= K) {
        float4 av = *(const float4*)src;
        As[kq + 0][mm] = av.x; As[kq + 1][mm] = av.y;
        As[kq + 2][mm] = av.z; As[kq + 3][mm] = av.w;
      } else {
        #pragma unroll
        for (int j = 0; j < 4; ++j) {
          int kk = k0 + kq + j;
          As[kq + j][mm] = (kk < K) ? src[j] : 0.f;
        }
      }
    }
    {
      int kk = tid >> 4;
      int nq = (tid & 15) * 4;
      const float* src = W + (size_t)(k0 + kk) * N + col0 + nq;
      if (k0 + 16 <= K && col0 + 64 <= N) {
        *(float4*)&Bs[kk][nq] = *(const float4*)src;
      } else {
        #pragma unroll
        for (int j = 0; j < 4; ++j) {
          int n = col0 + nq + j;
          Bs[kk][nq + j] = (k0 + kk < K && n < N) ? src[j] : 0.f;
        }
      }
    }
    __syncthreads();
    #pragma unroll
    for (int k = 0; k < 16; ++k) {
      float4 a = *(const float4*)&As[k][ty * 4];
      float4 bv = *(const float4*)&Bs[k][tx * 4];
      float av[4] = {a.x, a.y, a.z, a.w};
      float bb[4] = {bv.x, bv.y, bv.z, bv.w};
      #pragma unroll
      for (int i = 0; i < 4; ++i)
        #pragma unroll
        for (int j = 0; j < 4; ++j)
          acc[i][j] += av[i] * bb[j];
    }
    __syncthreads();
  }

  #pragma unroll
  for (int i = 0; i < 4; ++i) {
    int r = row0 + ty * 4 + i;
    if (r >= M) continue;
    #pragma unroll
    for (int j = 0; j < 4; ++j) {
      int c = col0 + tx * 4 + j;
      if (c >= N) continue;
      float v = acc[i][j] + bias[c];
      if (act) v = (v >= 0.f) ? v : 0.2f * v;
      C[(size_t)r * N + c] = v;
    }
  }
}

__global__ __launch_bounds__(256) void bn_scale_k(const float* __restrict__ stats,
                                                  const float* __restrict__ g,
                                                  const float* __restrict__ be,
                                                  float invN,
                                                  float* __restrict__ ss) {
  int c = threadIdx.x;
  if (c >= 200) return;
  float m = stats[c] * invN;
  float var = stats[200 + c] * invN - m * m;
  float sc = rsqrtf(var + 1e-5f) * g[c];
  ss[c] = sc;
  ss[200 + c] = be[c] - m * sc;
}

__global__ __launch_bounds__(256) void bn3d_stats_k(const float* __restrict__ x,
                                                    float* __restrict__ stats) {
  int t = threadIdx.x;
  if (t >= 200) return;
  const int bs = BDIM / 64;  // 16
  const float* p = x + (size_t)blockIdx.x * bs * 1600 + t * 8;
  float s = 0.f, q = 0.f;
  for (int b = 0; b < bs; ++b) {
    float4 v0 = *(const float4*)(p + (size_t)b * 1600);
    float4 v1 = *(const float4*)(p + (size_t)b * 1600 + 4);
    s += v0.x + v0.y + v0.z + v0.w + v1.x + v1.y + v1.z + v1.w;
    q += v0.x * v0.x + v0.y * v0.y + v0.z * v0.z + v0.w * v0.w
       + v1.x * v1.x + v1.y * v1.y + v1.z * v1.z + v1.w * v1.w;
  }
  atomicAdd(&stats[t], s);
  atomicAdd(&stats[200 + t], q);
}

__global__ __launch_bounds__(256) void bn3d_apply_k(float* __restrict__ x,
                                                    const float* __restrict__ ss) {
  const size_t nvec = (size_t)BDIM * 1600 / 4;
  size_t stride = (size_t)gridDim.x * blockDim.x;
  for (size_t i = (size_t)blockIdx.x * blockDim.x + threadIdx.x; i < nvec; i += stride) {
    int r = (int)((i >> 1) % 200);
    float4 v = ((float4*)x)[i];
    float sc = ss[r], sh = ss[200 + r];
    v.x = v.x * sc + sh;
    v.y = v.y * sc + sh;
    v.z = v.z * sc + sh;
    v.w = v.w * sc + sh;
    ((float4*)x)[i] = v;
  }
}

extern "C" void kernel_launch(void* const* d_in, const int* in_sizes, int n_in,
                              void* d_out, int out_size, void* d_ws, size_t ws_size,
                              hipStream_t stream) {
  const float* intra = (const float*)d_in[1];
  const float* inter = (const float*)d_in[2];
  const float* nodef = (const float*)d_in[3];
  const float* W0 = (const float*)d_in[4];
  const float* b0 = (const float*)d_in[5];
  const float* W1 = (const float*)d_in[6];
  const float* b1 = (const float*)d_in[7];
  const float* g1 = (const float*)d_in[8];
  const float* be1 = (const float*)d_in[9];
  const float* W2 = (const float*)d_in[10];
  const float* b2 = (const float*)d_in[11];
  const float* g2 = (const float*)d_in[12];
  const float* be2 = (const float*)d_in[13];
  const float* W3 = (const float*)d_in[14];
  const float* b3 = (const float*)d_in[15];
  const float* W4 = (const float*)d_in[16];
  const float* b4 = (const float*)d_in[17];
  const float* g3 = (const float*)d_in[18];
  const float* be3 = (const float*)d_in[19];
  const float* Wc1 = (const float*)d_in[20];
  const float* bc1 = (const float*)d_in[21];
  const float* Wc2 = (const float*)d_in[22];
  const float* bc2 = (const float*)d_in[23];
  const float* Wc3 = (const float*)d_in[24];
  const float* bc3 = (const float*)d_in[25];
  float* out = (float*)d_out;

  // Layout: 2 bf16 planes (ping-pong), then fp32 scratch + weights.
  unsigned short* P0 = (unsigned short*)d_ws;
  unsigned short* P1 = P0 + PLSZ;
  float* fbase = (float*)(P1 + PLSZ);
  float* rsI  = fbase;                         // 204,800
  float* rsP  = rsI + NROWS;                   // 8,192
  float* stats = rsP + BDIM * 8;               // 512
  float* ssbuf = stats + 512;                  // 512
  float* h1 = ssbuf + 512;                     // 262,144
  float* h2 = h1 + (size_t)BDIM * 256;         // 32,768
  unsigned short* wt = (unsigned short*)(h2 + 32768);
  const size_t W200SZ = 2 * 7 * 7 * 64 * 8;    // 50,176 shorts
  const size_t W64SZ  = 1 * 7 * 4 * 64 * 8;    // 14,336 shorts
  unsigned short* w0f = wt;
  unsigned short* w1f = w0f + W200SZ;
  unsigned short* w2f = w1f + W200SZ;
  unsigned short* w3f = w2f + W200SZ;
  // fp32 aliases over the (dead-at-that-point) P0 plane
  float* H3   = (float*)P0;                    // 204800 x 64 fp32 (52.4 MB)
  float* bufC = H3 + (size_t)NROWS * 64;       // 204800 x 8 fp32 (6.5 MB)

  // zero plane tail pads (last row k-overrun must not read NaN garbage)
  hipMemsetAsync(P0 + XELEMS, 0, PLPAD * 2, stream);
  hipMemsetAsync(P1 + XELEMS, 0, PLPAD * 2, stream);

  wconv3_k<<<(int)((W200SZ + 255) / 256), 256, 0, stream>>>(W0, 200, 200, 7, 2, w0f);
  wconv3_k<<<(int)((W200SZ + 255) / 256), 256, 0, stream>>>(W1, 200, 200, 7, 2, w1f);
  wconv3_k<<<(int)((W200SZ + 255) / 256), 256, 0, stream>>>(W2, 200, 200, 7, 2, w2f);
  wconv3_k<<<(int)((W64SZ + 255) / 256), 256, 0, stream>>>(W3, 200, 64, 4, 1, w3f);

  rowsum4_k<<<NROWS / 4, 256, 0, stream>>>(intra, rsI);
  intersum_k<<<(BDIM * 8 + 255) / 256, 256, 0, stream>>>(inter, rsP);

  // block 1: nodef (fp32) -> X1 (P0)
  seg_combine_bf_k<0, 0><<<BDIM, 128, 0, stream>>>(
      nodef, nullptr, rsI, rsP, nullptr, P0);

  // H = leaky(X1@W0+b0): P0 -> P1
  gemm_bf_k<7, 1, 0, 0><<<dim3(NROWS / 128, 2), 256, 0, stream>>>(
      P0, w0f, b0, P1, nullptr, 200, nullptr);
  // Y1 = H@W1+b1 (+stats): P1 -> P0
  hipMemsetAsync(stats, 0, 400 * sizeof(float), stream);
  gemm_bf_k<7, 0, 1, 0><<<dim3(NROWS / 128, 2), 256, 0, stream>>>(
      P1, w1f, b1, P0, nullptr, 200, stats);
  bn_scale_k<<<1, 256, 0, stream>>>(stats, g1, be1, 1.f / (float)NROWS, ssbuf);

  // block 2 (BN1 fold): P0 -> X2 (P1)
  seg_combine_bf_k<1, 1><<<BDIM, 128, 0, stream>>>(
      nullptr, P0, rsI, rsP, ssbuf, P1);

  // Y2 = leaky(X2@W2+b2) (+stats): P1 -> P0
  hipMemsetAsync(stats, 0, 400 * sizeof(float), stream);
  gemm_bf_k<7, 1, 1, 0><<<dim3(NROWS / 128, 2), 256, 0, stream>>>(
      P1, w2f, b2, P0, nullptr, 200, stats);
  bn_scale_k<<<1, 256, 0, stream>>>(stats, g2, be2, 1.f / (float)NROWS, ssbuf);

  // block 3 (BN2 fold): P0 -> X3 (P1)
  seg_combine_bf_k<1, 1><<<BDIM, 128, 0, stream>>>(
      nullptr, P0, rsI, rsP, ssbuf, P1);

  // H3 = leaky(X3@W3+b3): P1 -> fp32 H3 (aliases P0, which is dead)
  gemm_bf_k<4, 1, 0, 1><<<dim3(NROWS / 128, 1), 256, 0, stream>>>(
      P1, w3f, b3, nullptr, H3, 64, nullptr);
  // leaky(H3@W4+b4) -> bufC
  gemm_bias_act<<<dim3(1, NROWS / 64), 256, 0, stream>>>(H3, W4, b4, bufC, NROWS, 8, 64, 1);

  // bn3d on bufC (1024 x 1600)
  hipMemsetAsync(stats, 0, 400 * sizeof(float), stream);
  bn3d_stats_k<<<64, 256, 0, stream>>>(bufC, stats);
  bn_scale_k<<<1, 256, 0, stream>>>(stats, g3, be3, 1.f / 8192.f, ssbuf);
  bn3d_apply_k<<<512, 256, 0, stream>>>(bufC, ssbuf);

  // classifier
  gemm_bias_act<<<dim3(4, BDIM / 64), 256, 0, stream>>>(bufC, Wc1, bc1, h1, BDIM, 256, 1600, 1);
  gemm_bias_act<<<dim3(1, BDIM / 64), 256, 0, stream>>>(h1, Wc2, bc2, h2, BDIM, 32, 256, 1);
  gemm_bias_act<<<dim3(1, BDIM / 64), 256, 0, stream>>>(h2, Wc3, bc3, out, BDIM, 2, 32, 0);
}

// Round 9
// 781.092 us; speedup vs baseline: 3.4837x; 1.0094x over previous
//
#include <hip/hip_runtime.h>
#include <hip/hip_bf16.h>

// Problem constants
#define BDIM 1024
#define ROI 200
#define DIN 200
#define NSUB 8
#define NROWS (BDIM * ROI)           // 204800
#define XELEMS ((size_t)NROWS * 200) // 40,960,000
#define PLPAD 32                     // tail pad (shorts) per plane for k-overrun
#define PLSZ (XELEMS + PLPAD)        // shorts per bf16 plane

typedef __attribute__((ext_vector_type(8))) short short8;
typedef __attribute__((ext_vector_type(4))) float f32x4;

__device__ __constant__ float d_invcnt[8] = {
    1.f/41.f, 1.f/29.f, 1.f/21.f, 1.f/19.f, 1.f/20.f, 1.f/7.f, 1.f/21.f, 1.f/42.f};

__device__ inline unsigned short f2bf_rn(float x) {
  unsigned u = __float_as_uint(x);
  return (unsigned short)((u + 0x7FFFu + ((u >> 16) & 1u)) >> 16);
}

// rs_intra: one wave per row, 4 rows per block
__global__ __launch_bounds__(256) void rowsum4_k(const float* __restrict__ in,
                                                 float* __restrict__ out) {
  int row = blockIdx.x * 4 + (threadIdx.x >> 6);
  int lane = threadIdx.x & 63;
  const float* p = in + (size_t)row * 200;
  float v = p[lane] + p[lane + 64] + p[lane + 128];
  if (lane < 8) v += p[lane + 192];
  #pragma unroll
  for (int off = 32; off > 0; off >>= 1) v += __shfl_down(v, off);
  if (lane == 0) out[row] = v;
}

__global__ __launch_bounds__(256) void intersum_k(const float* __restrict__ in,
                                                  float* __restrict__ out) {
  int i = blockIdx.x * blockDim.x + threadIdx.x;
  if (i >= BDIM * NSUB) return;
  const float* p = in + (size_t)i * 8;
  float v = 0.f;
  #pragma unroll
  for (int c = 0; c < 8; ++c) v += p[c];
  out[i] = v;
}

// Fused seg_mean + block_combine (+ optional BN fold).
// Input fp32 (INPL=0) or packed bf16 plane (INPL=1); output packed bf16 plane.
// 128 threads; thread t<100 owns cols (2t, 2t+1) of batch blockIdx.x.
template<int INPL, int BN>
__global__ __launch_bounds__(128) void seg_combine_bf_k(
    const float* __restrict__ xf, const unsigned short* __restrict__ xp,
    const float* __restrict__ rsI, const float* __restrict__ rsP,
    const float* __restrict__ ss, unsigned short* __restrict__ yp) {
  constexpr int STARTS[8] = {0, 41, 70, 91, 110, 130, 137, 158};
  constexpr int ENDS[8]   = {41, 70, 91, 110, 130, 137, 158, 200};
  int b = blockIdx.x;
  int t = threadIdx.x;
  if (t >= 100) return;
  int c0 = 2 * t;
  size_t base = (size_t)b * 40000 + c0;
  float sc0 = 1.f, sh0 = 0.f, sc1 = 1.f, sh1 = 0.f;
  if (BN) { sc0 = ss[c0]; sh0 = ss[200 + c0]; sc1 = ss[c0 + 1]; sh1 = ss[200 + c0 + 1]; }
  float pr0[8], pr1[8];
  #pragma unroll
  for (int s = 0; s < 8; ++s) {
    float a0 = 0.f, a1 = 0.f;
    #pragma unroll 4
    for (int r = STARTS[s]; r < ENDS[s]; ++r) {
      size_t idx = base + (size_t)r * 200;
      float v0, v1;
      if (INPL) {
        unsigned u = *(const unsigned*)(xp + idx);
        v0 = __uint_as_float(u << 16);
        v1 = __uint_as_float(u & 0xFFFF0000u);
      } else {
        float2 fv = *(const float2*)(xf + idx);
        v0 = fv.x; v1 = fv.y;
      }
      a0 += v0; a1 += v1;
    }
    a0 *= d_invcnt[s]; a1 *= d_invcnt[s];
    if (BN) { a0 = a0 * sc0 + sh0; a1 = a1 * sc1 + sh1; }
    float rp = rsP[b * 8 + s];
    pr0[s] = rp * a0; pr1[s] = rp * a1;
  }
  const float* rsIb = rsI + b * 200;
  #pragma unroll
  for (int s = 0; s < 8; ++s) {
    float p0 = pr0[s], p1 = pr1[s];
    #pragma unroll 4
    for (int r = STARTS[s]; r < ENDS[s]; ++r) {
      size_t idx = base + (size_t)r * 200;
      float v0, v1;
      if (INPL) {
        unsigned u = *(const unsigned*)(xp + idx);
        v0 = __uint_as_float(u << 16);
        v1 = __uint_as_float(u & 0xFFFF0000u);
      } else {
        float2 fv = *(const float2*)(xf + idx);
        v0 = fv.x; v1 = fv.y;
      }
      if (BN) { v0 = v0 * sc0 + sh0; v1 = v1 * sc1 + sh1; }
      float ri = rsIb[r];
      float y0 = 0.5f * (ri * v0 + p0);
      float y1 = 0.5f * (ri * v1 + p1);
      unsigned o = (unsigned)f2bf_rn(y0) | ((unsigned)f2bf_rn(y1) << 16);
      *(unsigned*)(yp + idx) = o;
    }
  }
}

// Weight preconversion into per-colblock fragment-major granule layout for
// mfma_f32_16x16x32_bf16:
// dst[((((cb*KSTEPS)+ks)*NFRAG + frag)*64 + lane)*8 + j]
//   = bf16(W[ks*32 + (lane>>4)*8 + j][cb*NFRAG*16 + frag*16 + (lane&15)])
__global__ __launch_bounds__(256) void wconv3_k(const float* __restrict__ W, int K, int N,
                                                int NFRAG, int NB, int KSTEPS,
                                                unsigned short* __restrict__ dst) {
  int total = NB * KSTEPS * NFRAG * 64 * 8;
  int idx = blockIdx.x * 256 + threadIdx.x;
  if (idx >= total) return;
  int j = idx & 7;
  int lane = (idx >> 3) & 63;
  int rest = idx >> 9;
  int frag = rest % NFRAG;
  int rest2 = rest / NFRAG;
  int ks = rest2 % KSTEPS;
  int cb = rest2 / KSTEPS;
  int k = ks * 32 + ((lane >> 4) << 3) + j;
  int col = cb * NFRAG * 16 + frag * 16 + (lane & 15);
  float v = (k < K && col < N) ? W[(size_t)k * N + col] : 0.f;
  dst[idx] = f2bf_rn(v);
}

// bf16-plane MFMA GEMM: C = act(A @ W + bias). A = single bf16 plane
// (stride 200), W bf16 fragment-major staged once to LDS (one barrier).
// 4 waves x 32 rows = 128 rows/block; NFRAG*16 cols per col-block (grid.y).
// Wave loads its whole A strip (14 x 16B) upfront; K-loop is pure
// {ds_read_b128 + 2 MFMA}. Output: packed bf16 plane.
template<int NFRAG, int ACT, int STATS>
__global__ __launch_bounds__(256, 3) void gemm_bf_k(
    const unsigned short* __restrict__ A, const unsigned short* __restrict__ Wf,
    const float* __restrict__ bias, unsigned short* __restrict__ Cp,
    int N, float* __restrict__ stats) {
  constexpr int G = NFRAG * 7 * 64;  // 16B granules in this col-block's W slice
  __shared__ unsigned short wlds[G * 8];
  __shared__ float s_sum[NFRAG * 16];
  __shared__ float s_sq[NFRAG * 16];
  int tid = threadIdx.x;
  int lane = tid & 63;
  int wid = tid >> 6;

  // one-time W stage (linear copy; slice contiguous)
  const unsigned short* wsrc = Wf + (size_t)blockIdx.y * G * 8;
  for (int g = tid; g < G; g += 256)
    *(int4*)&wlds[(size_t)g * 8] = *(const int4*)&wsrc[(size_t)g * 8];
  if (STATS && tid < NFRAG * 16) { s_sum[tid] = 0.f; s_sq[tid] = 0.f; }

  int row0 = blockIdx.x * 128 + wid * 32;
  const unsigned short* pA = A + (size_t)(row0 + (lane & 15)) * 200 + ((lane >> 4) << 3);
  const unsigned short* pB = pA + 16 * 200;

  // upfront A burst: whole K strip, both row-fragments (14 x 16B = 56 VGPR)
  short8 aA[7], aB[7];
  #pragma unroll
  for (int i = 0; i < 7; ++i) {
    aA[i] = *(const short8*)(pA + i * 32);
    aB[i] = *(const short8*)(pB + i * 32);
  }
  __builtin_amdgcn_sched_barrier(0);  // keep the burst above everything below
  __syncthreads();                    // W ready (also drains vmcnt)

  f32x4 accA[NFRAG], accB[NFRAG];
  #pragma unroll
  for (int f = 0; f < NFRAG; ++f) { accA[f] = 0.0f; accB[f] = 0.0f; }

  #pragma unroll
  for (int ks = 0; ks < 7; ++ks) {
    const short8* wp = (const short8*)wlds + (size_t)(ks * NFRAG) * 64 + lane;
    #pragma unroll
    for (int f = 0; f < NFRAG; ++f) {
      short8 wv = wp[(size_t)f * 64];
      accA[f] = __builtin_amdgcn_mfma_f32_16x16x32_bf16(aA[ks], wv, accA[f], 0, 0, 0);
      accB[f] = __builtin_amdgcn_mfma_f32_16x16x32_bf16(aB[ks], wv, accB[f], 0, 0, 0);
    }
  }

  // epilogue: col = cb*NFRAG*16 + f*16 + (lane&15); row = row0 + (lane>>4)*4 + r (+16 for B)
  int colbase = blockIdx.y * NFRAG * 16;
  int r0 = (lane >> 4) * 4;
  #pragma unroll
  for (int f = 0; f < NFRAG; ++f) {
    int col = colbase + f * 16 + (lane & 15);
    if (col < N) {
      float b = bias[col];
      float ls = 0.f, lq = 0.f;
      #pragma unroll
      for (int r = 0; r < 4; ++r) {
        int row = row0 + r0 + r;
        float v = accA[f][r] + b;
        if (ACT) v = (v >= 0.f) ? v : 0.2f * v;
        Cp[(size_t)row * 200 + col] = f2bf_rn(v);
        if (STATS) { ls += v; lq += v * v; }
      }
      #pragma unroll
      for (int r = 0; r < 4; ++r) {
        int row = row0 + 16 + r0 + r;
        float v = accB[f][r] + b;
        if (ACT) v = (v >= 0.f) ? v : 0.2f * v;
        Cp[(size_t)row * 200 + col] = f2bf_rn(v);
        if (STATS) { ls += v; lq += v * v; }
      }
      if (STATS) {
        atomicAdd(&s_sum[f * 16 + (lane & 15)], ls);
        atomicAdd(&s_sq[f * 16 + (lane & 15)], lq);
      }
    }
  }
  if (STATS) {
    __syncthreads();
    if (tid < NFRAG * 16) {
      int col = colbase + tid;
      if (col < 200) {
        atomicAdd(&stats[col], s_sum[tid]);
        atomicAdd(&stats[200 + col], s_sq[tid]);
      }
    }
  }
}

// Fused W3+W4: bufC = leaky(leaky(X3@W3+b3)@W4+b4). X3 = bf16 plane.
// H3 (128x64) lives only in LDS (padded stride 72 shorts, wave-local
// write->read, no barrier). Second MFMA K=64 (2 k-steps) with W4 fragment.
__global__ __launch_bounds__(256, 3) void gemm_w34_k(
    const unsigned short* __restrict__ A, const unsigned short* __restrict__ W3f,
    const unsigned short* __restrict__ W4f, const float* __restrict__ b3,
    const float* __restrict__ b4, float* __restrict__ C) {
  __shared__ unsigned short w3lds[7 * 4 * 64 * 8];   // 28 KB
  __shared__ unsigned short w4lds[2 * 64 * 8];       // 2 KB
  __shared__ unsigned short h3buf[128][72];          // 18 KB (padded: 144B rows)
  int tid = threadIdx.x;
  int lane = tid & 63;
  int wid = tid >> 6;

  for (int g = tid; g < 7 * 4 * 64; g += 256)
    *(int4*)&w3lds[(size_t)g * 8] = *(const int4*)&W3f[(size_t)g * 8];
  if (tid < 128)
    *(int4*)&w4lds[(size_t)tid * 8] = *(const int4*)&W4f[(size_t)tid * 8];

  int row0 = blockIdx.x * 128 + wid * 32;
  const unsigned short* pA = A + (size_t)(row0 + (lane & 15)) * 200 + ((lane >> 4) << 3);
  const unsigned short* pB = pA + 16 * 200;
  short8 aA[7], aB[7];
  #pragma unroll
  for (int i = 0; i < 7; ++i) {
    aA[i] = *(const short8*)(pA + i * 32);
    aB[i] = *(const short8*)(pB + i * 32);
  }
  __builtin_amdgcn_sched_barrier(0);
  __syncthreads();

  f32x4 accA[4], accB[4];
  #pragma unroll
  for (int f = 0; f < 4; ++f) { accA[f] = 0.0f; accB[f] = 0.0f; }
  #pragma unroll
  for (int ks = 0; ks < 7; ++ks) {
    const short8* wp = (const short8*)w3lds + (size_t)(ks * 4) * 64 + lane;
    #pragma unroll
    for (int f = 0; f < 4; ++f) {
      short8 wv = wp[(size_t)f * 64];
      accA[f] = __builtin_amdgcn_mfma_f32_16x16x32_bf16(aA[ks], wv, accA[f], 0, 0, 0);
      accB[f] = __builtin_amdgcn_mfma_f32_16x16x32_bf16(aB[ks], wv, accB[f], 0, 0, 0);
    }
  }

  // H3 -> LDS (leaky + b3), wave-local rows wid*32..wid*32+31
  int r0 = (lane >> 4) * 4;
  #pragma unroll
  for (int f = 0; f < 4; ++f) {
    int col = f * 16 + (lane & 15);
    float bb = b3[col];
    #pragma unroll
    for (int r = 0; r < 4; ++r) {
      float v = accA[f][r] + bb;
      v = (v >= 0.f) ? v : 0.2f * v;
      h3buf[wid * 32 + r0 + r][col] = f2bf_rn(v);
      v = accB[f][r] + bb;
      v = (v >= 0.f) ? v : 0.2f * v;
      h3buf[wid * 32 + 16 + r0 + r][col] = f2bf_rn(v);
    }
  }
  // wave-local LDS write->read: compiler inserts lgkmcnt; no barrier needed.
  f32x4 acc2A = 0.0f, acc2B = 0.0f;
  #pragma unroll
  for (int ks = 0; ks < 2; ++ks) {
    short8 a2A = *(const short8*)&h3buf[wid * 32 + (lane & 15)][ks * 32 + ((lane >> 4) << 3)];
    short8 a2B = *(const short8*)&h3buf[wid * 32 + 16 + (lane & 15)][ks * 32 + ((lane >> 4) << 3)];
    short8 wv = *(const short8*)&w4lds[(size_t)(ks * 64 + lane) * 8];
    acc2A = __builtin_amdgcn_mfma_f32_16x16x32_bf16(a2A, wv, acc2A, 0, 0, 0);
    acc2B = __builtin_amdgcn_mfma_f32_16x16x32_bf16(a2B, wv, acc2B, 0, 0, 0);
  }
  int col = lane & 15;
  if (col < 8) {
    float bb = b4[col];
    #pragma unroll
    for (int r = 0; r < 4; ++r) {
      int row = row0 + r0 + r;
      float v = acc2A[r] + bb;
      v = (v >= 0.f) ? v : 0.2f * v;
      C[(size_t)row * 8 + col] = v;
      v = acc2B[r] + bb;
      v = (v >= 0.f) ? v : 0.2f * v;
      C[(size_t)(row + 16) * 8 + col] = v;
    }
  }
}

__global__ __launch_bounds__(256) void bn_scale_k(const float* __restrict__ stats,
                                                  const float* __restrict__ g,
                                                  const float* __restrict__ be,
                                                  float invN,
                                                  float* __restrict__ ss) {
  int c = threadIdx.x;
  if (c >= 200) return;
  float m = stats[c] * invN;
  float var = stats[200 + c] * invN - m * m;
  float sc = rsqrtf(var + 1e-5f) * g[c];
  ss[c] = sc;
  ss[200 + c] = be[c] - m * sc;
}

__global__ __launch_bounds__(256) void bn3d_stats_k(const float* __restrict__ x,
                                                    float* __restrict__ stats) {
  int t = threadIdx.x;
  if (t >= 200) return;
  const int bs = BDIM / 64;  // 16
  const float* p = x + (size_t)blockIdx.x * bs * 1600 + t * 8;
  float s = 0.f, q = 0.f;
  for (int b = 0; b < bs; ++b) {
    float4 v0 = *(const float4*)(p + (size_t)b * 1600);
    float4 v1 = *(const float4*)(p + (size_t)b * 1600 + 4);
    s += v0.x + v0.y + v0.z + v0.w + v1.x + v1.y + v1.z + v1.w;
    q += v0.x * v0.x + v0.y * v0.y + v0.z * v0.z + v0.w * v0.w
       + v1.x * v1.x + v1.y * v1.y + v1.z * v1.z + v1.w * v1.w;
  }
  atomicAdd(&stats[t], s);
  atomicAdd(&stats[200 + t], q);
}

// Fused classifier: out = leaky(leaky(xhat@Wc1+bc1)@Wc2+bc2)@Wc3+bc3,
// xhat = bn3d affine of bufC. 8 batch rows per block, 128 blocks.
__global__ __launch_bounds__(256) void classifier_k(
    const float* __restrict__ x, const float* __restrict__ ss,
    const float* __restrict__ Wc1, const float* __restrict__ bc1,
    const float* __restrict__ Wc2, const float* __restrict__ bc2,
    const float* __restrict__ Wc3, const float* __restrict__ bc3,
    float* __restrict__ out) {
  __shared__ float xs[8][1600];
  __shared__ float h1s[8][256];
  __shared__ float h2s[8][32];
  int t = threadIdx.x;
  int b0 = blockIdx.x * 8;
  // load + bn3d affine (r = k>>3; float4 stays within one r)
  for (int i = t; i < 3200; i += 256) {
    int j = i / 400;
    int kq = (i - j * 400) * 4;
    int r = kq >> 3;
    float4 v = *(const float4*)(x + (size_t)(b0 + j) * 1600 + kq);
    float sc = ss[r], sh = ss[200 + r];
    v.x = v.x * sc + sh; v.y = v.y * sc + sh;
    v.z = v.z * sc + sh; v.w = v.w * sc + sh;
    *(float4*)&xs[j][kq] = v;
  }
  __syncthreads();
  float acc[8];
  #pragma unroll
  for (int j = 0; j < 8; ++j) acc[j] = 0.f;
  #pragma unroll 4
  for (int k = 0; k < 1600; ++k) {
    float wv = Wc1[(size_t)k * 256 + t];
    #pragma unroll
    for (int j = 0; j < 8; ++j) acc[j] += xs[j][k] * wv;
  }
  #pragma unroll
  for (int j = 0; j < 8; ++j) {
    float v = acc[j] + bc1[t];
    h1s[j][t] = (v >= 0.f) ? v : 0.2f * v;
  }
  __syncthreads();
  {
    int j = t >> 5, c = t & 31;
    float a = 0.f;
    #pragma unroll 4
    for (int k = 0; k < 256; ++k) a += h1s[j][k] * Wc2[k * 32 + c];
    float v = a + bc2[c];
    h2s[j][c] = (v >= 0.f) ? v : 0.2f * v;
  }
  __syncthreads();
  if (t < 16) {
    int j = t >> 1, c = t & 1;
    float a = 0.f;
    #pragma unroll
    for (int k = 0; k < 32; ++k) a += h2s[j][k] * Wc3[k * 2 + c];
    out[(size_t)(b0 + j) * 2 + c] = a + bc3[c];
  }
}

extern "C" void kernel_launch(void* const* d_in, const int* in_sizes, int n_in,
                              void* d_out, int out_size, void* d_ws, size_t ws_size,
                              hipStream_t stream) {
  const float* intra = (const float*)d_in[1];
  const float* inter = (const float*)d_in[2];
  const float* nodef = (const float*)d_in[3];
  const float* W0 = (const float*)d_in[4];
  const float* b0 = (const float*)d_in[5];
  const float* W1 = (const float*)d_in[6];
  const float* b1 = (const float*)d_in[7];
  const float* g1 = (const float*)d_in[8];
  const float* be1 = (const float*)d_in[9];
  const float* W2 = (const float*)d_in[10];
  const float* b2 = (const float*)d_in[11];
  const float* g2 = (const float*)d_in[12];
  const float* be2 = (const float*)d_in[13];
  const float* W3 = (const float*)d_in[14];
  const float* b3 = (const float*)d_in[15];
  const float* W4 = (const float*)d_in[16];
  const float* b4 = (const float*)d_in[17];
  const float* g3 = (const float*)d_in[18];
  const float* be3 = (const float*)d_in[19];
  const float* Wc1 = (const float*)d_in[20];
  const float* bc1 = (const float*)d_in[21];
  const float* Wc2 = (const float*)d_in[22];
  const float* bc2 = (const float*)d_in[23];
  const float* Wc3 = (const float*)d_in[24];
  const float* bc3 = (const float*)d_in[25];
  float* out = (float*)d_out;

  // Layout: 2 bf16 planes (ping-pong), then fp32 scratch + weights.
  unsigned short* P0 = (unsigned short*)d_ws;
  unsigned short* P1 = P0 + PLSZ;
  float* fbase = (float*)(P1 + PLSZ);
  float* rsI  = fbase;                         // 204,800
  float* rsP  = rsI + NROWS;                   // 8,192
  float* stats = rsP + BDIM * 8;               // 512
  float* ssbuf = stats + 512;                  // 512
  unsigned short* wt = (unsigned short*)(ssbuf + 512);
  const size_t W200SZ = 2 * 7 * 7 * 64 * 8;    // 50,176 shorts
  const size_t W3SZ   = 1 * 7 * 4 * 64 * 8;    // 14,336 shorts
  const size_t W4SZ   = 1 * 2 * 1 * 64 * 8;    // 1,024 shorts
  unsigned short* w0f = wt;
  unsigned short* w1f = w0f + W200SZ;
  unsigned short* w2f = w1f + W200SZ;
  unsigned short* w3f = w2f + W200SZ;
  unsigned short* w4f = w3f + W3SZ;
  // fp32 alias over the (dead-at-that-point) P0 plane
  float* bufC = (float*)P0;                    // 204800 x 8 fp32 (6.5 MB)

  // zero plane tail pads (last row k-overrun must not read NaN garbage)
  hipMemsetAsync(P0 + XELEMS, 0, PLPAD * 2, stream);
  hipMemsetAsync(P1 + XELEMS, 0, PLPAD * 2, stream);

  wconv3_k<<<(int)((W200SZ + 255) / 256), 256, 0, stream>>>(W0, 200, 200, 7, 2, 7, w0f);
  wconv3_k<<<(int)((W200SZ + 255) / 256), 256, 0, stream>>>(W1, 200, 200, 7, 2, 7, w1f);
  wconv3_k<<<(int)((W200SZ + 255) / 256), 256, 0, stream>>>(W2, 200, 200, 7, 2, 7, w2f);
  wconv3_k<<<(int)((W3SZ + 255) / 256), 256, 0, stream>>>(W3, 200, 64, 4, 1, 7, w3f);
  wconv3_k<<<(int)((W4SZ + 255) / 256), 256, 0, stream>>>(W4, 64, 8, 1, 1, 2, w4f);

  rowsum4_k<<<NROWS / 4, 256, 0, stream>>>(intra, rsI);
  intersum_k<<<(BDIM * 8 + 255) / 256, 256, 0, stream>>>(inter, rsP);

  // block 1: nodef (fp32) -> X1 (P0)
  seg_combine_bf_k<0, 0><<<BDIM, 128, 0, stream>>>(
      nodef, nullptr, rsI, rsP, nullptr, P0);

  // H = leaky(X1@W0+b0): P0 -> P1
  gemm_bf_k<7, 1, 0><<<dim3(NROWS / 128, 2), 256, 0, stream>>>(
      P0, w0f, b0, P1, 200, nullptr);
  // Y1 = H@W1+b1 (+stats): P1 -> P0
  hipMemsetAsync(stats, 0, 400 * sizeof(float), stream);
  gemm_bf_k<7, 0, 1><<<dim3(NROWS / 128, 2), 256, 0, stream>>>(
      P1, w1f, b1, P0, 200, stats);
  bn_scale_k<<<1, 256, 0, stream>>>(stats, g1, be1, 1.f / (float)NROWS, ssbuf);

  // block 2 (BN1 fold): P0 -> X2 (P1)
  seg_combine_bf_k<1, 1><<<BDIM, 128, 0, stream>>>(
      nullptr, P0, rsI, rsP, ssbuf, P1);

  // Y2 = leaky(X2@W2+b2) (+stats): P1 -> P0
  hipMemsetAsync(stats, 0, 400 * sizeof(float), stream);
  gemm_bf_k<7, 1, 1><<<dim3(NROWS / 128, 2), 256, 0, stream>>>(
      P1, w2f, b2, P0, 200, stats);
  bn_scale_k<<<1, 256, 0, stream>>>(stats, g2, be2, 1.f / (float)NROWS, ssbuf);

  // block 3 (BN2 fold): P0 -> X3 (P1)
  seg_combine_bf_k<1, 1><<<BDIM, 128, 0, stream>>>(
      nullptr, P0, rsI, rsP, ssbuf, P1);

  // bufC = leaky(leaky(X3@W3+b3)@W4+b4): P1 -> bufC (aliases P0, dead)
  gemm_w34_k<<<NROWS / 128, 256, 0, stream>>>(P1, w3f, w4f, b3, b4, bufC);

  // bn3d stats on raw bufC, then affine folded into classifier load
  hipMemsetAsync(stats, 0, 400 * sizeof(float), stream);
  bn3d_stats_k<<<64, 256, 0, stream>>>(bufC, stats);
  bn_scale_k<<<1, 256, 0, stream>>>(stats, g3, be3, 1.f / 8192.f, ssbuf);

  // fused classifier (+bn3d apply): bufC -> out
  classifier_k<<<BDIM / 8, 256, 0, stream>>>(
      bufC, ssbuf, Wc1, bc1, Wc2, bc2, Wc3, bc3, out);
}

// Round 10
// 627.186 us; speedup vs baseline: 4.3385x; 1.2454x over previous
//
#include <hip/hip_runtime.h>
#include <hip/hip_bf16.h>

// Problem constants
#define BDIM 1024
#define ROI 200
#define DIN 200
#define NSUB 8
#define NROWS (BDIM * ROI)           // 204800
#define XELEMS ((size_t)NROWS * 200) // 40,960,000
#define PLPAD 32                     // tail pad (shorts) per plane for k-overrun
#define PLSZ (XELEMS + PLPAD)        // shorts per bf16 plane

typedef __attribute__((ext_vector_type(8))) short short8;
typedef __attribute__((ext_vector_type(4))) float f32x4;

__device__ __constant__ float d_invcnt[8] = {
    1.f/41.f, 1.f/29.f, 1.f/21.f, 1.f/19.f, 1.f/20.f, 1.f/7.f, 1.f/21.f, 1.f/42.f};

__device__ inline unsigned short f2bf_rn(float x) {
  unsigned u = __float_as_uint(x);
  return (unsigned short)((u + 0x7FFFu + ((u >> 16) & 1u)) >> 16);
}

// rs_intra: one wave per row, 4 rows per block
__global__ __launch_bounds__(256) void rowsum4_k(const float* __restrict__ in,
                                                 float* __restrict__ out) {
  int row = blockIdx.x * 4 + (threadIdx.x >> 6);
  int lane = threadIdx.x & 63;
  const float* p = in + (size_t)row * 200;
  float v = p[lane] + p[lane + 64] + p[lane + 128];
  if (lane < 8) v += p[lane + 192];
  #pragma unroll
  for (int off = 32; off > 0; off >>= 1) v += __shfl_down(v, off);
  if (lane == 0) out[row] = v;
}

__global__ __launch_bounds__(256) void intersum_k(const float* __restrict__ in,
                                                  float* __restrict__ out) {
  int i = blockIdx.x * blockDim.x + threadIdx.x;
  if (i >= BDIM * NSUB) return;
  const float* p = in + (size_t)i * 8;
  float v = 0.f;
  #pragma unroll
  for (int c = 0; c < 8; ++c) v += p[c];
  out[i] = v;
}

// Fused seg_mean + block_combine (+ optional BN fold).
// Input fp32 (INPL=0) or packed bf16 plane (INPL=1); output packed bf16 plane.
// 128 threads; thread t<100 owns cols (2t, 2t+1) of batch blockIdx.x.
template<int INPL, int BN>
__global__ __launch_bounds__(128) void seg_combine_bf_k(
    const float* __restrict__ xf, const unsigned short* __restrict__ xp,
    const float* __restrict__ rsI, const float* __restrict__ rsP,
    const float* __restrict__ ss, unsigned short* __restrict__ yp) {
  constexpr int STARTS[8] = {0, 41, 70, 91, 110, 130, 137, 158};
  constexpr int ENDS[8]   = {41, 70, 91, 110, 130, 137, 158, 200};
  int b = blockIdx.x;
  int t = threadIdx.x;
  if (t >= 100) return;
  int c0 = 2 * t;
  size_t base = (size_t)b * 40000 + c0;
  float sc0 = 1.f, sh0 = 0.f, sc1 = 1.f, sh1 = 0.f;
  if (BN) { sc0 = ss[c0]; sh0 = ss[200 + c0]; sc1 = ss[c0 + 1]; sh1 = ss[200 + c0 + 1]; }
  float pr0[8], pr1[8];
  #pragma unroll
  for (int s = 0; s < 8; ++s) {
    float a0 = 0.f, a1 = 0.f;
    #pragma unroll 4
    for (int r = STARTS[s]; r < ENDS[s]; ++r) {
      size_t idx = base + (size_t)r * 200;
      float v0, v1;
      if (INPL) {
        unsigned u = *(const unsigned*)(xp + idx);
        v0 = __uint_as_float(u << 16);
        v1 = __uint_as_float(u & 0xFFFF0000u);
      } else {
        float2 fv = *(const float2*)(xf + idx);
        v0 = fv.x; v1 = fv.y;
      }
      a0 += v0; a1 += v1;
    }
    a0 *= d_invcnt[s]; a1 *= d_invcnt[s];
    if (BN) { a0 = a0 * sc0 + sh0; a1 = a1 * sc1 + sh1; }
    float rp = rsP[b * 8 + s];
    pr0[s] = rp * a0; pr1[s] = rp * a1;
  }
  const float* rsIb = rsI + b * 200;
  #pragma unroll
  for (int s = 0; s < 8; ++s) {
    float p0 = pr0[s], p1 = pr1[s];
    #pragma unroll 4
    for (int r = STARTS[s]; r < ENDS[s]; ++r) {
      size_t idx = base + (size_t)r * 200;
      float v0, v1;
      if (INPL) {
        unsigned u = *(const unsigned*)(xp + idx);
        v0 = __uint_as_float(u << 16);
        v1 = __uint_as_float(u & 0xFFFF0000u);
      } else {
        float2 fv = *(const float2*)(xf + idx);
        v0 = fv.x; v1 = fv.y;
      }
      if (BN) { v0 = v0 * sc0 + sh0; v1 = v1 * sc1 + sh1; }
      float ri = rsIb[r];
      float y0 = 0.5f * (ri * v0 + p0);
      float y1 = 0.5f * (ri * v1 + p1);
      unsigned o = (unsigned)f2bf_rn(y0) | ((unsigned)f2bf_rn(y1) << 16);
      *(unsigned*)(yp + idx) = o;
    }
  }
}

// Weight preconversion into per-colblock fragment-major granule layout for
// mfma_f32_16x16x32_bf16:
// dst[((((cb*KSTEPS)+ks)*NFRAG + frag)*64 + lane)*8 + j]
//   = bf16(W[ks*32 + (lane>>4)*8 + j][cb*NFRAG*16 + frag*16 + (lane&15)])
__global__ __launch_bounds__(256) void wconv3_k(const float* __restrict__ W, int K, int N,
                                                int NFRAG, int NB, int KSTEPS,
                                                unsigned short* __restrict__ dst) {
  int total = NB * KSTEPS * NFRAG * 64 * 8;
  int idx = blockIdx.x * 256 + threadIdx.x;
  if (idx >= total) return;
  int j = idx & 7;
  int lane = (idx >> 3) & 63;
  int rest = idx >> 9;
  int frag = rest % NFRAG;
  int rest2 = rest / NFRAG;
  int ks = rest2 % KSTEPS;
  int cb = rest2 / KSTEPS;
  int k = ks * 32 + ((lane >> 4) << 3) + j;
  int col = cb * NFRAG * 16 + frag * 16 + (lane & 15);
  float v = (k < K && col < N) ? W[(size_t)k * N + col] : 0.f;
  dst[idx] = f2bf_rn(v);
}

// bf16-plane MFMA GEMM: C = act(A @ W + bias). A = single bf16 plane
// (stride 200), W bf16 fragment-major staged once to LDS (one barrier).
// 4 waves x 32 rows = 128 rows/block; NFRAG*16 cols per col-block (grid.y).
template<int NFRAG, int ACT, int STATS>
__global__ __launch_bounds__(256, 3) void gemm_bf_k(
    const unsigned short* __restrict__ A, const unsigned short* __restrict__ Wf,
    const float* __restrict__ bias, unsigned short* __restrict__ Cp,
    int N, float* __restrict__ stats) {
  constexpr int G = NFRAG * 7 * 64;  // 16B granules in this col-block's W slice
  __shared__ unsigned short wlds[G * 8];
  __shared__ float s_sum[NFRAG * 16];
  __shared__ float s_sq[NFRAG * 16];
  int tid = threadIdx.x;
  int lane = tid & 63;
  int wid = tid >> 6;

  const unsigned short* wsrc = Wf + (size_t)blockIdx.y * G * 8;
  for (int g = tid; g < G; g += 256)
    *(int4*)&wlds[(size_t)g * 8] = *(const int4*)&wsrc[(size_t)g * 8];
  if (STATS && tid < NFRAG * 16) { s_sum[tid] = 0.f; s_sq[tid] = 0.f; }

  int row0 = blockIdx.x * 128 + wid * 32;
  const unsigned short* pA = A + (size_t)(row0 + (lane & 15)) * 200 + ((lane >> 4) << 3);
  const unsigned short* pB = pA + 16 * 200;

  short8 aA[7], aB[7];
  #pragma unroll
  for (int i = 0; i < 7; ++i) {
    aA[i] = *(const short8*)(pA + i * 32);
    aB[i] = *(const short8*)(pB + i * 32);
  }
  __builtin_amdgcn_sched_barrier(0);
  __syncthreads();

  f32x4 accA[NFRAG], accB[NFRAG];
  #pragma unroll
  for (int f = 0; f < NFRAG; ++f) { accA[f] = 0.0f; accB[f] = 0.0f; }

  #pragma unroll
  for (int ks = 0; ks < 7; ++ks) {
    const short8* wp = (const short8*)wlds + (size_t)(ks * NFRAG) * 64 + lane;
    #pragma unroll
    for (int f = 0; f < NFRAG; ++f) {
      short8 wv = wp[(size_t)f * 64];
      accA[f] = __builtin_amdgcn_mfma_f32_16x16x32_bf16(aA[ks], wv, accA[f], 0, 0, 0);
      accB[f] = __builtin_amdgcn_mfma_f32_16x16x32_bf16(aB[ks], wv, accB[f], 0, 0, 0);
    }
  }

  int colbase = blockIdx.y * NFRAG * 16;
  int r0 = (lane >> 4) * 4;
  #pragma unroll
  for (int f = 0; f < NFRAG; ++f) {
    int col = colbase + f * 16 + (lane & 15);
    if (col < N) {
      float b = bias[col];
      float ls = 0.f, lq = 0.f;
      #pragma unroll
      for (int r = 0; r < 4; ++r) {
        int row = row0 + r0 + r;
        float v = accA[f][r] + b;
        if (ACT) v = (v >= 0.f) ? v : 0.2f * v;
        Cp[(size_t)row * 200 + col] = f2bf_rn(v);
        if (STATS) { ls += v; lq += v * v; }
      }
      #pragma unroll
      for (int r = 0; r < 4; ++r) {
        int row = row0 + 16 + r0 + r;
        float v = accB[f][r] + b;
        if (ACT) v = (v >= 0.f) ? v : 0.2f * v;
        Cp[(size_t)row * 200 + col] = f2bf_rn(v);
        if (STATS) { ls += v; lq += v * v; }
      }
      if (STATS) {
        atomicAdd(&s_sum[f * 16 + (lane & 15)], ls);
        atomicAdd(&s_sq[f * 16 + (lane & 15)], lq);
      }
    }
  }
  if (STATS) {
    __syncthreads();
    if (tid < NFRAG * 16) {
      int col = colbase + tid;
      if (col < 200) {
        atomicAdd(&stats[col], s_sum[tid]);
        atomicAdd(&stats[200 + col], s_sq[tid]);
      }
    }
  }
}

// Fused W3+W4: xcls = leaky(leaky(X3@W3+b3)@W4+b4) written as bf16 (1024x1600).
// H3 (128x64) lives only in LDS (padded stride 72 shorts, wave-local).
__global__ __launch_bounds__(256, 3) void gemm_w34_k(
    const unsigned short* __restrict__ A, const unsigned short* __restrict__ W3f,
    const unsigned short* __restrict__ W4f, const float* __restrict__ b3,
    const float* __restrict__ b4, unsigned short* __restrict__ xcls) {
  __shared__ unsigned short w3lds[7 * 4 * 64 * 8];   // 28 KB
  __shared__ unsigned short w4lds[2 * 64 * 8];       // 2 KB
  __shared__ unsigned short h3buf[128][72];          // 18 KB
  int tid = threadIdx.x;
  int lane = tid & 63;
  int wid = tid >> 6;

  for (int g = tid; g < 7 * 4 * 64; g += 256)
    *(int4*)&w3lds[(size_t)g * 8] = *(const int4*)&W3f[(size_t)g * 8];
  if (tid < 128)
    *(int4*)&w4lds[(size_t)tid * 8] = *(const int4*)&W4f[(size_t)tid * 8];

  int row0 = blockIdx.x * 128 + wid * 32;
  const unsigned short* pA = A + (size_t)(row0 + (lane & 15)) * 200 + ((lane >> 4) << 3);
  const unsigned short* pB = pA + 16 * 200;
  short8 aA[7], aB[7];
  #pragma unroll
  for (int i = 0; i < 7; ++i) {
    aA[i] = *(const short8*)(pA + i * 32);
    aB[i] = *(const short8*)(pB + i * 32);
  }
  __builtin_amdgcn_sched_barrier(0);
  __syncthreads();

  f32x4 accA[4], accB[4];
  #pragma unroll
  for (int f = 0; f < 4; ++f) { accA[f] = 0.0f; accB[f] = 0.0f; }
  #pragma unroll
  for (int ks = 0; ks < 7; ++ks) {
    const short8* wp = (const short8*)w3lds + (size_t)(ks * 4) * 64 + lane;
    #pragma unroll
    for (int f = 0; f < 4; ++f) {
      short8 wv = wp[(size_t)f * 64];
      accA[f] = __builtin_amdgcn_mfma_f32_16x16x32_bf16(aA[ks], wv, accA[f], 0, 0, 0);
      accB[f] = __builtin_amdgcn_mfma_f32_16x16x32_bf16(aB[ks], wv, accB[f], 0, 0, 0);
    }
  }

  int r0 = (lane >> 4) * 4;
  #pragma unroll
  for (int f = 0; f < 4; ++f) {
    int col = f * 16 + (lane & 15);
    float bb = b3[col];
    #pragma unroll
    for (int r = 0; r < 4; ++r) {
      float v = accA[f][r] + bb;
      v = (v >= 0.f) ? v : 0.2f * v;
      h3buf[wid * 32 + r0 + r][col] = f2bf_rn(v);
      v = accB[f][r] + bb;
      v = (v >= 0.f) ? v : 0.2f * v;
      h3buf[wid * 32 + 16 + r0 + r][col] = f2bf_rn(v);
    }
  }
  // wave-local LDS write->read: compiler inserts lgkmcnt; no barrier needed.
  f32x4 acc2A = 0.0f, acc2B = 0.0f;
  #pragma unroll
  for (int ks = 0; ks < 2; ++ks) {
    short8 a2A = *(const short8*)&h3buf[wid * 32 + (lane & 15)][ks * 32 + ((lane >> 4) << 3)];
    short8 a2B = *(const short8*)&h3buf[wid * 32 + 16 + (lane & 15)][ks * 32 + ((lane >> 4) << 3)];
    short8 wv = *(const short8*)&w4lds[(size_t)(ks * 64 + lane) * 8];
    acc2A = __builtin_amdgcn_mfma_f32_16x16x32_bf16(a2A, wv, acc2A, 0, 0, 0);
    acc2B = __builtin_amdgcn_mfma_f32_16x16x32_bf16(a2B, wv, acc2B, 0, 0, 0);
  }
  int col = lane & 15;
  if (col < 8) {
    float bb = b4[col];
    #pragma unroll
    for (int r = 0; r < 4; ++r) {
      int row = row0 + r0 + r;
      float v = acc2A[r] + bb;
      v = (v >= 0.f) ? v : 0.2f * v;
      xcls[(size_t)(row / 200) * 1600 + (row % 200) * 8 + col] = f2bf_rn(v);
      int row2 = row + 16;
      v = acc2B[r] + bb;
      v = (v >= 0.f) ? v : 0.2f * v;
      xcls[(size_t)(row2 / 200) * 1600 + (row2 % 200) * 8 + col] = f2bf_rn(v);
    }
  }
}

__global__ __launch_bounds__(256) void bn_scale_k(const float* __restrict__ stats,
                                                  const float* __restrict__ g,
                                                  const float* __restrict__ be,
                                                  float invN,
                                                  float* __restrict__ ss) {
  int c = threadIdx.x;
  if (c >= 200) return;
  float m = stats[c] * invN;
  float var = stats[200 + c] * invN - m * m;
  float sc = rsqrtf(var + 1e-5f) * g[c];
  ss[c] = sc;
  ss[200 + c] = be[c] - m * sc;
}

// bn3d stats over bf16 xcls (1024 x 1600; r = col>>3)
__global__ __launch_bounds__(256) void bn3d_stats_bf_k(const unsigned short* __restrict__ x,
                                                       float* __restrict__ stats) {
  int t = threadIdx.x;
  if (t >= 200) return;
  const unsigned short* p = x + (size_t)blockIdx.x * 16 * 1600 + t * 8;
  float s = 0.f, q = 0.f;
  for (int b = 0; b < 16; ++b) {
    const unsigned* u = (const unsigned*)(p + (size_t)b * 1600);
    #pragma unroll
    for (int i = 0; i < 4; ++i) {
      unsigned w = u[i];
      float v0 = __uint_as_float(w << 16);
      float v1 = __uint_as_float(w & 0xFFFF0000u);
      s += v0 + v1;
      q += v0 * v0 + v1 * v1;
    }
  }
  atomicAdd(&stats[t], s);
  atomicAdd(&stats[200 + t], q);
}

// Wc1 fold + fragment-major bf16 conversion: Wc1'[k][n] = Wc1[k][n]*sc[k>>3].
// Layout: slice = cb*5+kc (cb<4 colblocks of 64, kc<5 kchunks of 320);
// dst[((slice*10+ks)*4+frag)*512 + lane*8 + j], k = kc*320+ks*32+(lane>>4)*8+j,
// col = cb*64 + frag*16 + (lane&15).
__global__ __launch_bounds__(256) void wcls_conv_k(const float* __restrict__ Wc1,
                                                   const float* __restrict__ ss,
                                                   unsigned short* __restrict__ dst) {
  int idx = blockIdx.x * 256 + threadIdx.x;
  if (idx >= 409600) return;
  int j = idx & 7;
  int lane = (idx >> 3) & 63;
  int rest = idx >> 9;
  int frag = rest & 3;
  int rest2 = rest >> 2;
  int ks = rest2 % 10;
  int slice = rest2 / 10;
  int kc = slice % 5, cb = slice / 5;
  int k = kc * 320 + ks * 32 + ((lane >> 4) << 3) + j;
  int col = cb * 64 + frag * 16 + (lane & 15);
  dst[idx] = f2bf_rn(Wc1[(size_t)k * 256 + col] * ss[k >> 3]);
}

// bias1' = bc1 + sum_k sh[k>>3] * Wc1[k][n]   (init, then 16-way k-chunk acc)
__global__ __launch_bounds__(256) void bias1_init_k(const float* __restrict__ bc1,
                                                    float* __restrict__ bias1p) {
  bias1p[threadIdx.x] = bc1[threadIdx.x];
}
__global__ __launch_bounds__(256) void bias1_acc_k(const float* __restrict__ Wc1,
                                                   const float* __restrict__ ss,
                                                   float* __restrict__ bias1p) {
  int t = threadIdx.x;
  int k0 = blockIdx.x * 100;
  float a = 0.f;
  #pragma unroll 4
  for (int k = k0; k < k0 + 100; ++k)
    a += ss[200 + (k >> 3)] * Wc1[(size_t)k * 256 + t];
  atomicAdd(&bias1p[t], a);
}

// Classifier GEMM1 (MFMA, K-split): h1f += xcls[128 rows] @ Wc1' chunk.
// grid (8 rowblocks, 4 colblocks, 5 kchunks); fp32 atomicAdd epilogue.
__global__ __launch_bounds__(256, 2) void gemm_cls1_k(
    const unsigned short* __restrict__ xcls, const unsigned short* __restrict__ Wf,
    float* __restrict__ h1f) {
  __shared__ unsigned short wlds[10 * 4 * 64 * 8];  // 40 KB
  int tid = threadIdx.x;
  int lane = tid & 63;
  int wid = tid >> 6;
  const unsigned short* wsrc = Wf + (size_t)(blockIdx.y * 5 + blockIdx.z) * (10 * 4 * 64) * 8;
  for (int g = tid; g < 10 * 4 * 64; g += 256)
    *(int4*)&wlds[(size_t)g * 8] = *(const int4*)&wsrc[(size_t)g * 8];

  int row0 = blockIdx.x * 128 + wid * 32;
  int kbase = blockIdx.z * 320;
  const unsigned short* pA = xcls + (size_t)(row0 + (lane & 15)) * 1600 + kbase + ((lane >> 4) << 3);
  const unsigned short* pB = pA + 16 * 1600;
  short8 aA[10], aB[10];
  #pragma unroll
  for (int i = 0; i < 10; ++i) {
    aA[i] = *(const short8*)(pA + i * 32);
    aB[i] = *(const short8*)(pB + i * 32);
  }
  __builtin_amdgcn_sched_barrier(0);
  __syncthreads();

  f32x4 accA[4], accB[4];
  #pragma unroll
  for (int f = 0; f < 4; ++f) { accA[f] = 0.0f; accB[f] = 0.0f; }
  #pragma unroll
  for (int ks = 0; ks < 10; ++ks) {
    const short8* wp = (const short8*)wlds + (size_t)(ks * 4) * 64 + lane;
    #pragma unroll
    for (int f = 0; f < 4; ++f) {
      short8 wv = wp[(size_t)f * 64];
      accA[f] = __builtin_amdgcn_mfma_f32_16x16x32_bf16(aA[ks], wv, accA[f], 0, 0, 0);
      accB[f] = __builtin_amdgcn_mfma_f32_16x16x32_bf16(aB[ks], wv, accB[f], 0, 0, 0);
    }
  }
  int colbase = blockIdx.y * 64;
  int r0 = (lane >> 4) * 4;
  #pragma unroll
  for (int f = 0; f < 4; ++f) {
    int col = colbase + f * 16 + (lane & 15);
    #pragma unroll
    for (int r = 0; r < 4; ++r) {
      atomicAdd(&h1f[(size_t)(row0 + r0 + r) * 256 + col], accA[f][r]);
      atomicAdd(&h1f[(size_t)(row0 + 16 + r0 + r) * 256 + col], accB[f][r]);
    }
  }
}

// Classifier tail: h1 = leaky(h1f + bias1'), h2 = leaky(h1@Wc2+bc2), out = h2@Wc3+bc3.
__global__ __launch_bounds__(256) void classifier2_k(
    const float* __restrict__ h1f, const float* __restrict__ bias1p,
    const float* __restrict__ Wc2, const float* __restrict__ bc2,
    const float* __restrict__ Wc3, const float* __restrict__ bc3,
    float* __restrict__ out) {
  __shared__ float h1s[8][256];
  __shared__ float h2s[8][32];
  int t = threadIdx.x;
  int b0 = blockIdx.x * 8;
  #pragma unroll
  for (int j = 0; j < 8; ++j) {
    float v = h1f[(size_t)(b0 + j) * 256 + t] + bias1p[t];
    h1s[j][t] = (v >= 0.f) ? v : 0.2f * v;
  }
  __syncthreads();
  {
    int j = t >> 5, c = t & 31;
    float a = 0.f;
    #pragma unroll 8
    for (int k = 0; k < 256; ++k) a += h1s[j][k] * Wc2[k * 32 + c];
    float v = a + bc2[c];
    h2s[j][c] = (v >= 0.f) ? v : 0.2f * v;
  }
  __syncthreads();
  if (t < 16) {
    int j = t >> 1, c = t & 1;
    float a = 0.f;
    #pragma unroll
    for (int k = 0; k < 32; ++k) a += h2s[j][k] * Wc3[k * 2 + c];
    out[(size_t)(b0 + j) * 2 + c] = a + bc3[c];
  }
}

extern "C" void kernel_launch(void* const* d_in, const int* in_sizes, int n_in,
                              void* d_out, int out_size, void* d_ws, size_t ws_size,
                              hipStream_t stream) {
  const float* intra = (const float*)d_in[1];
  const float* inter = (const float*)d_in[2];
  const float* nodef = (const float*)d_in[3];
  const float* W0 = (const float*)d_in[4];
  const float* b0 = (const float*)d_in[5];
  const float* W1 = (const float*)d_in[6];
  const float* b1 = (const float*)d_in[7];
  const float* g1 = (const float*)d_in[8];
  const float* be1 = (const float*)d_in[9];
  const float* W2 = (const float*)d_in[10];
  const float* b2 = (const float*)d_in[11];
  const float* g2 = (const float*)d_in[12];
  const float* be2 = (const float*)d_in[13];
  const float* W3 = (const float*)d_in[14];
  const float* b3 = (const float*)d_in[15];
  const float* W4 = (const float*)d_in[16];
  const float* b4 = (const float*)d_in[17];
  const float* g3 = (const float*)d_in[18];
  const float* be3 = (const float*)d_in[19];
  const float* Wc1 = (const float*)d_in[20];
  const float* bc1 = (const float*)d_in[21];
  const float* Wc2 = (const float*)d_in[22];
  const float* bc2 = (const float*)d_in[23];
  const float* Wc3 = (const float*)d_in[24];
  const float* bc3 = (const float*)d_in[25];
  float* out = (float*)d_out;

  // Layout: 2 bf16 planes (ping-pong), then fp32 scratch + weights.
  unsigned short* P0 = (unsigned short*)d_ws;
  unsigned short* P1 = P0 + PLSZ;
  float* fbase = (float*)(P1 + PLSZ);
  float* rsI  = fbase;                         // 204,800
  float* rsP  = rsI + NROWS;                   // 8,192
  float* stats = rsP + BDIM * 8;               // 512
  float* ssbuf = stats + 512;                  // 512
  float* h1f  = ssbuf + 512;                   // 262,144
  float* bias1p = h1f + (size_t)BDIM * 256;    // 256 (pad 512)
  unsigned short* wt = (unsigned short*)(bias1p + 512);
  const size_t W200SZ = 2 * 7 * 7 * 64 * 8;    // 50,176 shorts
  const size_t W3SZ   = 1 * 7 * 4 * 64 * 8;    // 14,336 shorts
  const size_t W4SZ   = 1 * 2 * 1 * 64 * 8;    // 1,024 shorts
  const size_t WC1SZ  = 409600;                // shorts
  unsigned short* w0f = wt;
  unsigned short* w1f = w0f + W200SZ;
  unsigned short* w2f = w1f + W200SZ;
  unsigned short* w3f = w2f + W200SZ;
  unsigned short* w4f = w3f + W3SZ;
  unsigned short* wc1f = w4f + W4SZ;
  // xcls (1024x1600 bf16) aliases the (dead-at-that-point) P0 plane
  unsigned short* xcls = P0;

  // zero plane tail pads
  hipMemsetAsync(P0 + XELEMS, 0, PLPAD * 2, stream);
  hipMemsetAsync(P1 + XELEMS, 0, PLPAD * 2, stream);

  wconv3_k<<<(int)((W200SZ + 255) / 256), 256, 0, stream>>>(W0, 200, 200, 7, 2, 7, w0f);
  wconv3_k<<<(int)((W200SZ + 255) / 256), 256, 0, stream>>>(W1, 200, 200, 7, 2, 7, w1f);
  wconv3_k<<<(int)((W200SZ + 255) / 256), 256, 0, stream>>>(W2, 200, 200, 7, 2, 7, w2f);
  wconv3_k<<<(int)((W3SZ + 255) / 256), 256, 0, stream>>>(W3, 200, 64, 4, 1, 7, w3f);
  wconv3_k<<<(int)((W4SZ + 255) / 256), 256, 0, stream>>>(W4, 64, 8, 1, 1, 2, w4f);

  rowsum4_k<<<NROWS / 4, 256, 0, stream>>>(intra, rsI);
  intersum_k<<<(BDIM * 8 + 255) / 256, 256, 0, stream>>>(inter, rsP);

  // block 1: nodef (fp32) -> X1 (P0)
  seg_combine_bf_k<0, 0><<<BDIM, 128, 0, stream>>>(
      nodef, nullptr, rsI, rsP, nullptr, P0);

  // H = leaky(X1@W0+b0): P0 -> P1
  gemm_bf_k<7, 1, 0><<<dim3(NROWS / 128, 2), 256, 0, stream>>>(
      P0, w0f, b0, P1, 200, nullptr);
  // Y1 = H@W1+b1 (+stats): P1 -> P0
  hipMemsetAsync(stats, 0, 400 * sizeof(float), stream);
  gemm_bf_k<7, 0, 1><<<dim3(NROWS / 128, 2), 256, 0, stream>>>(
      P1, w1f, b1, P0, 200, stats);
  bn_scale_k<<<1, 256, 0, stream>>>(stats, g1, be1, 1.f / (float)NROWS, ssbuf);

  // block 2 (BN1 fold): P0 -> X2 (P1)
  seg_combine_bf_k<1, 1><<<BDIM, 128, 0, stream>>>(
      nullptr, P0, rsI, rsP, ssbuf, P1);

  // Y2 = leaky(X2@W2+b2) (+stats): P1 -> P0
  hipMemsetAsync(stats, 0, 400 * sizeof(float), stream);
  gemm_bf_k<7, 1, 1><<<dim3(NROWS / 128, 2), 256, 0, stream>>>(
      P1, w2f, b2, P0, 200, stats);
  bn_scale_k<<<1, 256, 0, stream>>>(stats, g2, be2, 1.f / (float)NROWS, ssbuf);

  // block 3 (BN2 fold): P0 -> X3 (P1)
  seg_combine_bf_k<1, 1><<<BDIM, 128, 0, stream>>>(
      nullptr, P0, rsI, rsP, ssbuf, P1);

  // xcls = leaky(leaky(X3@W3+b3)@W4+b4): P1 -> xcls (aliases P0, dead)
  gemm_w34_k<<<NROWS / 128, 256, 0, stream>>>(P1, w3f, w4f, b3, b4, xcls);

  // bn3d stats on xcls; affine folded into Wc1/bias1
  hipMemsetAsync(stats, 0, 400 * sizeof(float), stream);
  bn3d_stats_bf_k<<<64, 256, 0, stream>>>(xcls, stats);
  bn_scale_k<<<1, 256, 0, stream>>>(stats, g3, be3, 1.f / 8192.f, ssbuf);

  // fold BN3d into Wc1 (scale) and bias1 (shift)
  wcls_conv_k<<<1600, 256, 0, stream>>>(Wc1, ssbuf, wc1f);
  bias1_init_k<<<1, 256, 0, stream>>>(bc1, bias1p);
  bias1_acc_k<<<16, 256, 0, stream>>>(Wc1, ssbuf, bias1p);

  // classifier GEMM1 (MFMA, K-split atomics) then tail
  hipMemsetAsync(h1f, 0, (size_t)BDIM * 256 * sizeof(float), stream);
  gemm_cls1_k<<<dim3(8, 4, 5), 256, 0, stream>>>(xcls, wc1f, h1f);
  classifier2_k<<<BDIM / 8, 256, 0, stream>>>(h1f, bias1p, Wc2, bc2, Wc3, bc3, out);
}

// Round 11
// 592.999 us; speedup vs baseline: 4.5886x; 1.0577x over previous
//
#include <hip/hip_runtime.h>
#include <hip/hip_bf16.h>

// Problem constants
#define BDIM 1024
#define ROI 200
#define DIN 200
#define NSUB 8
#define NROWS (BDIM * ROI)           // 204800
#define XELEMS ((size_t)NROWS * 200) // 40,960,000
#define PLPAD 32                     // tail pad (shorts) per plane for k-overrun
#define PLSZ (XELEMS + PLPAD)        // shorts per bf16 plane

typedef __attribute__((ext_vector_type(8))) short short8;
typedef __attribute__((ext_vector_type(4))) float f32x4;

__device__ __constant__ float d_invcnt[8] = {
    1.f/41.f, 1.f/29.f, 1.f/21.f, 1.f/19.f, 1.f/20.f, 1.f/7.f, 1.f/21.f, 1.f/42.f};

__device__ inline unsigned short f2bf_rn(float x) {
  unsigned u = __float_as_uint(x);
  return (unsigned short)((u + 0x7FFFu + ((u >> 16) & 1u)) >> 16);
}

// async global->LDS, 16B per lane; LDS dest = uniform base + lane*16
__device__ inline void gload_lds16(const unsigned short* src, unsigned short* dst) {
  __builtin_amdgcn_global_load_lds(
      (const __attribute__((address_space(1))) void*)src,
      (__attribute__((address_space(3))) void*)dst, 16, 0, 0);
}

// rs_intra: one wave per row, 4 rows per block
__global__ __launch_bounds__(256) void rowsum4_k(const float* __restrict__ in,
                                                 float* __restrict__ out) {
  int row = blockIdx.x * 4 + (threadIdx.x >> 6);
  int lane = threadIdx.x & 63;
  const float* p = in + (size_t)row * 200;
  float v = p[lane] + p[lane + 64] + p[lane + 128];
  if (lane < 8) v += p[lane + 192];
  #pragma unroll
  for (int off = 32; off > 0; off >>= 1) v += __shfl_down(v, off);
  if (lane == 0) out[row] = v;
}

__global__ __launch_bounds__(256) void intersum_k(const float* __restrict__ in,
                                                  float* __restrict__ out) {
  int i = blockIdx.x * blockDim.x + threadIdx.x;
  if (i >= BDIM * NSUB) return;
  const float* p = in + (size_t)i * 8;
  float v = 0.f;
  #pragma unroll
  for (int c = 0; c < 8; ++c) v += p[c];
  out[i] = v;
}

// Fused seg_mean + block_combine (+ optional BN fold).
// Input fp32 (INPL=0) or packed bf16 plane (INPL=1); output packed bf16 plane.
// 128 threads; thread t<100 owns cols (2t, 2t+1) of batch blockIdx.x.
template<int INPL, int BN>
__global__ __launch_bounds__(128) void seg_combine_bf_k(
    const float* __restrict__ xf, const unsigned short* __restrict__ xp,
    const float* __restrict__ rsI, const float* __restrict__ rsP,
    const float* __restrict__ ss, unsigned short* __restrict__ yp) {
  constexpr int STARTS[8] = {0, 41, 70, 91, 110, 130, 137, 158};
  constexpr int ENDS[8]   = {41, 70, 91, 110, 130, 137, 158, 200};
  int b = blockIdx.x;
  int t = threadIdx.x;
  if (t >= 100) return;
  int c0 = 2 * t;
  size_t base = (size_t)b * 40000 + c0;
  float sc0 = 1.f, sh0 = 0.f, sc1 = 1.f, sh1 = 0.f;
  if (BN) { sc0 = ss[c0]; sh0 = ss[200 + c0]; sc1 = ss[c0 + 1]; sh1 = ss[200 + c0 + 1]; }
  float pr0[8], pr1[8];
  #pragma unroll
  for (int s = 0; s < 8; ++s) {
    float a0 = 0.f, a1 = 0.f;
    #pragma unroll 4
    for (int r = STARTS[s]; r < ENDS[s]; ++r) {
      size_t idx = base + (size_t)r * 200;
      float v0, v1;
      if (INPL) {
        unsigned u = *(const unsigned*)(xp + idx);
        v0 = __uint_as_float(u << 16);
        v1 = __uint_as_float(u & 0xFFFF0000u);
      } else {
        float2 fv = *(const float2*)(xf + idx);
        v0 = fv.x; v1 = fv.y;
      }
      a0 += v0; a1 += v1;
    }
    a0 *= d_invcnt[s]; a1 *= d_invcnt[s];
    if (BN) { a0 = a0 * sc0 + sh0; a1 = a1 * sc1 + sh1; }
    float rp = rsP[b * 8 + s];
    pr0[s] = rp * a0; pr1[s] = rp * a1;
  }
  const float* rsIb = rsI + b * 200;
  #pragma unroll
  for (int s = 0; s < 8; ++s) {
    float p0 = pr0[s], p1 = pr1[s];
    #pragma unroll 4
    for (int r = STARTS[s]; r < ENDS[s]; ++r) {
      size_t idx = base + (size_t)r * 200;
      float v0, v1;
      if (INPL) {
        unsigned u = *(const unsigned*)(xp + idx);
        v0 = __uint_as_float(u << 16);
        v1 = __uint_as_float(u & 0xFFFF0000u);
      } else {
        float2 fv = *(const float2*)(xf + idx);
        v0 = fv.x; v1 = fv.y;
      }
      if (BN) { v0 = v0 * sc0 + sh0; v1 = v1 * sc1 + sh1; }
      float ri = rsIb[r];
      float y0 = 0.5f * (ri * v0 + p0);
      float y1 = 0.5f * (ri * v1 + p1);
      unsigned o = (unsigned)f2bf_rn(y0) | ((unsigned)f2bf_rn(y1) << 16);
      *(unsigned*)(yp + idx) = o;
    }
  }
}

// Weight preconversion into per-colblock fragment-major granule layout for
// mfma_f32_16x16x32_bf16:
// dst[((((cb*KSTEPS)+ks)*NFRAG + frag)*64 + lane)*8 + j]
//   = bf16(W[ks*32 + (lane>>4)*8 + j][cb*NFRAG*16 + frag*16 + (lane&15)])
__global__ __launch_bounds__(256) void wconv3_k(const float* __restrict__ W, int K, int N,
                                                int NFRAG, int NB, int KSTEPS,
                                                unsigned short* __restrict__ dst) {
  int total = NB * KSTEPS * NFRAG * 64 * 8;
  int idx = blockIdx.x * 256 + threadIdx.x;
  if (idx >= total) return;
  int j = idx & 7;
  int lane = (idx >> 3) & 63;
  int rest = idx >> 9;
  int frag = rest % NFRAG;
  int rest2 = rest / NFRAG;
  int ks = rest2 % KSTEPS;
  int cb = rest2 / KSTEPS;
  int k = ks * 32 + ((lane >> 4) << 3) + j;
  int col = cb * NFRAG * 16 + frag * 16 + (lane & 15);
  float v = (k < K && col < N) ? W[(size_t)k * N + col] : 0.f;
  dst[idx] = f2bf_rn(v);
}

// bf16-plane MFMA GEMM: C = act(A @ W + bias). A = single bf16 plane
// (stride 200), W bf16 fragment-major staged once to LDS via async
// global_load_lds (fire-and-forget, 1KB/wave-instr). 4 waves x 32 rows =
// 128 rows/block; NFRAG*16 cols per col-block (grid.y).
template<int NFRAG, int ACT, int STATS>
__global__ __launch_bounds__(256, 3) void gemm_bf_k(
    const unsigned short* __restrict__ A, const unsigned short* __restrict__ Wf,
    const float* __restrict__ bias, unsigned short* __restrict__ Cp,
    int N, float* __restrict__ stats) {
  constexpr int G = NFRAG * 7 * 64;  // 16B granules in this col-block's W slice
  __shared__ unsigned short wlds[G * 8];
  __shared__ float s_sum[NFRAG * 16];
  __shared__ float s_sq[NFRAG * 16];
  int tid = threadIdx.x;
  int lane = tid & 63;
  int wid = tid >> 6;

  // async W stage: each wave-instr moves 64 granules (1 KB), no VGPR roundtrip
  const unsigned short* wsrc = Wf + (size_t)blockIdx.y * G * 8;
  for (int g0 = wid * 64; g0 < G; g0 += 256)
    gload_lds16(wsrc + (size_t)(g0 + lane) * 8, &wlds[(size_t)g0 * 8]);
  if (STATS && tid < NFRAG * 16) { s_sum[tid] = 0.f; s_sq[tid] = 0.f; }

  int row0 = blockIdx.x * 128 + wid * 32;
  const unsigned short* pA = A + (size_t)(row0 + (lane & 15)) * 200 + ((lane >> 4) << 3);
  const unsigned short* pB = pA + 16 * 200;

  // upfront A burst: whole K strip, both row-fragments (14 x 16B = 56 VGPR)
  short8 aA[7], aB[7];
  #pragma unroll
  for (int i = 0; i < 7; ++i) {
    aA[i] = *(const short8*)(pA + i * 32);
    aB[i] = *(const short8*)(pB + i * 32);
  }
  __builtin_amdgcn_sched_barrier(0);
  __syncthreads();   // drains vmcnt: W in LDS, A in regs

  f32x4 accA[NFRAG], accB[NFRAG];
  #pragma unroll
  for (int f = 0; f < NFRAG; ++f) { accA[f] = 0.0f; accB[f] = 0.0f; }

  #pragma unroll
  for (int ks = 0; ks < 7; ++ks) {
    const short8* wp = (const short8*)wlds + (size_t)(ks * NFRAG) * 64 + lane;
    #pragma unroll
    for (int f = 0; f < NFRAG; ++f) {
      short8 wv = wp[(size_t)f * 64];
      accA[f] = __builtin_amdgcn_mfma_f32_16x16x32_bf16(aA[ks], wv, accA[f], 0, 0, 0);
      accB[f] = __builtin_amdgcn_mfma_f32_16x16x32_bf16(aB[ks], wv, accB[f], 0, 0, 0);
    }
  }

  int colbase = blockIdx.y * NFRAG * 16;
  int r0 = (lane >> 4) * 4;
  #pragma unroll
  for (int f = 0; f < NFRAG; ++f) {
    int col = colbase + f * 16 + (lane & 15);
    if (col < N) {
      float b = bias[col];
      float ls = 0.f, lq = 0.f;
      #pragma unroll
      for (int r = 0; r < 4; ++r) {
        int row = row0 + r0 + r;
        float v = accA[f][r] + b;
        if (ACT) v = (v >= 0.f) ? v : 0.2f * v;
        Cp[(size_t)row * 200 + col] = f2bf_rn(v);
        if (STATS) { ls += v; lq += v * v; }
      }
      #pragma unroll
      for (int r = 0; r < 4; ++r) {
        int row = row0 + 16 + r0 + r;
        float v = accB[f][r] + b;
        if (ACT) v = (v >= 0.f) ? v : 0.2f * v;
        Cp[(size_t)row * 200 + col] = f2bf_rn(v);
        if (STATS) { ls += v; lq += v * v; }
      }
      if (STATS) {
        atomicAdd(&s_sum[f * 16 + (lane & 15)], ls);
        atomicAdd(&s_sq[f * 16 + (lane & 15)], lq);
      }
    }
  }
  if (STATS) {
    __syncthreads();
    if (tid < NFRAG * 16) {
      int col = colbase + tid;
      if (col < 200) {
        atomicAdd(&stats[col], s_sum[tid]);
        atomicAdd(&stats[200 + col], s_sq[tid]);
      }
    }
  }
}

// Fused W3+W4: xcls = leaky(leaky(X3@W3+b3)@W4+b4) written as bf16 (1024x1600).
// H3 (128x64) lives only in LDS (padded stride 72 shorts, wave-local).
__global__ __launch_bounds__(256, 3) void gemm_w34_k(
    const unsigned short* __restrict__ A, const unsigned short* __restrict__ W3f,
    const unsigned short* __restrict__ W4f, const float* __restrict__ b3,
    const float* __restrict__ b4, unsigned short* __restrict__ xcls) {
  __shared__ unsigned short w3lds[7 * 4 * 64 * 8];   // 28 KB (1792 granules)
  __shared__ unsigned short w4lds[2 * 64 * 8];       // 2 KB (128 granules)
  __shared__ unsigned short h3buf[128][72];          // 18 KB
  int tid = threadIdx.x;
  int lane = tid & 63;
  int wid = tid >> 6;

  for (int g0 = wid * 64; g0 < 1792; g0 += 256)
    gload_lds16(W3f + (size_t)(g0 + lane) * 8, &w3lds[(size_t)g0 * 8]);
  for (int g0 = wid * 64; g0 < 128; g0 += 256)
    gload_lds16(W4f + (size_t)(g0 + lane) * 8, &w4lds[(size_t)g0 * 8]);

  int row0 = blockIdx.x * 128 + wid * 32;
  const unsigned short* pA = A + (size_t)(row0 + (lane & 15)) * 200 + ((lane >> 4) << 3);
  const unsigned short* pB = pA + 16 * 200;
  short8 aA[7], aB[7];
  #pragma unroll
  for (int i = 0; i < 7; ++i) {
    aA[i] = *(const short8*)(pA + i * 32);
    aB[i] = *(const short8*)(pB + i * 32);
  }
  __builtin_amdgcn_sched_barrier(0);
  __syncthreads();

  f32x4 accA[4], accB[4];
  #pragma unroll
  for (int f = 0; f < 4; ++f) { accA[f] = 0.0f; accB[f] = 0.0f; }
  #pragma unroll
  for (int ks = 0; ks < 7; ++ks) {
    const short8* wp = (const short8*)w3lds + (size_t)(ks * 4) * 64 + lane;
    #pragma unroll
    for (int f = 0; f < 4; ++f) {
      short8 wv = wp[(size_t)f * 64];
      accA[f] = __builtin_amdgcn_mfma_f32_16x16x32_bf16(aA[ks], wv, accA[f], 0, 0, 0);
      accB[f] = __builtin_amdgcn_mfma_f32_16x16x32_bf16(aB[ks], wv, accB[f], 0, 0, 0);
    }
  }

  int r0 = (lane >> 4) * 4;
  #pragma unroll
  for (int f = 0; f < 4; ++f) {
    int col = f * 16 + (lane & 15);
    float bb = b3[col];
    #pragma unroll
    for (int r = 0; r < 4; ++r) {
      float v = accA[f][r] + bb;
      v = (v >= 0.f) ? v : 0.2f * v;
      h3buf[wid * 32 + r0 + r][col] = f2bf_rn(v);
      v = accB[f][r] + bb;
      v = (v >= 0.f) ? v : 0.2f * v;
      h3buf[wid * 32 + 16 + r0 + r][col] = f2bf_rn(v);
    }
  }
  // wave-local LDS write->read: compiler inserts lgkmcnt; no barrier needed.
  f32x4 acc2A = 0.0f, acc2B = 0.0f;
  #pragma unroll
  for (int ks = 0; ks < 2; ++ks) {
    short8 a2A = *(const short8*)&h3buf[wid * 32 + (lane & 15)][ks * 32 + ((lane >> 4) << 3)];
    short8 a2B = *(const short8*)&h3buf[wid * 32 + 16 + (lane & 15)][ks * 32 + ((lane >> 4) << 3)];
    short8 wv = *(const short8*)&w4lds[(size_t)(ks * 64 + lane) * 8];
    acc2A = __builtin_amdgcn_mfma_f32_16x16x32_bf16(a2A, wv, acc2A, 0, 0, 0);
    acc2B = __builtin_amdgcn_mfma_f32_16x16x32_bf16(a2B, wv, acc2B, 0, 0, 0);
  }
  int col = lane & 15;
  if (col < 8) {
    float bb = b4[col];
    #pragma unroll
    for (int r = 0; r < 4; ++r) {
      int row = row0 + r0 + r;
      float v = acc2A[r] + bb;
      v = (v >= 0.f) ? v : 0.2f * v;
      xcls[(size_t)(row / 200) * 1600 + (row % 200) * 8 + col] = f2bf_rn(v);
      int row2 = row + 16;
      v = acc2B[r] + bb;
      v = (v >= 0.f) ? v : 0.2f * v;
      xcls[(size_t)(row2 / 200) * 1600 + (row2 % 200) * 8 + col] = f2bf_rn(v);
    }
  }
}

__global__ __launch_bounds__(256) void bn_scale_k(const float* __restrict__ stats,
                                                  const float* __restrict__ g,
                                                  const float* __restrict__ be,
                                                  float invN,
                                                  float* __restrict__ ss) {
  int c = threadIdx.x;
  if (c >= 200) return;
  float m = stats[c] * invN;
  float var = stats[200 + c] * invN - m * m;
  float sc = rsqrtf(var + 1e-5f) * g[c];
  ss[c] = sc;
  ss[200 + c] = be[c] - m * sc;
}

// bn3d stats over bf16 xcls (1024 x 1600; r = col>>3)
__global__ __launch_bounds__(256) void bn3d_stats_bf_k(const unsigned short* __restrict__ x,
                                                       float* __restrict__ stats) {
  int t = threadIdx.x;
  if (t >= 200) return;
  const unsigned short* p = x + (size_t)blockIdx.x * 16 * 1600 + t * 8;
  float s = 0.f, q = 0.f;
  for (int b = 0; b < 16; ++b) {
    const unsigned* u = (const unsigned*)(p + (size_t)b * 1600);
    #pragma unroll
    for (int i = 0; i < 4; ++i) {
      unsigned w = u[i];
      float v0 = __uint_as_float(w << 16);
      float v1 = __uint_as_float(w & 0xFFFF0000u);
      s += v0 + v1;
      q += v0 * v0 + v1 * v1;
    }
  }
  atomicAdd(&stats[t], s);
  atomicAdd(&stats[200 + t], q);
}

// Wc1 fold + fragment-major bf16 conversion: Wc1'[k][n] = Wc1[k][n]*sc[k>>3].
__global__ __launch_bounds__(256) void wcls_conv_k(const float* __restrict__ Wc1,
                                                   const float* __restrict__ ss,
                                                   unsigned short* __restrict__ dst) {
  int idx = blockIdx.x * 256 + threadIdx.x;
  if (idx >= 409600) return;
  int j = idx & 7;
  int lane = (idx >> 3) & 63;
  int rest = idx >> 9;
  int frag = rest & 3;
  int rest2 = rest >> 2;
  int ks = rest2 % 10;
  int slice = rest2 / 10;
  int kc = slice % 5, cb = slice / 5;
  int k = kc * 320 + ks * 32 + ((lane >> 4) << 3) + j;
  int col = cb * 64 + frag * 16 + (lane & 15);
  dst[idx] = f2bf_rn(Wc1[(size_t)k * 256 + col] * ss[k >> 3]);
}

// bias1' = bc1 + sum_k sh[k>>3] * Wc1[k][n]
__global__ __launch_bounds__(256) void bias1_init_k(const float* __restrict__ bc1,
                                                    float* __restrict__ bias1p) {
  bias1p[threadIdx.x] = bc1[threadIdx.x];
}
__global__ __launch_bounds__(256) void bias1_acc_k(const float* __restrict__ Wc1,
                                                   const float* __restrict__ ss,
                                                   float* __restrict__ bias1p) {
  int t = threadIdx.x;
  int k0 = blockIdx.x * 100;
  float a = 0.f;
  #pragma unroll 4
  for (int k = k0; k < k0 + 100; ++k)
    a += ss[200 + (k >> 3)] * Wc1[(size_t)k * 256 + t];
  atomicAdd(&bias1p[t], a);
}

// Classifier GEMM1 (MFMA, K-split): h1f += xcls[128 rows] @ Wc1' chunk.
// grid (8 rowblocks, 4 colblocks, 5 kchunks); fp32 atomicAdd epilogue.
__global__ __launch_bounds__(256, 3) void gemm_cls1_k(
    const unsigned short* __restrict__ xcls, const unsigned short* __restrict__ Wf,
    float* __restrict__ h1f) {
  __shared__ unsigned short wlds[10 * 4 * 64 * 8];  // 40 KB (2560 granules)
  int tid = threadIdx.x;
  int lane = tid & 63;
  int wid = tid >> 6;
  const unsigned short* wsrc = Wf + (size_t)(blockIdx.y * 5 + blockIdx.z) * (10 * 4 * 64) * 8;
  for (int g0 = wid * 64; g0 < 2560; g0 += 256)
    gload_lds16(wsrc + (size_t)(g0 + lane) * 8, &wlds[(size_t)g0 * 8]);

  int row0 = blockIdx.x * 128 + wid * 32;
  int kbase = blockIdx.z * 320;
  const unsigned short* pA = xcls + (size_t)(row0 + (lane & 15)) * 1600 + kbase + ((lane >> 4) << 3);
  const unsigned short* pB = pA + 16 * 1600;
  short8 aA[10], aB[10];
  #pragma unroll
  for (int i = 0; i < 10; ++i) {
    aA[i] = *(const short8*)(pA + i * 32);
    aB[i] = *(const short8*)(pB + i * 32);
  }
  __builtin_amdgcn_sched_barrier(0);
  __syncthreads();

  f32x4 accA[4], accB[4];
  #pragma unroll
  for (int f = 0; f < 4; ++f) { accA[f] = 0.0f; accB[f] = 0.0f; }
  #pragma unroll
  for (int ks = 0; ks < 10; ++ks) {
    const short8* wp = (const short8*)wlds + (size_t)(ks * 4) * 64 + lane;
    #pragma unroll
    for (int f = 0; f < 4; ++f) {
      short8 wv = wp[(size_t)f * 64];
      accA[f] = __builtin_amdgcn_mfma_f32_16x16x32_bf16(aA[ks], wv, accA[f], 0, 0, 0);
      accB[f] = __builtin_amdgcn_mfma_f32_16x16x32_bf16(aB[ks], wv, accB[f], 0, 0, 0);
    }
  }
  int colbase = blockIdx.y * 64;
  int r0 = (lane >> 4) * 4;
  #pragma unroll
  for (int f = 0; f < 4; ++f) {
    int col = colbase + f * 16 + (lane & 15);
    #pragma unroll
    for (int r = 0; r < 4; ++r) {
      atomicAdd(&h1f[(size_t)(row0 + r0 + r) * 256 + col], accA[f][r]);
      atomicAdd(&h1f[(size_t)(row0 + 16 + r0 + r) * 256 + col], accB[f][r]);
    }
  }
}

// Classifier tail: h1 = leaky(h1f + bias1'), h2 = leaky(h1@Wc2+bc2), out = h2@Wc3+bc3.
__global__ __launch_bounds__(256) void classifier2_k(
    const float* __restrict__ h1f, const float* __restrict__ bias1p,
    const float* __restrict__ Wc2, const float* __restrict__ bc2,
    const float* __restrict__ Wc3, const float* __restrict__ bc3,
    float* __restrict__ out) {
  __shared__ float h1s[8][256];
  __shared__ float h2s[8][32];
  int t = threadIdx.x;
  int b0 = blockIdx.x * 8;
  #pragma unroll
  for (int j = 0; j < 8; ++j) {
    float v = h1f[(size_t)(b0 + j) * 256 + t] + bias1p[t];
    h1s[j][t] = (v >= 0.f) ? v : 0.2f * v;
  }
  __syncthreads();
  {
    int j = t >> 5, c = t & 31;
    float a = 0.f;
    #pragma unroll 8
    for (int k = 0; k < 256; ++k) a += h1s[j][k] * Wc2[k * 32 + c];
    float v = a + bc2[c];
    h2s[j][c] = (v >= 0.f) ? v : 0.2f * v;
  }
  __syncthreads();
  if (t < 16) {
    int j = t >> 1, c = t & 1;
    float a = 0.f;
    #pragma unroll
    for (int k = 0; k < 32; ++k) a += h2s[j][k] * Wc3[k * 2 + c];
    out[(size_t)(b0 + j) * 2 + c] = a + bc3[c];
  }
}

extern "C" void kernel_launch(void* const* d_in, const int* in_sizes, int n_in,
                              void* d_out, int out_size, void* d_ws, size_t ws_size,
                              hipStream_t stream) {
  const float* intra = (const float*)d_in[1];
  const float* inter = (const float*)d_in[2];
  const float* nodef = (const float*)d_in[3];
  const float* W0 = (const float*)d_in[4];
  const float* b0 = (const float*)d_in[5];
  const float* W1 = (const float*)d_in[6];
  const float* b1 = (const float*)d_in[7];
  const float* g1 = (const float*)d_in[8];
  const float* be1 = (const float*)d_in[9];
  const float* W2 = (const float*)d_in[10];
  const float* b2 = (const float*)d_in[11];
  const float* g2 = (const float*)d_in[12];
  const float* be2 = (const float*)d_in[13];
  const float* W3 = (const float*)d_in[14];
  const float* b3 = (const float*)d_in[15];
  const float* W4 = (const float*)d_in[16];
  const float* b4 = (const float*)d_in[17];
  const float* g3 = (const float*)d_in[18];
  const float* be3 = (const float*)d_in[19];
  const float* Wc1 = (const float*)d_in[20];
  const float* bc1 = (const float*)d_in[21];
  const float* Wc2 = (const float*)d_in[22];
  const float* bc2 = (const float*)d_in[23];
  const float* Wc3 = (const float*)d_in[24];
  const float* bc3 = (const float*)d_in[25];
  float* out = (float*)d_out;

  // Layout: 2 bf16 planes (ping-pong), then fp32 scratch + weights.
  unsigned short* P0 = (unsigned short*)d_ws;
  unsigned short* P1 = P0 + PLSZ;
  float* fbase = (float*)(P1 + PLSZ);
  float* rsI  = fbase;                         // 204,800
  float* rsP  = rsI + NROWS;                   // 8,192
  float* stats = rsP + BDIM * 8;               // 512
  float* ssbuf = stats + 512;                  // 512
  float* h1f  = ssbuf + 512;                   // 262,144
  float* bias1p = h1f + (size_t)BDIM * 256;    // 256 (pad 512)
  unsigned short* wt = (unsigned short*)(bias1p + 512);
  const size_t W200SZ = 2 * 7 * 7 * 64 * 8;    // 50,176 shorts
  const size_t W3SZ   = 1 * 7 * 4 * 64 * 8;    // 14,336 shorts
  const size_t W4SZ   = 1 * 2 * 1 * 64 * 8;    // 1,024 shorts
  unsigned short* w0f = wt;
  unsigned short* w1f = w0f + W200SZ;
  unsigned short* w2f = w1f + W200SZ;
  unsigned short* w3f = w2f + W200SZ;
  unsigned short* w4f = w3f + W3SZ;
  unsigned short* wc1f = w4f + W4SZ;
  // xcls (1024x1600 bf16) aliases the (dead-at-that-point) P0 plane
  unsigned short* xcls = P0;

  // zero plane tail pads
  hipMemsetAsync(P0 + XELEMS, 0, PLPAD * 2, stream);
  hipMemsetAsync(P1 + XELEMS, 0, PLPAD * 2, stream);

  wconv3_k<<<(int)((W200SZ + 255) / 256), 256, 0, stream>>>(W0, 200, 200, 7, 2, 7, w0f);
  wconv3_k<<<(int)((W200SZ + 255) / 256), 256, 0, stream>>>(W1, 200, 200, 7, 2, 7, w1f);
  wconv3_k<<<(int)((W200SZ + 255) / 256), 256, 0, stream>>>(W2, 200, 200, 7, 2, 7, w2f);
  wconv3_k<<<(int)((W3SZ + 255) / 256), 256, 0, stream>>>(W3, 200, 64, 4, 1, 7, w3f);
  wconv3_k<<<(int)((W4SZ + 255) / 256), 256, 0, stream>>>(W4, 64, 8, 1, 1, 2, w4f);

  rowsum4_k<<<NROWS / 4, 256, 0, stream>>>(intra, rsI);
  intersum_k<<<(BDIM * 8 + 255) / 256, 256, 0, stream>>>(inter, rsP);

  // block 1: nodef (fp32) -> X1 (P0)
  seg_combine_bf_k<0, 0><<<BDIM, 128, 0, stream>>>(
      nodef, nullptr, rsI, rsP, nullptr, P0);

  // H = leaky(X1@W0+b0): P0 -> P1
  gemm_bf_k<7, 1, 0><<<dim3(NROWS / 128, 2), 256, 0, stream>>>(
      P0, w0f, b0, P1, 200, nullptr);
  // Y1 = H@W1+b1 (+stats): P1 -> P0
  hipMemsetAsync(stats, 0, 400 * sizeof(float), stream);
  gemm_bf_k<7, 0, 1><<<dim3(NROWS / 128, 2), 256, 0, stream>>>(
      P1, w1f, b1, P0, 200, stats);
  bn_scale_k<<<1, 256, 0, stream>>>(stats, g1, be1, 1.f / (float)NROWS, ssbuf);

  // block 2 (BN1 fold): P0 -> X2 (P1)
  seg_combine_bf_k<1, 1><<<BDIM, 128, 0, stream>>>(
      nullptr, P0, rsI, rsP, ssbuf, P1);

  // Y2 = leaky(X2@W2+b2) (+stats): P1 -> P0
  hipMemsetAsync(stats, 0, 400 * sizeof(float), stream);
  gemm_bf_k<7, 1, 1><<<dim3(NROWS / 128, 2), 256, 0, stream>>>(
      P1, w2f, b2, P0, 200, stats);
  bn_scale_k<<<1, 256, 0, stream>>>(stats, g2, be2, 1.f / (float)NROWS, ssbuf);

  // block 3 (BN2 fold): P0 -> X3 (P1)
  seg_combine_bf_k<1, 1><<<BDIM, 128, 0, stream>>>(
      nullptr, P0, rsI, rsP, ssbuf, P1);

  // xcls = leaky(leaky(X3@W3+b3)@W4+b4): P1 -> xcls (aliases P0, dead)
  gemm_w34_k<<<NROWS / 128, 256, 0, stream>>>(P1, w3f, w4f, b3, b4, xcls);

  // bn3d stats on xcls; affine folded into Wc1/bias1
  hipMemsetAsync(stats, 0, 400 * sizeof(float), stream);
  bn3d_stats_bf_k<<<64, 256, 0, stream>>>(xcls, stats);
  bn_scale_k<<<1, 256, 0, stream>>>(stats, g3, be3, 1.f / 8192.f, ssbuf);

  // fold BN3d into Wc1 (scale) and bias1 (shift)
  wcls_conv_k<<<1600, 256, 0, stream>>>(Wc1, ssbuf, wc1f);
  bias1_init_k<<<1, 256, 0, stream>>>(bc1, bias1p);
  bias1_acc_k<<<16, 256, 0, stream>>>(Wc1, ssbuf, bias1p);

  // classifier GEMM1 (MFMA, K-split atomics) then tail
  hipMemsetAsync(h1f, 0, (size_t)BDIM * 256 * sizeof(float), stream);
  gemm_cls1_k<<<dim3(8, 4, 5), 256, 0, stream>>>(xcls, wc1f, h1f);
  classifier2_k<<<BDIM / 8, 256, 0, stream>>>(h1f, bias1p, Wc2, bc2, Wc3, bc3, out);
}

// Round 12
// 512.374 us; speedup vs baseline: 5.3107x; 1.1574x over previous
//
#include <hip/hip_runtime.h>
#include <hip/hip_bf16.h>

// Problem constants
#define BDIM 1024
#define ROI 200
#define DIN 200
#define NSUB 8
#define NROWS (BDIM * ROI)           // 204800
#define XELEMS ((size_t)NROWS * 200) // 40,960,000
#define PLPAD 32                     // tail pad (shorts) per plane for k-overrun
#define PLSZ (XELEMS + PLPAD)        // shorts per bf16 plane

typedef __attribute__((ext_vector_type(8))) short short8;
typedef __attribute__((ext_vector_type(4))) float f32x4;

__device__ __constant__ float d_invcnt[8] = {
    1.f/41.f, 1.f/29.f, 1.f/21.f, 1.f/19.f, 1.f/20.f, 1.f/7.f, 1.f/21.f, 1.f/42.f};

__device__ inline unsigned short f2bf_rn(float x) {
  unsigned u = __float_as_uint(x);
  return (unsigned short)((u + 0x7FFFu + ((u >> 16) & 1u)) >> 16);
}
__device__ constexpr int seg_of_c(int r) {
  return (r < 41) ? 0 : (r < 70) ? 1 : (r < 91) ? 2 : (r < 110) ? 3
       : (r < 130) ? 4 : (r < 137) ? 5 : (r < 158) ? 6 : 7;
}

// async global->LDS, 16B per lane; LDS dest = uniform base + lane*16
__device__ inline void gload_lds16(const unsigned short* src, unsigned short* dst) {
  __builtin_amdgcn_global_load_lds(
      (const __attribute__((address_space(1))) void*)src,
      (__attribute__((address_space(3))) void*)dst, 16, 0, 0);
}

// A-burst: whole K strip (7 granules) for two 16-row fragments
__device__ inline void aburst7(const unsigned short* pA, const unsigned short* pB,
                               short8 (&aA)[7], short8 (&aB)[7]) {
  #pragma unroll
  for (int i = 0; i < 7; ++i) {
    aA[i] = *(const short8*)(pA + i * 32);
    aB[i] = *(const short8*)(pB + i * 32);
  }
}

// rs_intra: one wave per row, 4 rows per block
__global__ __launch_bounds__(256) void rowsum4_k(const float* __restrict__ in,
                                                 float* __restrict__ out) {
  int row = blockIdx.x * 4 + (threadIdx.x >> 6);
  int lane = threadIdx.x & 63;
  const float* p = in + (size_t)row * 200;
  float v = p[lane] + p[lane + 64] + p[lane + 128];
  if (lane < 8) v += p[lane + 192];
  #pragma unroll
  for (int off = 32; off > 0; off >>= 1) v += __shfl_down(v, off);
  if (lane == 0) out[row] = v;
}

__global__ __launch_bounds__(256) void intersum_k(const float* __restrict__ in,
                                                  float* __restrict__ out) {
  int i = blockIdx.x * blockDim.x + threadIdx.x;
  if (i >= BDIM * NSUB) return;
  const float* p = in + (size_t)i * 8;
  float v = 0.f;
  #pragma unroll
  for (int c = 0; c < 8; ++c) v += p[c];
  out[i] = v;
}

// Fused seg_mean + block_combine (+ optional BN fold), r-major full unroll.
// 128 threads; thread t<100 owns cols (2t, 2t+1) of batch blockIdx.x.
template<int INPL, int BN>
__global__ __launch_bounds__(128) void seg_combine_bf_k(
    const float* __restrict__ xf, const unsigned short* __restrict__ xp,
    const float* __restrict__ rsI, const float* __restrict__ rsP,
    const float* __restrict__ ss, unsigned short* __restrict__ yp) {
  int b = blockIdx.x;
  int t = threadIdx.x;
  if (t >= 100) return;
  int c0 = 2 * t;
  size_t base = (size_t)b * 40000 + c0;
  float sc0 = 1.f, sh0 = 0.f, sc1 = 1.f, sh1 = 0.f;
  if (BN) { sc0 = ss[c0]; sh0 = ss[200 + c0]; sc1 = ss[c0 + 1]; sh1 = ss[200 + c0 + 1]; }
  float a0[8] = {0,0,0,0,0,0,0,0};
  float a1[8] = {0,0,0,0,0,0,0,0};
  // phase 1: r-major, fully unrolled -> 200 independent loads, static acc idx
  #pragma unroll
  for (int r = 0; r < 200; ++r) {
    size_t idx = base + (size_t)r * 200;
    float v0, v1;
    if (INPL) {
      unsigned u = *(const unsigned*)(xp + idx);
      v0 = __uint_as_float(u << 16);
      v1 = __uint_as_float(u & 0xFFFF0000u);
    } else {
      float2 fv = *(const float2*)(xf + idx);
      v0 = fv.x; v1 = fv.y;
    }
    int s = seg_of_c(r);
    a0[s] += v0; a1[s] += v1;
  }
  float pr0[8], pr1[8];
  #pragma unroll
  for (int s = 0; s < 8; ++s) {
    float m0 = a0[s] * d_invcnt[s];
    float m1 = a1[s] * d_invcnt[s];
    if (BN) { m0 = m0 * sc0 + sh0; m1 = m1 * sc1 + sh1; }
    float rp = rsP[b * 8 + s];
    pr0[s] = rp * m0; pr1[s] = rp * m1;
  }
  const float* rsIb = rsI + b * 200;
  // phase 2: r-major, fully unrolled (x re-read is L2-hot)
  #pragma unroll
  for (int r = 0; r < 200; ++r) {
    size_t idx = base + (size_t)r * 200;
    float v0, v1;
    if (INPL) {
      unsigned u = *(const unsigned*)(xp + idx);
      v0 = __uint_as_float(u << 16);
      v1 = __uint_as_float(u & 0xFFFF0000u);
    } else {
      float2 fv = *(const float2*)(xf + idx);
      v0 = fv.x; v1 = fv.y;
    }
    if (BN) { v0 = v0 * sc0 + sh0; v1 = v1 * sc1 + sh1; }
    int s = seg_of_c(r);
    float ri = rsIb[r];
    float y0 = 0.5f * (ri * v0 + pr0[s]);
    float y1 = 0.5f * (ri * v1 + pr1[s]);
    unsigned o = (unsigned)f2bf_rn(y0) | ((unsigned)f2bf_rn(y1) << 16);
    *(unsigned*)(yp + idx) = o;
  }
}

// Weight preconversion into per-colblock fragment-major granule layout for
// mfma_f32_16x16x32_bf16.
__global__ __launch_bounds__(256) void wconv3_k(const float* __restrict__ W, int K, int N,
                                                int NFRAG, int NB, int KSTEPS,
                                                unsigned short* __restrict__ dst) {
  int total = NB * KSTEPS * NFRAG * 64 * 8;
  int idx = blockIdx.x * 256 + threadIdx.x;
  if (idx >= total) return;
  int j = idx & 7;
  int lane = (idx >> 3) & 63;
  int rest = idx >> 9;
  int frag = rest % NFRAG;
  int rest2 = rest / NFRAG;
  int ks = rest2 % KSTEPS;
  int cb = rest2 / KSTEPS;
  int k = ks * 32 + ((lane >> 4) << 3) + j;
  int col = cb * NFRAG * 16 + frag * 16 + (lane & 15);
  float v = (k < K && col < N) ? W[(size_t)k * N + col] : 0.f;
  dst[idx] = f2bf_rn(v);
}

// Persistent bf16-plane MFMA GEMM: 4 row-tiles per block, W staged once,
// A-bursts double-buffered (prefetch tile t+1 before computing tile t).
// grid (400, 2); 4 waves x 32 rows = 128 rows/tile.
template<int NFRAG, int ACT, int STATS>
__global__ __launch_bounds__(256, 2) void gemm_bf_k(
    const unsigned short* __restrict__ A, const unsigned short* __restrict__ Wf,
    const float* __restrict__ bias, unsigned short* __restrict__ Cp,
    int N, float* __restrict__ stats) {
  constexpr int G = NFRAG * 7 * 64;
  __shared__ unsigned short wlds[G * 8];
  __shared__ float s_sum[NFRAG * 16];
  __shared__ float s_sq[NFRAG * 16];
  int tid = threadIdx.x;
  int lane = tid & 63;
  int wid = tid >> 6;

  const unsigned short* wsrc = Wf + (size_t)blockIdx.y * G * 8;
  for (int g0 = wid * 64; g0 < G; g0 += 256)
    gload_lds16(wsrc + (size_t)(g0 + lane) * 8, &wlds[(size_t)g0 * 8]);
  if (STATS && tid < NFRAG * 16) { s_sum[tid] = 0.f; s_sq[tid] = 0.f; }

  const unsigned short* baseA = A + (size_t)(lane & 15) * 200 + ((lane >> 4) << 3);
  int colbase = blockIdx.y * NFRAG * 16;
  int r0 = (lane >> 4) * 4;

  short8 aA0[7], aB0[7], aA1[7], aB1[7];
  {
    size_t off = (size_t)(blockIdx.x * 128 + wid * 32) * 200;
    aburst7(baseA + off, baseA + off + 16 * 200, aA0, aB0);
  }
  __builtin_amdgcn_sched_barrier(0);
  __syncthreads();  // W in LDS, first burst in regs

  #pragma unroll
  for (int t = 0; t < 4; ++t) {
    int rt = blockIdx.x + 400 * t;
    int row0 = rt * 128 + wid * 32;
    // prefetch next tile into the other register set
    if (t < 3) {
      size_t off = (size_t)((rt + 400) * 128 + wid * 32) * 200;
      if (t & 1) aburst7(baseA + off, baseA + off + 16 * 200, aA0, aB0);
      else       aburst7(baseA + off, baseA + off + 16 * 200, aA1, aB1);
      __builtin_amdgcn_sched_barrier(0);  // keep prefetch above compute
    }
    f32x4 accA[NFRAG], accB[NFRAG];
    #pragma unroll
    for (int f = 0; f < NFRAG; ++f) { accA[f] = 0.0f; accB[f] = 0.0f; }
    #pragma unroll
    for (int ks = 0; ks < 7; ++ks) {
      const short8* wp = (const short8*)wlds + (size_t)(ks * NFRAG) * 64 + lane;
      short8 av = (t & 1) ? aA1[ks] : aA0[ks];
      short8 bv = (t & 1) ? aB1[ks] : aB0[ks];
      #pragma unroll
      for (int f = 0; f < NFRAG; ++f) {
        short8 wv = wp[(size_t)f * 64];
        accA[f] = __builtin_amdgcn_mfma_f32_16x16x32_bf16(av, wv, accA[f], 0, 0, 0);
        accB[f] = __builtin_amdgcn_mfma_f32_16x16x32_bf16(bv, wv, accB[f], 0, 0, 0);
      }
    }
    #pragma unroll
    for (int f = 0; f < NFRAG; ++f) {
      int col = colbase + f * 16 + (lane & 15);
      if (col < N) {
        float b = bias[col];
        float ls = 0.f, lq = 0.f;
        #pragma unroll
        for (int r = 0; r < 4; ++r) {
          int row = row0 + r0 + r;
          float v = accA[f][r] + b;
          if (ACT) v = (v >= 0.f) ? v : 0.2f * v;
          Cp[(size_t)row * 200 + col] = f2bf_rn(v);
          if (STATS) { ls += v; lq += v * v; }
        }
        #pragma unroll
        for (int r = 0; r < 4; ++r) {
          int row = row0 + 16 + r0 + r;
          float v = accB[f][r] + b;
          if (ACT) v = (v >= 0.f) ? v : 0.2f * v;
          Cp[(size_t)row * 200 + col] = f2bf_rn(v);
          if (STATS) { ls += v; lq += v * v; }
        }
        if (STATS) {
          atomicAdd(&s_sum[f * 16 + (lane & 15)], ls);
          atomicAdd(&s_sq[f * 16 + (lane & 15)], lq);
        }
      }
    }
  }
  if (STATS) {
    __syncthreads();
    if (tid < NFRAG * 16) {
      int col = colbase + tid;
      if (col < 200) {
        atomicAdd(&stats[col], s_sum[tid]);
        atomicAdd(&stats[200 + col], s_sq[tid]);
      }
    }
  }
}

// Persistent fused W3+W4: 4 row-tiles per block, A double-buffered.
// xcls = leaky(leaky(X3@W3+b3)@W4+b4) as bf16 (1024x1600).
__global__ __launch_bounds__(256, 2) void gemm_w34_k(
    const unsigned short* __restrict__ A, const unsigned short* __restrict__ W3f,
    const unsigned short* __restrict__ W4f, const float* __restrict__ b3,
    const float* __restrict__ b4, unsigned short* __restrict__ xcls) {
  __shared__ unsigned short w3lds[7 * 4 * 64 * 8];   // 28 KB
  __shared__ unsigned short w4lds[2 * 64 * 8];       // 2 KB
  __shared__ unsigned short h3buf[128][72];          // 18 KB
  int tid = threadIdx.x;
  int lane = tid & 63;
  int wid = tid >> 6;

  for (int g0 = wid * 64; g0 < 1792; g0 += 256)
    gload_lds16(W3f + (size_t)(g0 + lane) * 8, &w3lds[(size_t)g0 * 8]);
  for (int g0 = wid * 64; g0 < 128; g0 += 256)
    gload_lds16(W4f + (size_t)(g0 + lane) * 8, &w4lds[(size_t)g0 * 8]);

  const unsigned short* baseA = A + (size_t)(lane & 15) * 200 + ((lane >> 4) << 3);
  int r0 = (lane >> 4) * 4;

  short8 aA0[7], aB0[7], aA1[7], aB1[7];
  {
    size_t off = (size_t)(blockIdx.x * 128 + wid * 32) * 200;
    aburst7(baseA + off, baseA + off + 16 * 200, aA0, aB0);
  }
  __builtin_amdgcn_sched_barrier(0);
  __syncthreads();

  #pragma unroll
  for (int t = 0; t < 4; ++t) {
    int rt = blockIdx.x + 400 * t;
    int row0 = rt * 128 + wid * 32;
    if (t < 3) {
      size_t off = (size_t)((rt + 400) * 128 + wid * 32) * 200;
      if (t & 1) aburst7(baseA + off, baseA + off + 16 * 200, aA0, aB0);
      else       aburst7(baseA + off, baseA + off + 16 * 200, aA1, aB1);
      __builtin_amdgcn_sched_barrier(0);
    }
    f32x4 accA[4], accB[4];
    #pragma unroll
    for (int f = 0; f < 4; ++f) { accA[f] = 0.0f; accB[f] = 0.0f; }
    #pragma unroll
    for (int ks = 0; ks < 7; ++ks) {
      const short8* wp = (const short8*)w3lds + (size_t)(ks * 4) * 64 + lane;
      short8 av = (t & 1) ? aA1[ks] : aA0[ks];
      short8 bv = (t & 1) ? aB1[ks] : aB0[ks];
      #pragma unroll
      for (int f = 0; f < 4; ++f) {
        short8 wv = wp[(size_t)f * 64];
        accA[f] = __builtin_amdgcn_mfma_f32_16x16x32_bf16(av, wv, accA[f], 0, 0, 0);
        accB[f] = __builtin_amdgcn_mfma_f32_16x16x32_bf16(bv, wv, accB[f], 0, 0, 0);
      }
    }
    #pragma unroll
    for (int f = 0; f < 4; ++f) {
      int col = f * 16 + (lane & 15);
      float bb = b3[col];
      #pragma unroll
      for (int r = 0; r < 4; ++r) {
        float v = accA[f][r] + bb;
        v = (v >= 0.f) ? v : 0.2f * v;
        h3buf[wid * 32 + r0 + r][col] = f2bf_rn(v);
        v = accB[f][r] + bb;
        v = (v >= 0.f) ? v : 0.2f * v;
        h3buf[wid * 32 + 16 + r0 + r][col] = f2bf_rn(v);
      }
    }
    // wave-local LDS write->read: compiler inserts lgkmcnt; no barrier needed.
    f32x4 acc2A = 0.0f, acc2B = 0.0f;
    #pragma unroll
    for (int ks = 0; ks < 2; ++ks) {
      short8 a2A = *(const short8*)&h3buf[wid * 32 + (lane & 15)][ks * 32 + ((lane >> 4) << 3)];
      short8 a2B = *(const short8*)&h3buf[wid * 32 + 16 + (lane & 15)][ks * 32 + ((lane >> 4) << 3)];
      short8 wv = *(const short8*)&w4lds[(size_t)(ks * 64 + lane) * 8];
      acc2A = __builtin_amdgcn_mfma_f32_16x16x32_bf16(a2A, wv, acc2A, 0, 0, 0);
      acc2B = __builtin_amdgcn_mfma_f32_16x16x32_bf16(a2B, wv, acc2B, 0, 0, 0);
    }
    int col = lane & 15;
    if (col < 8) {
      float bb = b4[col];
      #pragma unroll
      for (int r = 0; r < 4; ++r) {
        int row = row0 + r0 + r;
        float v = acc2A[r] + bb;
        v = (v >= 0.f) ? v : 0.2f * v;
        xcls[(size_t)(row / 200) * 1600 + (row % 200) * 8 + col] = f2bf_rn(v);
        int row2 = row + 16;
        v = acc2B[r] + bb;
        v = (v >= 0.f) ? v : 0.2f * v;
        xcls[(size_t)(row2 / 200) * 1600 + (row2 % 200) * 8 + col] = f2bf_rn(v);
      }
    }
  }
}

__global__ __launch_bounds__(256) void bn_scale_k(const float* __restrict__ stats,
                                                  const float* __restrict__ g,
                                                  const float* __restrict__ be,
                                                  float invN,
                                                  float* __restrict__ ss) {
  int c = threadIdx.x;
  if (c >= 200) return;
  float m = stats[c] * invN;
  float var = stats[200 + c] * invN - m * m;
  float sc = rsqrtf(var + 1e-5f) * g[c];
  ss[c] = sc;
  ss[200 + c] = be[c] - m * sc;
}

// bn3d stats over bf16 xcls (1024 x 1600; r = col>>3)
__global__ __launch_bounds__(256) void bn3d_stats_bf_k(const unsigned short* __restrict__ x,
                                                       float* __restrict__ stats) {
  int t = threadIdx.x;
  if (t >= 200) return;
  const unsigned short* p = x + (size_t)blockIdx.x * 16 * 1600 + t * 8;
  float s = 0.f, q = 0.f;
  for (int b = 0; b < 16; ++b) {
    const unsigned* u = (const unsigned*)(p + (size_t)b * 1600);
    #pragma unroll
    for (int i = 0; i < 4; ++i) {
      unsigned w = u[i];
      float v0 = __uint_as_float(w << 16);
      float v1 = __uint_as_float(w & 0xFFFF0000u);
      s += v0 + v1;
      q += v0 * v0 + v1 * v1;
    }
  }
  atomicAdd(&stats[t], s);
  atomicAdd(&stats[200 + t], q);
}

// Wc1 fold + fragment-major bf16 conversion: Wc1'[k][n] = Wc1[k][n]*sc[k>>3].
__global__ __launch_bounds__(256) void wcls_conv_k(const float* __restrict__ Wc1,
                                                   const float* __restrict__ ss,
                                                   unsigned short* __restrict__ dst) {
  int idx = blockIdx.x * 256 + threadIdx.x;
  if (idx >= 409600) return;
  int j = idx & 7;
  int lane = (idx >> 3) & 63;
  int rest = idx >> 9;
  int frag = rest & 3;
  int rest2 = rest >> 2;
  int ks = rest2 % 10;
  int slice = rest2 / 10;
  int kc = slice % 5, cb = slice / 5;
  int k = kc * 320 + ks * 32 + ((lane >> 4) << 3) + j;
  int col = cb * 64 + frag * 16 + (lane & 15);
  dst[idx] = f2bf_rn(Wc1[(size_t)k * 256 + col] * ss[k >> 3]);
}

// bias1' = bc1 + sum_k sh[k>>3] * Wc1[k][n]
__global__ __launch_bounds__(256) void bias1_init_k(const float* __restrict__ bc1,
                                                    float* __restrict__ bias1p) {
  bias1p[threadIdx.x] = bc1[threadIdx.x];
}
__global__ __launch_bounds__(256) void bias1_acc_k(const float* __restrict__ Wc1,
                                                   const float* __restrict__ ss,
                                                   float* __restrict__ bias1p) {
  int t = threadIdx.x;
  int k0 = blockIdx.x * 100;
  float a = 0.f;
  #pragma unroll 4
  for (int k = k0; k < k0 + 100; ++k)
    a += ss[200 + (k >> 3)] * Wc1[(size_t)k * 256 + t];
  atomicAdd(&bias1p[t], a);
}

// Classifier GEMM1 (MFMA, K-split): h1f += xcls[128 rows] @ Wc1' chunk.
__global__ __launch_bounds__(256, 3) void gemm_cls1_k(
    const unsigned short* __restrict__ xcls, const unsigned short* __restrict__ Wf,
    float* __restrict__ h1f) {
  __shared__ unsigned short wlds[10 * 4 * 64 * 8];  // 40 KB
  int tid = threadIdx.x;
  int lane = tid & 63;
  int wid = tid >> 6;
  const unsigned short* wsrc = Wf + (size_t)(blockIdx.y * 5 + blockIdx.z) * (10 * 4 * 64) * 8;
  for (int g0 = wid * 64; g0 < 2560; g0 += 256)
    gload_lds16(wsrc + (size_t)(g0 + lane) * 8, &wlds[(size_t)g0 * 8]);

  int row0 = blockIdx.x * 128 + wid * 32;
  int kbase = blockIdx.z * 320;
  const unsigned short* pA = xcls + (size_t)(row0 + (lane & 15)) * 1600 + kbase + ((lane >> 4) << 3);
  const unsigned short* pB = pA + 16 * 1600;
  short8 aA[10], aB[10];
  #pragma unroll
  for (int i = 0; i < 10; ++i) {
    aA[i] = *(const short8*)(pA + i * 32);
    aB[i] = *(const short8*)(pB + i * 32);
  }
  __builtin_amdgcn_sched_barrier(0);
  __syncthreads();

  f32x4 accA[4], accB[4];
  #pragma unroll
  for (int f = 0; f < 4; ++f) { accA[f] = 0.0f; accB[f] = 0.0f; }
  #pragma unroll
  for (int ks = 0; ks < 10; ++ks) {
    const short8* wp = (const short8*)wlds + (size_t)(ks * 4) * 64 + lane;
    #pragma unroll
    for (int f = 0; f < 4; ++f) {
      short8 wv = wp[(size_t)f * 64];
      accA[f] = __builtin_amdgcn_mfma_f32_16x16x32_bf16(aA[ks], wv, accA[f], 0, 0, 0);
      accB[f] = __builtin_amdgcn_mfma_f32_16x16x32_bf16(aB[ks], wv, accB[f], 0, 0, 0);
    }
  }
  int colbase = blockIdx.y * 64;
  int r0 = (lane >> 4) * 4;
  #pragma unroll
  for (int f = 0; f < 4; ++f) {
    int col = colbase + f * 16 + (lane & 15);
    #pragma unroll
    for (int r = 0; r < 4; ++r) {
      atomicAdd(&h1f[(size_t)(row0 + r0 + r) * 256 + col], accA[f][r]);
      atomicAdd(&h1f[(size_t)(row0 + 16 + r0 + r) * 256 + col], accB[f][r]);
    }
  }
}

// Classifier tail: h1 = leaky(h1f + bias1'), h2 = leaky(h1@Wc2+bc2), out = h2@Wc3+bc3.
__global__ __launch_bounds__(256) void classifier2_k(
    const float* __restrict__ h1f, const float* __restrict__ bias1p,
    const float* __restrict__ Wc2, const float* __restrict__ bc2,
    const float* __restrict__ Wc3, const float* __restrict__ bc3,
    float* __restrict__ out) {
  __shared__ float h1s[8][256];
  __shared__ float h2s[8][32];
  int t = threadIdx.x;
  int b0 = blockIdx.x * 8;
  #pragma unroll
  for (int j = 0; j < 8; ++j) {
    float v = h1f[(size_t)(b0 + j) * 256 + t] + bias1p[t];
    h1s[j][t] = (v >= 0.f) ? v : 0.2f * v;
  }
  __syncthreads();
  {
    int j = t >> 5, c = t & 31;
    float a = 0.f;
    #pragma unroll 8
    for (int k = 0; k < 256; ++k) a += h1s[j][k] * Wc2[k * 32 + c];
    float v = a + bc2[c];
    h2s[j][c] = (v >= 0.f) ? v : 0.2f * v;
  }
  __syncthreads();
  if (t < 16) {
    int j = t >> 1, c = t & 1;
    float a = 0.f;
    #pragma unroll
    for (int k = 0; k < 32; ++k) a += h2s[j][k] * Wc3[k * 2 + c];
    out[(size_t)(b0 + j) * 2 + c] = a + bc3[c];
  }
}

extern "C" void kernel_launch(void* const* d_in, const int* in_sizes, int n_in,
                              void* d_out, int out_size, void* d_ws, size_t ws_size,
                              hipStream_t stream) {
  const float* intra = (const float*)d_in[1];
  const float* inter = (const float*)d_in[2];
  const float* nodef = (const float*)d_in[3];
  const float* W0 = (const float*)d_in[4];
  const float* b0 = (const float*)d_in[5];
  const float* W1 = (const float*)d_in[6];
  const float* b1 = (const float*)d_in[7];
  const float* g1 = (const float*)d_in[8];
  const float* be1 = (const float*)d_in[9];
  const float* W2 = (const float*)d_in[10];
  const float* b2 = (const float*)d_in[11];
  const float* g2 = (const float*)d_in[12];
  const float* be2 = (const float*)d_in[13];
  const float* W3 = (const float*)d_in[14];
  const float* b3 = (const float*)d_in[15];
  const float* W4 = (const float*)d_in[16];
  const float* b4 = (const float*)d_in[17];
  const float* g3 = (const float*)d_in[18];
  const float* be3 = (const float*)d_in[19];
  const float* Wc1 = (const float*)d_in[20];
  const float* bc1 = (const float*)d_in[21];
  const float* Wc2 = (const float*)d_in[22];
  const float* bc2 = (const float*)d_in[23];
  const float* Wc3 = (const float*)d_in[24];
  const float* bc3 = (const float*)d_in[25];
  float* out = (float*)d_out;

  // Layout: 2 bf16 planes (ping-pong), then fp32 scratch + weights.
  unsigned short* P0 = (unsigned short*)d_ws;
  unsigned short* P1 = P0 + PLSZ;
  float* fbase = (float*)(P1 + PLSZ);
  float* rsI  = fbase;                         // 204,800
  float* rsP  = rsI + NROWS;                   // 8,192
  float* stats = rsP + BDIM * 8;               // 512
  float* ssbuf = stats + 512;                  // 512
  float* h1f  = ssbuf + 512;                   // 262,144
  float* bias1p = h1f + (size_t)BDIM * 256;    // 256 (pad 512)
  unsigned short* wt = (unsigned short*)(bias1p + 512);
  const size_t W200SZ = 2 * 7 * 7 * 64 * 8;    // 50,176 shorts
  const size_t W3SZ   = 1 * 7 * 4 * 64 * 8;    // 14,336 shorts
  const size_t W4SZ   = 1 * 2 * 1 * 64 * 8;    // 1,024 shorts
  unsigned short* w0f = wt;
  unsigned short* w1f = w0f + W200SZ;
  unsigned short* w2f = w1f + W200SZ;
  unsigned short* w3f = w2f + W200SZ;
  unsigned short* w4f = w3f + W3SZ;
  unsigned short* wc1f = w4f + W4SZ;
  // xcls (1024x1600 bf16) aliases the (dead-at-that-point) P0 plane
  unsigned short* xcls = P0;

  // zero plane tail pads
  hipMemsetAsync(P0 + XELEMS, 0, PLPAD * 2, stream);
  hipMemsetAsync(P1 + XELEMS, 0, PLPAD * 2, stream);

  wconv3_k<<<(int)((W200SZ + 255) / 256), 256, 0, stream>>>(W0, 200, 200, 7, 2, 7, w0f);
  wconv3_k<<<(int)((W200SZ + 255) / 256), 256, 0, stream>>>(W1, 200, 200, 7, 2, 7, w1f);
  wconv3_k<<<(int)((W200SZ + 255) / 256), 256, 0, stream>>>(W2, 200, 200, 7, 2, 7, w2f);
  wconv3_k<<<(int)((W3SZ + 255) / 256), 256, 0, stream>>>(W3, 200, 64, 4, 1, 7, w3f);
  wconv3_k<<<(int)((W4SZ + 255) / 256), 256, 0, stream>>>(W4, 64, 8, 1, 1, 2, w4f);

  rowsum4_k<<<NROWS / 4, 256, 0, stream>>>(intra, rsI);
  intersum_k<<<(BDIM * 8 + 255) / 256, 256, 0, stream>>>(inter, rsP);

  // block 1: nodef (fp32) -> X1 (P0)
  seg_combine_bf_k<0, 0><<<BDIM, 128, 0, stream>>>(
      nodef, nullptr, rsI, rsP, nullptr, P0);

  // H = leaky(X1@W0+b0): P0 -> P1
  gemm_bf_k<7, 1, 0><<<dim3(400, 2), 256, 0, stream>>>(
      P0, w0f, b0, P1, 200, nullptr);
  // Y1 = H@W1+b1 (+stats): P1 -> P0
  hipMemsetAsync(stats, 0, 400 * sizeof(float), stream);
  gemm_bf_k<7, 0, 1><<<dim3(400, 2), 256, 0, stream>>>(
      P1, w1f, b1, P0, 200, stats);
  bn_scale_k<<<1, 256, 0, stream>>>(stats, g1, be1, 1.f / (float)NROWS, ssbuf);

  // block 2 (BN1 fold): P0 -> X2 (P1)
  seg_combine_bf_k<1, 1><<<BDIM, 128, 0, stream>>>(
      nullptr, P0, rsI, rsP, ssbuf, P1);

  // Y2 = leaky(X2@W2+b2) (+stats): P1 -> P0
  hipMemsetAsync(stats, 0, 400 * sizeof(float), stream);
  gemm_bf_k<7, 1, 1><<<dim3(400, 2), 256, 0, stream>>>(
      P1, w2f, b2, P0, 200, stats);
  bn_scale_k<<<1, 256, 0, stream>>>(stats, g2, be2, 1.f / (float)NROWS, ssbuf);

  // block 3 (BN2 fold): P0 -> X3 (P1)
  seg_combine_bf_k<1, 1><<<BDIM, 128, 0, stream>>>(
      nullptr, P0, rsI, rsP, ssbuf, P1);

  // xcls = leaky(leaky(X3@W3+b3)@W4+b4): P1 -> xcls (aliases P0, dead)
  gemm_w34_k<<<400, 256, 0, stream>>>(P1, w3f, w4f, b3, b4, xcls);

  // bn3d stats on xcls; affine folded into Wc1/bias1
  hipMemsetAsync(stats, 0, 400 * sizeof(float), stream);
  bn3d_stats_bf_k<<<64, 256, 0, stream>>>(xcls, stats);
  bn_scale_k<<<1, 256, 0, stream>>>(stats, g3, be3, 1.f / 8192.f, ssbuf);

  // fold BN3d into Wc1 (scale) and bias1 (shift)
  wcls_conv_k<<<1600, 256, 0, stream>>>(Wc1, ssbuf, wc1f);
  bias1_init_k<<<1, 256, 0, stream>>>(bc1, bias1p);
  bias1_acc_k<<<16, 256, 0, stream>>>(Wc1, ssbuf, bias1p);

  // classifier GEMM1 (MFMA, K-split atomics) then tail
  hipMemsetAsync(h1f, 0, (size_t)BDIM * 256 * sizeof(float), stream);
  gemm_cls1_k<<<dim3(8, 4, 5), 256, 0, stream>>>(xcls, wc1f, h1f);
  classifier2_k<<<BDIM / 8, 256, 0, stream>>>(h1f, bias1p, Wc2, bc2, Wc3, bc3, out);
}